// Round 3
// baseline (6724.185 us; speedup 1.0000x reference)
//
#include <hip/hip_runtime.h>

#define MTOK 8192      // B*S
#define HD   768
#define H3   2304
#define NL   6
#define TT   32        // number of CRF tags (reference: T = 32)

typedef __attribute__((ext_vector_type(4))) float f32x4;
typedef __attribute__((ext_vector_type(8))) short v8bf;     // 8 bf16 in 4 VGPRs
typedef __attribute__((ext_vector_type(4))) unsigned short us4;

__device__ __forceinline__ unsigned short bf16rne(float v) {
    unsigned int u = __float_as_uint(v);
    u += 0x7FFFu + ((u >> 16) & 1u);
    return (unsigned short)(u >> 16);
}
__device__ __forceinline__ float bf2f(unsigned short h) {
    return __uint_as_float(((unsigned int)h) << 16);
}
// returns hi-bf16 in low 16 bits, mid-bf16 (residual) in high 16 bits
__device__ __forceinline__ unsigned int split_pack(float v) {
    unsigned short h = bf16rne(v);
    unsigned short m = bf16rne(v - bf2f(h));
    return (unsigned int)h | ((unsigned int)m << 16);
}

// ---------------------------------------------------------------------------
// GEMM: C[M=8192][N] = A[8192][768] (f32) x W[N][768]^T (f32) + bias, opt ReLU.
// 2-term bf16 split of both operands, 4 MFMA products => ~2^-17 rel accuracy.
// BM=BN=128, BK=64; 4 waves (2x2), each 64x64 via 4x4 frags of 16x16x32.
// ---------------------------------------------------------------------------
template<bool RELU>
__global__ __launch_bounds__(256)
void gemm_split_kernel(const float* __restrict__ A, const float* __restrict__ W,
                       const float* __restrict__ bias, float* __restrict__ C, int N)
{
    __shared__ unsigned short Ah[128 * 64], Am[128 * 64], Bh[128 * 64], Bm[128 * 64];
    const int tid = threadIdx.x;
    const int lane = tid & 63, wave = tid >> 6;
    const int wm = wave >> 1, wn = wave & 1;
    const int bn = blockIdx.x, bm = blockIdx.y;
    const int g = lane >> 4, lr = lane & 15;
    f32x4 acc[4][4] = {};

    for (int kt = 0; kt < 12; ++kt) {
        __syncthreads();
        // stage A and W k-slabs: f32 -> (hi, mid) bf16, XOR-swizzled LDS
        #pragma unroll
        for (int j = 0; j < 8; ++j) {
            int fid = tid + 256 * j;
            int row = fid >> 4, c4 = fid & 15;
            int ub = row * 64 + ((((c4 >> 1) ^ (row & 7)) << 3) | ((c4 & 1) << 2));
            float4 va = *reinterpret_cast<const float4*>(A + (size_t)(bm * 128 + row) * HD + kt * 64 + c4 * 4);
            us4 hv, mv;
            unsigned int p;
            p = split_pack(va.x); hv[0] = (unsigned short)p; mv[0] = (unsigned short)(p >> 16);
            p = split_pack(va.y); hv[1] = (unsigned short)p; mv[1] = (unsigned short)(p >> 16);
            p = split_pack(va.z); hv[2] = (unsigned short)p; mv[2] = (unsigned short)(p >> 16);
            p = split_pack(va.w); hv[3] = (unsigned short)p; mv[3] = (unsigned short)(p >> 16);
            *reinterpret_cast<us4*>(&Ah[ub]) = hv;
            *reinterpret_cast<us4*>(&Am[ub]) = mv;
            float4 vb = *reinterpret_cast<const float4*>(W + (size_t)(bn * 128 + row) * HD + kt * 64 + c4 * 4);
            p = split_pack(vb.x); hv[0] = (unsigned short)p; mv[0] = (unsigned short)(p >> 16);
            p = split_pack(vb.y); hv[1] = (unsigned short)p; mv[1] = (unsigned short)(p >> 16);
            p = split_pack(vb.z); hv[2] = (unsigned short)p; mv[2] = (unsigned short)(p >> 16);
            p = split_pack(vb.w); hv[3] = (unsigned short)p; mv[3] = (unsigned short)(p >> 16);
            *reinterpret_cast<us4*>(&Bh[ub]) = hv;
            *reinterpret_cast<us4*>(&Bm[ub]) = mv;
        }
        __syncthreads();
        #pragma unroll
        for (int kk = 0; kk < 2; ++kk) {
            v8bf ah[4], am[4], bh[4], bmv[4];
            #pragma unroll
            for (int i = 0; i < 4; ++i) {
                int row = wm * 64 + i * 16 + lr;
                int ub = row * 64 + ((((kk << 2) + g) ^ (row & 7)) << 3);
                ah[i] = *reinterpret_cast<const v8bf*>(&Ah[ub]);
                am[i] = *reinterpret_cast<const v8bf*>(&Am[ub]);
            }
            #pragma unroll
            for (int i = 0; i < 4; ++i) {
                int row = wn * 64 + i * 16 + lr;
                int ub = row * 64 + ((((kk << 2) + g) ^ (row & 7)) << 3);
                bh[i]  = *reinterpret_cast<const v8bf*>(&Bh[ub]);
                bmv[i] = *reinterpret_cast<const v8bf*>(&Bm[ub]);
            }
            #pragma unroll
            for (int i = 0; i < 4; ++i)
                #pragma unroll
                for (int j = 0; j < 4; ++j) {
                    acc[i][j] = __builtin_amdgcn_mfma_f32_16x16x32_bf16(ah[i], bh[j],  acc[i][j], 0, 0, 0);
                    acc[i][j] = __builtin_amdgcn_mfma_f32_16x16x32_bf16(ah[i], bmv[j], acc[i][j], 0, 0, 0);
                    acc[i][j] = __builtin_amdgcn_mfma_f32_16x16x32_bf16(am[i], bh[j],  acc[i][j], 0, 0, 0);
                    acc[i][j] = __builtin_amdgcn_mfma_f32_16x16x32_bf16(am[i], bmv[j], acc[i][j], 0, 0, 0);
                }
        }
    }
    #pragma unroll
    for (int j = 0; j < 4; ++j) {
        int n = bn * 128 + wn * 64 + j * 16 + lr;
        float bv = bias[n];
        #pragma unroll
        for (int i = 0; i < 4; ++i) {
            int mr = bm * 128 + wm * 64 + i * 16 + 4 * g;
            #pragma unroll
            for (int r = 0; r < 4; ++r) {
                float y = acc[i][j][r] + bv;
                if (RELU) y = fmaxf(y, 0.0f);
                C[(size_t)(mr + r) * N + n] = y;
            }
        }
    }
}

// ---------------------------------------------------------------------------
// Flash-style attention. Grid: (8 q-tiles, B*NH). Block: 256 thr = 4 waves.
// Each wave owns 16 q-rows; online softmax per 16-lane row-group.
// qkv f32 [8192][2304]; o f32 [8192][768] (token-major, col = h*64+d).
// ---------------------------------------------------------------------------
__global__ __launch_bounds__(256)
void attn_kernel(const float* __restrict__ qkv, float* __restrict__ o)
{
    __shared__ unsigned short Qh[64 * 64], Qm[64 * 64], Kh[64 * 64], Km[64 * 64],
                              Vh[64 * 64], Vm[64 * 64];
    __shared__ unsigned short Ph[4][16 * 64], Pm[4][16 * 64];
    const int qt = blockIdx.x;
    const int b = blockIdx.y / 12, h = blockIdx.y % 12;
    const int tid = threadIdx.x, lane = tid & 63, wave = tid >> 6;
    const int g = lane >> 4, lr = lane & 15;
    const size_t rowbase = (size_t)b * 512;

    // Q tile (64 rows x 64 d), split + swizzle into LDS
    #pragma unroll
    for (int e = 0; e < 16; ++e) {
        int idx = e * 256 + tid;
        int r = idx >> 6, d = idx & 63;
        float v = qkv[(rowbase + qt * 64 + r) * H3 + h * 64 + d];
        unsigned int pk = split_pack(v);
        int ub = r * 64 + ((((d >> 3) ^ (r & 7)) << 3) | (d & 7));
        Qh[ub] = (unsigned short)pk; Qm[ub] = (unsigned short)(pk >> 16);
    }

    float m_run[4] = {-__builtin_inff(), -__builtin_inff(), -__builtin_inff(), -__builtin_inff()};
    float l_run[4] = {};
    f32x4 O[4] = {};

    for (int kt = 0; kt < 8; ++kt) {
        __syncthreads();
        // stage K (row=kpos, d-contig) and V transposed (row=d, k-contig)
        #pragma unroll
        for (int e = 0; e < 16; ++e) {
            int idx = e * 256 + tid;
            int r = idx >> 6, d = idx & 63;
            size_t tok = (rowbase + kt * 64 + r) * H3 + h * 64 + d;
            unsigned int pk = split_pack(qkv[tok + 768]);
            int ubk = r * 64 + ((((d >> 3) ^ (r & 7)) << 3) | (d & 7));
            Kh[ubk] = (unsigned short)pk; Km[ubk] = (unsigned short)(pk >> 16);
            pk = split_pack(qkv[tok + 1536]);
            int ubv = d * 64 + ((((r >> 3) ^ (d & 7)) << 3) | (r & 7));
            Vh[ubv] = (unsigned short)pk; Vm[ubv] = (unsigned short)(pk >> 16);
        }
        __syncthreads();

        // S = Q K^T (3 products: hh, hm, mh)
        f32x4 s[4] = {};
        #pragma unroll
        for (int kk = 0; kk < 2; ++kk) {
            int qrow = wave * 16 + lr;
            int uq = qrow * 64 + ((((kk << 2) + g) ^ (qrow & 7)) << 3);
            v8bf aqh = *reinterpret_cast<const v8bf*>(&Qh[uq]);
            v8bf aqm = *reinterpret_cast<const v8bf*>(&Qm[uq]);
            #pragma unroll
            for (int j = 0; j < 4; ++j) {
                int krow = j * 16 + lr;
                int uk = krow * 64 + ((((kk << 2) + g) ^ (krow & 7)) << 3);
                v8bf bkh = *reinterpret_cast<const v8bf*>(&Kh[uk]);
                v8bf bkm = *reinterpret_cast<const v8bf*>(&Km[uk]);
                s[j] = __builtin_amdgcn_mfma_f32_16x16x32_bf16(aqh, bkh, s[j], 0, 0, 0);
                s[j] = __builtin_amdgcn_mfma_f32_16x16x32_bf16(aqh, bkm, s[j], 0, 0, 0);
                s[j] = __builtin_amdgcn_mfma_f32_16x16x32_bf16(aqm, bkh, s[j], 0, 0, 0);
            }
        }
        // online softmax per row (row = 4*g + rr, lane-group = 16 lanes)
        float mnew[4], alpha[4], rsum[4];
        #pragma unroll
        for (int rr = 0; rr < 4; ++rr) {
            float t = fmaxf(fmaxf(s[0][rr], s[1][rr]), fmaxf(s[2][rr], s[3][rr])) * 0.125f;
            #pragma unroll
            for (int off = 1; off < 16; off <<= 1) t = fmaxf(t, __shfl_xor(t, off));
            mnew[rr] = fmaxf(m_run[rr], t);
            alpha[rr] = __expf(m_run[rr] - mnew[rr]);
            m_run[rr] = mnew[rr];
            rsum[rr] = 0.0f;
        }
        #pragma unroll
        for (int j = 0; j < 4; ++j) {
            #pragma unroll
            for (int rr = 0; rr < 4; ++rr) {
                float p = __expf(s[j][rr] * 0.125f - mnew[rr]);
                rsum[rr] += p;
                int prow = 4 * g + rr;
                int ub = prow * 64 + ((((j * 2 + (lr >> 3)) ^ (prow & 7)) << 3) | (lr & 7));
                unsigned int pk = split_pack(p);
                Ph[wave][ub] = (unsigned short)pk; Pm[wave][ub] = (unsigned short)(pk >> 16);
            }
        }
        #pragma unroll
        for (int rr = 0; rr < 4; ++rr) {
            float t = rsum[rr];
            #pragma unroll
            for (int off = 1; off < 16; off <<= 1) t += __shfl_xor(t, off);
            l_run[rr] = l_run[rr] * alpha[rr] + t;
            O[0][rr] *= alpha[rr]; O[1][rr] *= alpha[rr];
            O[2][rr] *= alpha[rr]; O[3][rr] *= alpha[rr];
        }
        // O += P V  (3 products)
        #pragma unroll
        for (int kk = 0; kk < 2; ++kk) {
            int up = lr * 64 + ((((kk << 2) + g) ^ (lr & 7)) << 3);
            v8bf aph = *reinterpret_cast<const v8bf*>(&Ph[wave][up]);
            v8bf apm = *reinterpret_cast<const v8bf*>(&Pm[wave][up]);
            #pragma unroll
            for (int j = 0; j < 4; ++j) {
                int vrow = j * 16 + lr;
                int uv = vrow * 64 + ((((kk << 2) + g) ^ (vrow & 7)) << 3);
                v8bf bvh = *reinterpret_cast<const v8bf*>(&Vh[uv]);
                v8bf bvm = *reinterpret_cast<const v8bf*>(&Vm[uv]);
                O[j] = __builtin_amdgcn_mfma_f32_16x16x32_bf16(aph, bvh, O[j], 0, 0, 0);
                O[j] = __builtin_amdgcn_mfma_f32_16x16x32_bf16(aph, bvm, O[j], 0, 0, 0);
                O[j] = __builtin_amdgcn_mfma_f32_16x16x32_bf16(apm, bvh, O[j], 0, 0, 0);
            }
        }
    }
    #pragma unroll
    for (int j = 0; j < 4; ++j) {
        int d = j * 16 + lr;
        #pragma unroll
        for (int rr = 0; rr < 4; ++rr) {
            size_t tok = rowbase + qt * 64 + wave * 16 + 4 * g + rr;
            o[tok * HD + h * 64 + d] = O[j][rr] / l_run[rr];
        }
    }
}

// ---------------------------------------------------------------------------
// x = LayerNorm(x + t) * g + b, one wave per token (768 = 12 per lane)
// ---------------------------------------------------------------------------
__global__ __launch_bounds__(256)
void ln_residual_kernel(float* __restrict__ x, const float* __restrict__ t,
                        const float* __restrict__ gamma, const float* __restrict__ beta)
{
    int tok = blockIdx.x * 4 + (threadIdx.x >> 6);
    int lane = threadIdx.x & 63;
    float v[12];
    float s = 0.0f;
    #pragma unroll
    for (int j = 0; j < 12; ++j) {
        int c = j * 64 + lane;
        v[j] = x[(size_t)tok * HD + c] + t[(size_t)tok * HD + c];
        s += v[j];
    }
    #pragma unroll
    for (int off = 32; off; off >>= 1) s += __shfl_xor(s, off);
    float mean = s * (1.0f / 768.0f);
    float vs = 0.0f;
    #pragma unroll
    for (int j = 0; j < 12; ++j) { float d = v[j] - mean; vs += d * d; }
    #pragma unroll
    for (int off = 32; off; off >>= 1) vs += __shfl_xor(vs, off);
    float rstd = rsqrtf(vs * (1.0f / 768.0f) + 1e-5f);
    #pragma unroll
    for (int j = 0; j < 12; ++j) {
        int c = j * 64 + lane;
        x[(size_t)tok * HD + c] = (v[j] - mean) * rstd * gamma[c] + beta[c];
    }
}

__global__ __launch_bounds__(256)
void embed_kernel(const int* __restrict__ ids, const float* __restrict__ emb,
                  float* __restrict__ x)
{
    int f4 = blockIdx.x * 256 + threadIdx.x;     // 8192*192 float4
    int tok = f4 / 192, c = f4 % 192;
    float4 v = *reinterpret_cast<const float4*>(emb + (size_t)ids[tok] * HD + c * 4);
    *reinterpret_cast<float4*>(x + (size_t)tok * HD + c * 4) = v;
}

// emis[tok][t] = dot768(x[tok], head_w[t]) + head_b[t] — wave per token, f32
__global__ __launch_bounds__(256)
void emis_kernel(const float* __restrict__ x, const float* __restrict__ hw,
                 const float* __restrict__ hb, float* __restrict__ emis)
{
    int tok = blockIdx.x * 4 + (threadIdx.x >> 6);
    int lane = threadIdx.x & 63;
    float xv[12];
    #pragma unroll
    for (int j = 0; j < 12; ++j) xv[j] = x[(size_t)tok * HD + j * 64 + lane];
    for (int t = 0; t < TT; ++t) {
        float a = 0.0f;
        #pragma unroll
        for (int j = 0; j < 12; ++j) a += xv[j] * hw[t * HD + j * 64 + lane];
        #pragma unroll
        for (int off = 32; off; off >>= 1) a += __shfl_xor(a, off);
        if (lane == 0) emis[(size_t)tok * TT + t] = a + hb[t];
    }
}

__global__ void crf_num_kernel(const float* __restrict__ emis, const int* __restrict__ labels,
                               const float* __restrict__ start, const float* __restrict__ end,
                               const float* __restrict__ trans, float* __restrict__ num)
{
    int b = blockIdx.x, lane = threadIdx.x;   // blockDim 64
    float a = 0.0f;
    for (int s = lane; s < 512; s += 64) {
        int lab = labels[b * 512 + s];
        a += emis[(size_t)(b * 512 + s) * TT + lab];
        if (s > 0) a += trans[labels[b * 512 + s - 1] * TT + lab];
        else a += start[lab];
        if (s == 511) a += end[lab];
    }
    #pragma unroll
    for (int off = 32; off; off >>= 1) a += __shfl_xor(a, off);
    if (lane == 0) num[b] = a;
}

__global__ void crf_fwd_kernel(const float* __restrict__ emis, const float* __restrict__ start,
                               const float* __restrict__ end, const float* __restrict__ trans,
                               float* __restrict__ logZ)
{
    int b = blockIdx.x, j = threadIdx.x;      // blockDim 64
    __shared__ float sc[TT], ns[TT], tr[TT * TT];
    for (int i = j; i < TT * TT; i += 64) tr[i] = trans[i];
    if (j < TT) sc[j] = start[j] + emis[(size_t)(b * 512) * TT + j];
    __syncthreads();
    for (int s = 1; s < 512; ++s) {
        if (j < TT) {
            float mx = -__builtin_inff();
            #pragma unroll
            for (int i = 0; i < TT; ++i) mx = fmaxf(mx, sc[i] + tr[i * TT + j]);
            float sm = 0.0f;
            #pragma unroll
            for (int i = 0; i < TT; ++i) sm += expf(sc[i] + tr[i * TT + j] - mx);
            ns[j] = mx + logf(sm) + emis[(size_t)(b * 512 + s) * TT + j];
        }
        __syncthreads();
        if (j < TT) sc[j] = ns[j];
        __syncthreads();
    }
    if (j == 0) {
        float mx = -__builtin_inff();
        for (int i = 0; i < TT; ++i) mx = fmaxf(mx, sc[i] + end[i]);
        float sm = 0.0f;
        for (int i = 0; i < TT; ++i) sm += expf(sc[i] + end[i] - mx);
        logZ[b] = mx + logf(sm);
    }
}

__global__ void crf_loss_kernel(const float* __restrict__ num, const float* __restrict__ logZ,
                                float* __restrict__ out)
{
    if (threadIdx.x == 0) {
        float s = 0.0f;
        for (int b = 0; b < 16; ++b) s += num[b] - logZ[b];
        out[0] = -s / 10000.0f;
    }
}

__global__ void crf_vit_kernel(const float* __restrict__ emis, const float* __restrict__ start,
                               const float* __restrict__ end, const float* __restrict__ trans,
                               float* __restrict__ out_tags)
{
    int b = blockIdx.x, j = threadIdx.x;      // blockDim 64
    __shared__ float sc[TT], ns[TT], tr[TT * TT];
    __shared__ unsigned char hist[511][TT];
    __shared__ int path[512];
    for (int i = j; i < TT * TT; i += 64) tr[i] = trans[i];
    if (j < TT) sc[j] = start[j] + emis[(size_t)(b * 512) * TT + j];
    __syncthreads();
    for (int s = 1; s < 512; ++s) {
        if (j < TT) {
            float best = sc[0] + tr[0 * TT + j]; int arg = 0;
            #pragma unroll
            for (int i = 1; i < TT; ++i) {
                float v = sc[i] + tr[i * TT + j];
                if (v > best) { best = v; arg = i; }     // first-max wins, as np.argmax
            }
            hist[s - 1][j] = (unsigned char)arg;
            ns[j] = best + emis[(size_t)(b * 512 + s) * TT + j];
        }
        __syncthreads();
        if (j < TT) sc[j] = ns[j];
        __syncthreads();
    }
    if (j == 0) {
        float best = sc[0] + end[0]; int arg = 0;
        for (int i = 1; i < TT; ++i) {
            float v = sc[i] + end[i];
            if (v > best) { best = v; arg = i; }
        }
        int t = arg; path[511] = t;
        for (int s = 510; s >= 0; --s) { t = hist[s][t]; path[s] = t; }
        for (int s = 0; s < 512; ++s) out_tags[(size_t)b * 512 + s] = (float)path[s];
    }
}

extern "C" void kernel_launch(void* const* d_in, const int* in_sizes, int n_in,
                              void* d_out, int out_size, void* d_ws, size_t ws_size,
                              hipStream_t stream)
{
    (void)in_sizes; (void)n_in; (void)out_size; (void)ws_size;
    const int*   input_ids = (const int*)d_in[0];
    const int*   labels    = (const int*)d_in[1];
    // d_in[2] = if_crf (fixed 1 per output shapes)
    const float* emb   = (const float*)d_in[3];
    const float* in_w  = (const float*)d_in[4];
    const float* in_b  = (const float*)d_in[5];
    const float* out_w = (const float*)d_in[6];
    const float* out_b = (const float*)d_in[7];
    const float* ln1g  = (const float*)d_in[8];
    const float* ln1b  = (const float*)d_in[9];
    const float* ln2g  = (const float*)d_in[10];
    const float* ln2b  = (const float*)d_in[11];
    const float* w1    = (const float*)d_in[12];
    const float* b1    = (const float*)d_in[13];
    const float* w2    = (const float*)d_in[14];
    const float* b2    = (const float*)d_in[15];
    const float* hw    = (const float*)d_in[16];
    const float* hb    = (const float*)d_in[17];
    const float* cs    = (const float*)d_in[18];
    const float* ce    = (const float*)d_in[19];
    const float* ct    = (const float*)d_in[20];
    float* out = (float*)d_out;

    char* ws = (char*)d_ws;
    float* x    = (float*)(ws);                  // 25,165,824 B
    float* qkv  = (float*)(ws + 25165824);       // 75,497,472 B
    float* o    = (float*)(ws + 100663296);      // 25,165,824 B
    float* tmp  = (float*)(ws + 125829120);      // 25,165,824 B
    float* ff1  = qkv;                           // reuse (qkv dead after attn)
    // emis/num/logZ reuse the o region (dead after the encoder loop):
    float* emis = o;                             // 8192*32*4 = 1,048,576 B
    float* numb = o + MTOK * TT;                 // 64 B
    float* logZ = numb + 16;                     // 64 B

    embed_kernel<<<MTOK * 192 / 256, 256, 0, stream>>>(input_ids, emb, x);

    for (int l = 0; l < NL; ++l) {
        gemm_split_kernel<false><<<dim3(18, 64), 256, 0, stream>>>(
            x, in_w + (size_t)l * H3 * HD, in_b + (size_t)l * H3, qkv, H3);
        attn_kernel<<<dim3(8, 192), 256, 0, stream>>>(qkv, o);
        gemm_split_kernel<false><<<dim3(6, 64), 256, 0, stream>>>(
            o, out_w + (size_t)l * HD * HD, out_b + (size_t)l * HD, tmp, HD);
        ln_residual_kernel<<<2048, 256, 0, stream>>>(x, tmp, ln1g + l * HD, ln1b + l * HD);
        gemm_split_kernel<true><<<dim3(6, 64), 256, 0, stream>>>(
            x, w1 + (size_t)l * HD * HD, b1 + (size_t)l * HD, ff1, HD);
        gemm_split_kernel<false><<<dim3(6, 64), 256, 0, stream>>>(
            ff1, w2 + (size_t)l * HD * HD, b2 + (size_t)l * HD, tmp, HD);
        ln_residual_kernel<<<2048, 256, 0, stream>>>(x, tmp, ln2g + l * HD, ln2b + l * HD);
    }

    (void)hipMemcpyAsync(d_out, x, (size_t)MTOK * HD * sizeof(float),
                         hipMemcpyDeviceToDevice, stream);

    emis_kernel<<<2048, 256, 0, stream>>>(x, hw, hb, emis);
    crf_num_kernel<<<16, 64, 0, stream>>>(emis, labels, cs, ce, ct, numb);
    crf_fwd_kernel<<<16, 64, 0, stream>>>(emis, cs, ce, ct, logZ);
    crf_loss_kernel<<<1, 64, 0, stream>>>(numb, logZ, out + 6291456);
    crf_vit_kernel<<<16, 64, 0, stream>>>(emis, cs, ce, ct, out + 6291457);
}

// Round 4
// 5715.508 us; speedup vs baseline: 1.1765x; 1.1765x over previous
//
#include <hip/hip_runtime.h>

#define MTOK 8192      // B*S
#define HD   768
#define H3   2304
#define NL   6
#define TT   32        // number of CRF tags (reference: T = 32)

typedef __attribute__((ext_vector_type(4))) float f32x4;
typedef __attribute__((ext_vector_type(8))) short v8bf;     // 8 bf16 in 4 VGPRs
typedef __attribute__((ext_vector_type(4))) unsigned short us4;

__device__ __forceinline__ unsigned short bf16rne(float v) {
    unsigned int u = __float_as_uint(v);
    u += 0x7FFFu + ((u >> 16) & 1u);
    return (unsigned short)(u >> 16);
}
__device__ __forceinline__ float bf2f(unsigned short h) {
    return __uint_as_float(((unsigned int)h) << 16);
}
// returns hi-bf16 in low 16 bits, mid-bf16 (residual) in high 16 bits
__device__ __forceinline__ unsigned int split_pack(float v) {
    unsigned short h = bf16rne(v);
    unsigned short m = bf16rne(v - bf2f(h));
    return (unsigned int)h | ((unsigned int)m << 16);
}

// ---------------------------------------------------------------------------
// GEMM: C[M=8192][N] = A[8192][768] (f32) x W[N][768]^T (f32) + bias, opt ReLU.
// 2-term bf16 split of both operands, 4 MFMA products => ~2^-17 rel accuracy.
// BM=BN=128, BK=64; 4 waves (2x2), each 64x64 via 4x4 frags of 16x16x32.
// ---------------------------------------------------------------------------
template<bool RELU>
__global__ __launch_bounds__(256)
void gemm_split_kernel(const float* __restrict__ A, const float* __restrict__ W,
                       const float* __restrict__ bias, float* __restrict__ C, int N)
{
    __shared__ unsigned short Ah[128 * 64], Am[128 * 64], Bh[128 * 64], Bm[128 * 64];
    const int tid = threadIdx.x;
    const int lane = tid & 63, wave = tid >> 6;
    const int wm = wave >> 1, wn = wave & 1;
    const int bn = blockIdx.x, bm = blockIdx.y;
    const int g = lane >> 4, lr = lane & 15;
    f32x4 acc[4][4] = {};

    for (int kt = 0; kt < 12; ++kt) {
        __syncthreads();
        // stage A and W k-slabs: f32 -> (hi, mid) bf16, XOR-swizzled LDS
        #pragma unroll
        for (int j = 0; j < 8; ++j) {
            int fid = tid + 256 * j;
            int row = fid >> 4, c4 = fid & 15;
            int ub = row * 64 + ((((c4 >> 1) ^ (row & 7)) << 3) | ((c4 & 1) << 2));
            float4 va = *reinterpret_cast<const float4*>(A + (size_t)(bm * 128 + row) * HD + kt * 64 + c4 * 4);
            us4 hv, mv;
            unsigned int p;
            p = split_pack(va.x); hv[0] = (unsigned short)p; mv[0] = (unsigned short)(p >> 16);
            p = split_pack(va.y); hv[1] = (unsigned short)p; mv[1] = (unsigned short)(p >> 16);
            p = split_pack(va.z); hv[2] = (unsigned short)p; mv[2] = (unsigned short)(p >> 16);
            p = split_pack(va.w); hv[3] = (unsigned short)p; mv[3] = (unsigned short)(p >> 16);
            *reinterpret_cast<us4*>(&Ah[ub]) = hv;
            *reinterpret_cast<us4*>(&Am[ub]) = mv;
            float4 vb = *reinterpret_cast<const float4*>(W + (size_t)(bn * 128 + row) * HD + kt * 64 + c4 * 4);
            p = split_pack(vb.x); hv[0] = (unsigned short)p; mv[0] = (unsigned short)(p >> 16);
            p = split_pack(vb.y); hv[1] = (unsigned short)p; mv[1] = (unsigned short)(p >> 16);
            p = split_pack(vb.z); hv[2] = (unsigned short)p; mv[2] = (unsigned short)(p >> 16);
            p = split_pack(vb.w); hv[3] = (unsigned short)p; mv[3] = (unsigned short)(p >> 16);
            *reinterpret_cast<us4*>(&Bh[ub]) = hv;
            *reinterpret_cast<us4*>(&Bm[ub]) = mv;
        }
        __syncthreads();
        #pragma unroll
        for (int kk = 0; kk < 2; ++kk) {
            v8bf ah[4], am[4], bh[4], bmv[4];
            #pragma unroll
            for (int i = 0; i < 4; ++i) {
                int row = wm * 64 + i * 16 + lr;
                int ub = row * 64 + ((((kk << 2) + g) ^ (row & 7)) << 3);
                ah[i] = *reinterpret_cast<const v8bf*>(&Ah[ub]);
                am[i] = *reinterpret_cast<const v8bf*>(&Am[ub]);
            }
            #pragma unroll
            for (int i = 0; i < 4; ++i) {
                int row = wn * 64 + i * 16 + lr;
                int ub = row * 64 + ((((kk << 2) + g) ^ (row & 7)) << 3);
                bh[i]  = *reinterpret_cast<const v8bf*>(&Bh[ub]);
                bmv[i] = *reinterpret_cast<const v8bf*>(&Bm[ub]);
            }
            #pragma unroll
            for (int i = 0; i < 4; ++i)
                #pragma unroll
                for (int j = 0; j < 4; ++j) {
                    acc[i][j] = __builtin_amdgcn_mfma_f32_16x16x32_bf16(ah[i], bh[j],  acc[i][j], 0, 0, 0);
                    acc[i][j] = __builtin_amdgcn_mfma_f32_16x16x32_bf16(ah[i], bmv[j], acc[i][j], 0, 0, 0);
                    acc[i][j] = __builtin_amdgcn_mfma_f32_16x16x32_bf16(am[i], bh[j],  acc[i][j], 0, 0, 0);
                    acc[i][j] = __builtin_amdgcn_mfma_f32_16x16x32_bf16(am[i], bmv[j], acc[i][j], 0, 0, 0);
                }
        }
    }
    #pragma unroll
    for (int j = 0; j < 4; ++j) {
        int n = bn * 128 + wn * 64 + j * 16 + lr;
        float bv = bias[n];
        #pragma unroll
        for (int i = 0; i < 4; ++i) {
            int mr = bm * 128 + wm * 64 + i * 16 + 4 * g;
            #pragma unroll
            for (int r = 0; r < 4; ++r) {
                float y = acc[i][j][r] + bv;
                if (RELU) y = fmaxf(y, 0.0f);
                C[(size_t)(mr + r) * N + n] = y;
            }
        }
    }
}

// ---------------------------------------------------------------------------
// Flash-style attention. Grid: (8 q-tiles, B*NH). Block: 256 thr = 4 waves.
// ---------------------------------------------------------------------------
__global__ __launch_bounds__(256)
void attn_kernel(const float* __restrict__ qkv, float* __restrict__ o)
{
    __shared__ unsigned short Qh[64 * 64], Qm[64 * 64], Kh[64 * 64], Km[64 * 64],
                              Vh[64 * 64], Vm[64 * 64];
    __shared__ unsigned short Ph[4][16 * 64], Pm[4][16 * 64];
    const int qt = blockIdx.x;
    const int b = blockIdx.y / 12, h = blockIdx.y % 12;
    const int tid = threadIdx.x, lane = tid & 63, wave = tid >> 6;
    const int g = lane >> 4, lr = lane & 15;
    const size_t rowbase = (size_t)b * 512;

    // Q tile (64 rows x 64 d), split + swizzle into LDS
    #pragma unroll
    for (int e = 0; e < 16; ++e) {
        int idx = e * 256 + tid;
        int r = idx >> 6, d = idx & 63;
        float v = qkv[(rowbase + qt * 64 + r) * H3 + h * 64 + d];
        unsigned int pk = split_pack(v);
        int ub = r * 64 + ((((d >> 3) ^ (r & 7)) << 3) | (d & 7));
        Qh[ub] = (unsigned short)pk; Qm[ub] = (unsigned short)(pk >> 16);
    }

    float m_run[4] = {-__builtin_inff(), -__builtin_inff(), -__builtin_inff(), -__builtin_inff()};
    float l_run[4] = {};
    f32x4 O[4] = {};

    for (int kt = 0; kt < 8; ++kt) {
        __syncthreads();
        // stage K (row=kpos, d-contig) and V transposed (row=d, k-contig)
        #pragma unroll
        for (int e = 0; e < 16; ++e) {
            int idx = e * 256 + tid;
            int r = idx >> 6, d = idx & 63;
            size_t tok = (rowbase + kt * 64 + r) * H3 + h * 64 + d;
            unsigned int pk = split_pack(qkv[tok + 768]);
            int ubk = r * 64 + ((((d >> 3) ^ (r & 7)) << 3) | (d & 7));
            Kh[ubk] = (unsigned short)pk; Km[ubk] = (unsigned short)(pk >> 16);
            pk = split_pack(qkv[tok + 1536]);
            int ubv = d * 64 + ((((r >> 3) ^ (d & 7)) << 3) | (r & 7));
            Vh[ubv] = (unsigned short)pk; Vm[ubv] = (unsigned short)(pk >> 16);
        }
        __syncthreads();

        // S = Q K^T (3 products: hh, hm, mh)
        f32x4 s[4] = {};
        #pragma unroll
        for (int kk = 0; kk < 2; ++kk) {
            int qrow = wave * 16 + lr;
            int uq = qrow * 64 + ((((kk << 2) + g) ^ (qrow & 7)) << 3);
            v8bf aqh = *reinterpret_cast<const v8bf*>(&Qh[uq]);
            v8bf aqm = *reinterpret_cast<const v8bf*>(&Qm[uq]);
            #pragma unroll
            for (int j = 0; j < 4; ++j) {
                int krow = j * 16 + lr;
                int uk = krow * 64 + ((((kk << 2) + g) ^ (krow & 7)) << 3);
                v8bf bkh = *reinterpret_cast<const v8bf*>(&Kh[uk]);
                v8bf bkm = *reinterpret_cast<const v8bf*>(&Km[uk]);
                s[j] = __builtin_amdgcn_mfma_f32_16x16x32_bf16(aqh, bkh, s[j], 0, 0, 0);
                s[j] = __builtin_amdgcn_mfma_f32_16x16x32_bf16(aqh, bkm, s[j], 0, 0, 0);
                s[j] = __builtin_amdgcn_mfma_f32_16x16x32_bf16(aqm, bkh, s[j], 0, 0, 0);
            }
        }
        // online softmax per row (row = 4*g + rr, lane-group = 16 lanes)
        float mnew[4], alpha[4], rsum[4];
        #pragma unroll
        for (int rr = 0; rr < 4; ++rr) {
            float t = fmaxf(fmaxf(s[0][rr], s[1][rr]), fmaxf(s[2][rr], s[3][rr])) * 0.125f;
            #pragma unroll
            for (int off = 1; off < 16; off <<= 1) t = fmaxf(t, __shfl_xor(t, off));
            mnew[rr] = fmaxf(m_run[rr], t);
            alpha[rr] = __expf(m_run[rr] - mnew[rr]);
            m_run[rr] = mnew[rr];
            rsum[rr] = 0.0f;
        }
        #pragma unroll
        for (int j = 0; j < 4; ++j) {
            #pragma unroll
            for (int rr = 0; rr < 4; ++rr) {
                float p = __expf(s[j][rr] * 0.125f - mnew[rr]);
                rsum[rr] += p;
                int prow = 4 * g + rr;
                int ub = prow * 64 + ((((j * 2 + (lr >> 3)) ^ (prow & 7)) << 3) | (lr & 7));
                unsigned int pk = split_pack(p);
                Ph[wave][ub] = (unsigned short)pk; Pm[wave][ub] = (unsigned short)(pk >> 16);
            }
        }
        #pragma unroll
        for (int rr = 0; rr < 4; ++rr) {
            float t = rsum[rr];
            #pragma unroll
            for (int off = 1; off < 16; off <<= 1) t += __shfl_xor(t, off);
            l_run[rr] = l_run[rr] * alpha[rr] + t;
            O[0][rr] *= alpha[rr]; O[1][rr] *= alpha[rr];
            O[2][rr] *= alpha[rr]; O[3][rr] *= alpha[rr];
        }
        // O += P V  (3 products)
        #pragma unroll
        for (int kk = 0; kk < 2; ++kk) {
            int up = lr * 64 + ((((kk << 2) + g) ^ (lr & 7)) << 3);
            v8bf aph = *reinterpret_cast<const v8bf*>(&Ph[wave][up]);
            v8bf apm = *reinterpret_cast<const v8bf*>(&Pm[wave][up]);
            #pragma unroll
            for (int j = 0; j < 4; ++j) {
                int vrow = j * 16 + lr;
                int uv = vrow * 64 + ((((kk << 2) + g) ^ (vrow & 7)) << 3);
                v8bf bvh = *reinterpret_cast<const v8bf*>(&Vh[uv]);
                v8bf bvm = *reinterpret_cast<const v8bf*>(&Vm[uv]);
                O[j] = __builtin_amdgcn_mfma_f32_16x16x32_bf16(aph, bvh, O[j], 0, 0, 0);
                O[j] = __builtin_amdgcn_mfma_f32_16x16x32_bf16(aph, bvm, O[j], 0, 0, 0);
                O[j] = __builtin_amdgcn_mfma_f32_16x16x32_bf16(apm, bvh, O[j], 0, 0, 0);
            }
        }
    }
    #pragma unroll
    for (int j = 0; j < 4; ++j) {
        int d = j * 16 + lr;
        #pragma unroll
        for (int rr = 0; rr < 4; ++rr) {
            size_t tok = rowbase + qt * 64 + wave * 16 + 4 * g + rr;
            o[tok * HD + h * 64 + d] = O[j][rr] / l_run[rr];
        }
    }
}

// ---------------------------------------------------------------------------
// x = LayerNorm(x + t) * g + b, one wave per token (768 = 12 per lane)
// ---------------------------------------------------------------------------
__global__ __launch_bounds__(256)
void ln_residual_kernel(float* __restrict__ x, const float* __restrict__ t,
                        const float* __restrict__ gamma, const float* __restrict__ beta)
{
    int tok = blockIdx.x * 4 + (threadIdx.x >> 6);
    int lane = threadIdx.x & 63;
    float v[12];
    float s = 0.0f;
    #pragma unroll
    for (int j = 0; j < 12; ++j) {
        int c = j * 64 + lane;
        v[j] = x[(size_t)tok * HD + c] + t[(size_t)tok * HD + c];
        s += v[j];
    }
    #pragma unroll
    for (int off = 32; off; off >>= 1) s += __shfl_xor(s, off);
    float mean = s * (1.0f / 768.0f);
    float vs = 0.0f;
    #pragma unroll
    for (int j = 0; j < 12; ++j) { float d = v[j] - mean; vs += d * d; }
    #pragma unroll
    for (int off = 32; off; off >>= 1) vs += __shfl_xor(vs, off);
    float rstd = rsqrtf(vs * (1.0f / 768.0f) + 1e-5f);
    #pragma unroll
    for (int j = 0; j < 12; ++j) {
        int c = j * 64 + lane;
        x[(size_t)tok * HD + c] = (v[j] - mean) * rstd * gamma[c] + beta[c];
    }
}

__global__ __launch_bounds__(256)
void embed_kernel(const int* __restrict__ ids, const float* __restrict__ emb,
                  float* __restrict__ x)
{
    int f4 = blockIdx.x * 256 + threadIdx.x;     // 8192*192 float4
    int tok = f4 / 192, c = f4 % 192;
    float4 v = *reinterpret_cast<const float4*>(emb + (size_t)ids[tok] * HD + c * 4);
    *reinterpret_cast<float4*>(x + (size_t)tok * HD + c * 4) = v;
}

// emis[tok][t] = dot768(x[tok], head_w[t]) + head_b[t] — wave per token, f32
__global__ __launch_bounds__(256)
void emis_kernel(const float* __restrict__ x, const float* __restrict__ hw,
                 const float* __restrict__ hb, float* __restrict__ emis)
{
    int tok = blockIdx.x * 4 + (threadIdx.x >> 6);
    int lane = threadIdx.x & 63;
    float xv[12];
    #pragma unroll
    for (int j = 0; j < 12; ++j) xv[j] = x[(size_t)tok * HD + j * 64 + lane];
    for (int t = 0; t < TT; ++t) {
        float a = 0.0f;
        #pragma unroll
        for (int j = 0; j < 12; ++j) a += xv[j] * hw[t * HD + j * 64 + lane];
        #pragma unroll
        for (int off = 32; off; off >>= 1) a += __shfl_xor(a, off);
        if (lane == 0) emis[(size_t)tok * TT + t] = a + hb[t];
    }
}

__global__ void crf_num_kernel(const float* __restrict__ emis, const int* __restrict__ labels,
                               const float* __restrict__ start, const float* __restrict__ end,
                               const float* __restrict__ trans, float* __restrict__ num)
{
    int b = blockIdx.x, lane = threadIdx.x;   // blockDim 64
    float a = 0.0f;
    for (int s = lane; s < 512; s += 64) {
        int lab = labels[b * 512 + s];
        a += emis[(size_t)(b * 512 + s) * TT + lab];
        if (s > 0) a += trans[labels[b * 512 + s - 1] * TT + lab];
        else a += start[lab];
        if (s == 511) a += end[lab];
    }
    #pragma unroll
    for (int off = 32; off; off >>= 1) a += __shfl_xor(a, off);
    if (lane == 0) num[b] = a;
}

// ---------------------------------------------------------------------------
// Fused CRF forward + viterbi. Grid 32 blocks x 64 threads (1 wave each).
// blocks 0..15: forward logZ for batch b. blocks 16..31: viterbi for b-16.
// Lane (h,j): h = lane>>5 picks i-half, j = lane&31 = destination state.
// Forward: ns_j = r + log(sum_i exp(sc_i - r) * E_ij), E = exp(trans) in regs.
// ---------------------------------------------------------------------------
__global__ __launch_bounds__(64)
void crf_path_kernel(const float* __restrict__ emis, const float* __restrict__ start,
                     const float* __restrict__ end, const float* __restrict__ trans,
                     float* __restrict__ logZ, float* __restrict__ out_tags)
{
    const int mode = blockIdx.x >> 4;          // 0 = forward, 1 = viterbi
    const int b = blockIdx.x & 15;
    const int lane = threadIdx.x;
    const int j = lane & 31;
    const int h = lane >> 5;
    const int hbase = h << 4;                  // 0 or 16
    __shared__ unsigned char hist[511][32];
    __shared__ float sval[32];
    __shared__ int path[512];

    const float* eb = emis + (size_t)b * 512 * TT;

    if (mode == 0) {
        float Ecol[16];
        #pragma unroll
        for (int ii = 0; ii < 16; ++ii) Ecol[ii] = __expf(trans[(hbase + ii) * TT + j]);
        float sc = start[j] + eb[j];
        for (int s = 1; s < 512; ++s) {
            float r = __shfl(sc, 0);           // uniform shift (exact in the identity)
            float p = __expf(sc - r);
            float dot = 0.0f;
            #pragma unroll
            for (int ii = 0; ii < 16; ++ii)
                dot = fmaf(__shfl(p, hbase + ii), Ecol[ii], dot);
            dot += __shfl_xor(dot, 32);        // combine i-halves
            sc = r + __logf(dot) + eb[s * TT + j];
        }
        float v = sc + end[j];
        float mx = v;
        #pragma unroll
        for (int off = 1; off < 32; off <<= 1) mx = fmaxf(mx, __shfl_xor(mx, off));
        float p = __expf(v - mx);
        float sm = p;
        #pragma unroll
        for (int off = 1; off < 32; off <<= 1) sm += __shfl_xor(sm, off);
        if (lane == 0) logZ[b] = mx + __logf(sm);
    } else {
        float tcol[16];
        #pragma unroll
        for (int ii = 0; ii < 16; ++ii) tcol[ii] = trans[(hbase + ii) * TT + j];
        float sc = start[j] + eb[j];
        for (int s = 1; s < 512; ++s) {
            float best = __shfl(sc, hbase) + tcol[0];
            int arg = hbase;
            #pragma unroll
            for (int ii = 1; ii < 16; ++ii) {
                float c = __shfl(sc, hbase + ii) + tcol[ii];
                if (c > best) { best = c; arg = hbase + ii; }   // first-max in half
            }
            float vo = __shfl_xor(best, 32);
            int   ao = __shfl_xor(arg, 32);
            // first-max across halves: lower i wins ties
            bool take = h ? !(best > vo) : (vo > best);
            if (take) { best = vo; arg = ao; }
            if (h == 0) hist[s - 1][j] = (unsigned char)arg;
            sc = best + eb[s * TT + j];
        }
        if (h == 0) sval[j] = sc + end[j];
        __syncthreads();
        if (lane == 0) {
            float best = sval[0]; int arg = 0;
            for (int i = 1; i < TT; ++i)
                if (sval[i] > best) { best = sval[i]; arg = i; }
            int t = arg; path[511] = t;
            for (int s = 510; s >= 0; --s) { t = hist[s][t]; path[s] = t; }
        }
        __syncthreads();
        for (int s = lane; s < 512; s += 64)
            out_tags[(size_t)b * 512 + s] = (float)path[s];
    }
}

__global__ void crf_loss_kernel(const float* __restrict__ num, const float* __restrict__ logZ,
                                float* __restrict__ out)
{
    if (threadIdx.x == 0) {
        float s = 0.0f;
        for (int b = 0; b < 16; ++b) s += num[b] - logZ[b];
        out[0] = -s / 10000.0f;
    }
}

extern "C" void kernel_launch(void* const* d_in, const int* in_sizes, int n_in,
                              void* d_out, int out_size, void* d_ws, size_t ws_size,
                              hipStream_t stream)
{
    (void)in_sizes; (void)n_in; (void)out_size; (void)ws_size;
    const int*   input_ids = (const int*)d_in[0];
    const int*   labels    = (const int*)d_in[1];
    // d_in[2] = if_crf (fixed 1 per output shapes)
    const float* emb   = (const float*)d_in[3];
    const float* in_w  = (const float*)d_in[4];
    const float* in_b  = (const float*)d_in[5];
    const float* out_w = (const float*)d_in[6];
    const float* out_b = (const float*)d_in[7];
    const float* ln1g  = (const float*)d_in[8];
    const float* ln1b  = (const float*)d_in[9];
    const float* ln2g  = (const float*)d_in[10];
    const float* ln2b  = (const float*)d_in[11];
    const float* w1    = (const float*)d_in[12];
    const float* b1    = (const float*)d_in[13];
    const float* w2    = (const float*)d_in[14];
    const float* b2    = (const float*)d_in[15];
    const float* hw    = (const float*)d_in[16];
    const float* hb    = (const float*)d_in[17];
    const float* cs    = (const float*)d_in[18];
    const float* ce    = (const float*)d_in[19];
    const float* ct    = (const float*)d_in[20];
    float* out = (float*)d_out;

    char* ws = (char*)d_ws;
    float* x    = (float*)(ws);                  // 25,165,824 B
    float* qkv  = (float*)(ws + 25165824);       // 75,497,472 B
    float* o    = (float*)(ws + 100663296);      // 25,165,824 B
    float* tmp  = (float*)(ws + 125829120);      // 25,165,824 B
    float* ff1  = qkv;                           // reuse (qkv dead after attn)
    // emis/num/logZ reuse the o region (dead after the encoder loop):
    float* emis = o;                             // 8192*32*4 = 1,048,576 B
    float* numb = o + MTOK * TT;                 // 64 B
    float* logZ = numb + 16;                     // 64 B

    embed_kernel<<<MTOK * 192 / 256, 256, 0, stream>>>(input_ids, emb, x);

    for (int l = 0; l < NL; ++l) {
        gemm_split_kernel<false><<<dim3(18, 64), 256, 0, stream>>>(
            x, in_w + (size_t)l * H3 * HD, in_b + (size_t)l * H3, qkv, H3);
        attn_kernel<<<dim3(8, 192), 256, 0, stream>>>(qkv, o);
        gemm_split_kernel<false><<<dim3(6, 64), 256, 0, stream>>>(
            o, out_w + (size_t)l * HD * HD, out_b + (size_t)l * HD, tmp, HD);
        ln_residual_kernel<<<2048, 256, 0, stream>>>(x, tmp, ln1g + l * HD, ln1b + l * HD);
        gemm_split_kernel<true><<<dim3(6, 64), 256, 0, stream>>>(
            x, w1 + (size_t)l * HD * HD, b1 + (size_t)l * HD, ff1, HD);
        gemm_split_kernel<false><<<dim3(6, 64), 256, 0, stream>>>(
            ff1, w2 + (size_t)l * HD * HD, b2 + (size_t)l * HD, tmp, HD);
        ln_residual_kernel<<<2048, 256, 0, stream>>>(x, tmp, ln2g + l * HD, ln2b + l * HD);
    }

    (void)hipMemcpyAsync(d_out, x, (size_t)MTOK * HD * sizeof(float),
                         hipMemcpyDeviceToDevice, stream);

    emis_kernel<<<2048, 256, 0, stream>>>(x, hw, hb, emis);
    crf_num_kernel<<<16, 64, 0, stream>>>(emis, labels, cs, ce, ct, numb);
    crf_path_kernel<<<32, 64, 0, stream>>>(emis, cs, ce, ct, logZ, out + 6291457);
    crf_loss_kernel<<<1, 64, 0, stream>>>(numb, logZ, out + 6291456);
}

// Round 5
// 4807.768 us; speedup vs baseline: 1.3986x; 1.1888x over previous
//
#include <hip/hip_runtime.h>

#define MTOK 8192      // B*S
#define HD   768
#define H3   2304
#define NL   6
#define TT   32        // CRF tags (reference: T = 32)

typedef __attribute__((ext_vector_type(4))) float f32x4;
typedef __attribute__((ext_vector_type(8))) short v8bf;     // 8 bf16 in 4 VGPRs
typedef __attribute__((ext_vector_type(4))) unsigned short us4;

__device__ __forceinline__ unsigned short bf16rne(float v) {
    unsigned int u = __float_as_uint(v);
    u += 0x7FFFu + ((u >> 16) & 1u);
    return (unsigned short)(u >> 16);
}
__device__ __forceinline__ float bf2f(unsigned short h) {
    return __uint_as_float(((unsigned int)h) << 16);
}
// hi bf16 in low 16 bits, mid (residual) bf16 in high 16 bits
__device__ __forceinline__ unsigned int split_pack(float v) {
    unsigned short h = bf16rne(v);
    unsigned short m = bf16rne(v - bf2f(h));
    return (unsigned int)h | ((unsigned int)m << 16);
}

// async global->LDS, 16B per lane, LDS dest = wave-uniform base + lane*16
__device__ __forceinline__ void gload16(const unsigned short* g, unsigned short* l) {
    __builtin_amdgcn_global_load_lds(
        (const __attribute__((address_space(1))) unsigned int*)g,
        (__attribute__((address_space(3))) unsigned int*)l, 16, 0, 0);
}

// ---------------------------------------------------------------------------
// Weight split: f32 -> (hi, mid) bf16 arrays. 4 elems/thread.
// ---------------------------------------------------------------------------
__global__ __launch_bounds__(256)
void wsplit_kernel(const float* __restrict__ src, unsigned short* __restrict__ h,
                   unsigned short* __restrict__ m, int n4)
{
    int i = blockIdx.x * 256 + threadIdx.x;
    if (i >= n4) return;
    float4 v = reinterpret_cast<const float4*>(src)[i];
    us4 hv, mv; unsigned int p;
    p = split_pack(v.x); hv[0] = (unsigned short)p; mv[0] = (unsigned short)(p >> 16);
    p = split_pack(v.y); hv[1] = (unsigned short)p; mv[1] = (unsigned short)(p >> 16);
    p = split_pack(v.z); hv[2] = (unsigned short)p; mv[2] = (unsigned short)(p >> 16);
    p = split_pack(v.w); hv[3] = (unsigned short)p; mv[3] = (unsigned short)(p >> 16);
    reinterpret_cast<us4*>(h)[i] = hv;
    reinterpret_cast<us4*>(m)[i] = mv;
}

// ---------------------------------------------------------------------------
// GEMM on pre-split operands: C = A x W^T + bias. A: [M][768] (hi,mid ushort),
// W: [N][768] (hi,mid). BM=BN=128, BK=64; 4 waves (2x2), 64x64 each.
// Staging via global_load_lds: linear LDS dest, pre-swizzled global source,
// XOR-swizzled ds_read (chunk ^ (row&7)).
// ---------------------------------------------------------------------------
template<bool RELU, bool SPLITOUT>
__global__ __launch_bounds__(256)
void gemm_pair_kernel(const unsigned short* __restrict__ Ahg, const unsigned short* __restrict__ Amg,
                      const unsigned short* __restrict__ Bhg, const unsigned short* __restrict__ Bmg,
                      const float* __restrict__ bias, float* __restrict__ Cf,
                      unsigned short* __restrict__ Ch, unsigned short* __restrict__ Cm, int N)
{
    __shared__ unsigned short lds[4][128 * 64];   // Ah, Am, Bh, Bm tiles (64 KB)
    const int tid = threadIdx.x;
    const int lane = tid & 63, wave = tid >> 6;
    const int wm = wave >> 1, wn = wave & 1;
    const int bn = blockIdx.x, bm = blockIdx.y;
    const int g = lane >> 4, lr = lane & 15;

    // staging geometry: lane -> (row = wave*32 + i*8 + (lane>>3), chunk = lane&7)
    const int srow = lane >> 3;
    const int schunk = ((lane & 7) ^ srow) * 8;   // pre-swizzled source chunk (shorts)
    const size_t aoff = ((size_t)(bm * 128 + wave * 32 + srow)) * HD + schunk;
    const size_t boff = ((size_t)(bn * 128 + wave * 32 + srow)) * HD + schunk;

    f32x4 acc[4][4] = {};

    for (int kt = 0; kt < 12; ++kt) {
        __syncthreads();
        const int k64 = kt * 64;
        #pragma unroll
        for (int i = 0; i < 4; ++i) {
            const size_t ra = aoff + (size_t)i * 8 * HD + k64;
            const size_t rb = boff + (size_t)i * 8 * HD + k64;
            unsigned short* lb = (unsigned short*)&lds[0][(wave * 32 + i * 8) * 64];
            gload16(Ahg + ra, lb);
            gload16(Amg + ra, lb + 8192);
            gload16(Bhg + rb, lb + 16384);
            gload16(Bmg + rb, lb + 24576);
        }
        __syncthreads();
        #pragma unroll
        for (int kk = 0; kk < 2; ++kk) {
            v8bf ah[4], am[4], bh[4], bmv[4];
            #pragma unroll
            for (int i = 0; i < 4; ++i) {
                int row = wm * 64 + i * 16 + lr;
                int ub = row * 64 + ((((kk << 2) + g) ^ (row & 7)) << 3);
                ah[i] = *reinterpret_cast<const v8bf*>(&lds[0][ub]);
                am[i] = *reinterpret_cast<const v8bf*>(&lds[1][ub]);
            }
            #pragma unroll
            for (int i = 0; i < 4; ++i) {
                int row = wn * 64 + i * 16 + lr;
                int ub = row * 64 + ((((kk << 2) + g) ^ (row & 7)) << 3);
                bh[i]  = *reinterpret_cast<const v8bf*>(&lds[2][ub]);
                bmv[i] = *reinterpret_cast<const v8bf*>(&lds[3][ub]);
            }
            #pragma unroll
            for (int i = 0; i < 4; ++i)
                #pragma unroll
                for (int j = 0; j < 4; ++j) {
                    acc[i][j] = __builtin_amdgcn_mfma_f32_16x16x32_bf16(ah[i], bh[j],  acc[i][j], 0, 0, 0);
                    acc[i][j] = __builtin_amdgcn_mfma_f32_16x16x32_bf16(ah[i], bmv[j], acc[i][j], 0, 0, 0);
                    acc[i][j] = __builtin_amdgcn_mfma_f32_16x16x32_bf16(am[i], bh[j],  acc[i][j], 0, 0, 0);
                    acc[i][j] = __builtin_amdgcn_mfma_f32_16x16x32_bf16(am[i], bmv[j], acc[i][j], 0, 0, 0);
                }
        }
    }
    #pragma unroll
    for (int j = 0; j < 4; ++j) {
        int n = bn * 128 + wn * 64 + j * 16 + lr;
        float bv = bias[n];
        #pragma unroll
        for (int i = 0; i < 4; ++i) {
            int mr = bm * 128 + wm * 64 + i * 16 + 4 * g;
            #pragma unroll
            for (int r = 0; r < 4; ++r) {
                float y = acc[i][j][r] + bv;
                if (RELU) y = fmaxf(y, 0.0f);
                size_t idx = (size_t)(mr + r) * N + n;
                if (SPLITOUT) {
                    unsigned int pk = split_pack(y);
                    Ch[idx] = (unsigned short)pk;
                    Cm[idx] = (unsigned short)(pk >> 16);
                } else {
                    Cf[idx] = y;
                }
            }
        }
    }
}

// ---------------------------------------------------------------------------
// Flash-style attention on pre-split qkv. Grid: (8 q-tiles, B*NH), 4 waves.
// ---------------------------------------------------------------------------
__global__ __launch_bounds__(256)
void attn_kernel(const unsigned short* __restrict__ qh, const unsigned short* __restrict__ qm,
                 unsigned short* __restrict__ ohp, unsigned short* __restrict__ omp)
{
    __shared__ unsigned short Qh[64 * 64], Qm[64 * 64], Kh[64 * 64], Km[64 * 64],
                              Vh[64 * 64], Vm[64 * 64];
    __shared__ unsigned short Ph[4][16 * 64], Pm[4][16 * 64];
    const int qt = blockIdx.x;
    const int b = blockIdx.y / 12, h = blockIdx.y % 12;
    const int tid = threadIdx.x, lane = tid & 63, wave = tid >> 6;
    const int g = lane >> 4, lr = lane & 15;
    const size_t rowbase = (size_t)b * 512;

    #pragma unroll
    for (int e = 0; e < 16; ++e) {
        int idx = e * 256 + tid;
        int r = idx >> 6, d = idx & 63;
        size_t t = (rowbase + qt * 64 + r) * H3 + h * 64 + d;
        int ub = r * 64 + ((((d >> 3) ^ (r & 7)) << 3) | (d & 7));
        Qh[ub] = qh[t]; Qm[ub] = qm[t];
    }

    float m_run[4] = {-__builtin_inff(), -__builtin_inff(), -__builtin_inff(), -__builtin_inff()};
    float l_run[4] = {};
    f32x4 O[4] = {};

    for (int kt = 0; kt < 8; ++kt) {
        __syncthreads();
        #pragma unroll
        for (int e = 0; e < 16; ++e) {
            int idx = e * 256 + tid;
            int r = idx >> 6, d = idx & 63;
            size_t t = (rowbase + kt * 64 + r) * H3 + h * 64 + d;
            int ubk = r * 64 + ((((d >> 3) ^ (r & 7)) << 3) | (d & 7));
            Kh[ubk] = qh[t + 768]; Km[ubk] = qm[t + 768];
            int ubv = d * 64 + ((((r >> 3) ^ (d & 7)) << 3) | (r & 7));
            Vh[ubv] = qh[t + 1536]; Vm[ubv] = qm[t + 1536];
        }
        __syncthreads();

        // S = Q K^T (3 products)
        f32x4 s[4] = {};
        #pragma unroll
        for (int kk = 0; kk < 2; ++kk) {
            int qrow = wave * 16 + lr;
            int uq = qrow * 64 + ((((kk << 2) + g) ^ (qrow & 7)) << 3);
            v8bf aqh = *reinterpret_cast<const v8bf*>(&Qh[uq]);
            v8bf aqm = *reinterpret_cast<const v8bf*>(&Qm[uq]);
            #pragma unroll
            for (int j = 0; j < 4; ++j) {
                int krow = j * 16 + lr;
                int uk = krow * 64 + ((((kk << 2) + g) ^ (krow & 7)) << 3);
                v8bf bkh = *reinterpret_cast<const v8bf*>(&Kh[uk]);
                v8bf bkm = *reinterpret_cast<const v8bf*>(&Km[uk]);
                s[j] = __builtin_amdgcn_mfma_f32_16x16x32_bf16(aqh, bkh, s[j], 0, 0, 0);
                s[j] = __builtin_amdgcn_mfma_f32_16x16x32_bf16(aqh, bkm, s[j], 0, 0, 0);
                s[j] = __builtin_amdgcn_mfma_f32_16x16x32_bf16(aqm, bkh, s[j], 0, 0, 0);
            }
        }
        float mnew[4], alpha[4], rsum[4];
        #pragma unroll
        for (int rr = 0; rr < 4; ++rr) {
            float t = fmaxf(fmaxf(s[0][rr], s[1][rr]), fmaxf(s[2][rr], s[3][rr])) * 0.125f;
            #pragma unroll
            for (int off = 1; off < 16; off <<= 1) t = fmaxf(t, __shfl_xor(t, off));
            mnew[rr] = fmaxf(m_run[rr], t);
            alpha[rr] = __expf(m_run[rr] - mnew[rr]);
            m_run[rr] = mnew[rr];
            rsum[rr] = 0.0f;
        }
        #pragma unroll
        for (int j = 0; j < 4; ++j) {
            #pragma unroll
            for (int rr = 0; rr < 4; ++rr) {
                float p = __expf(s[j][rr] * 0.125f - mnew[rr]);
                rsum[rr] += p;
                int prow = 4 * g + rr;
                int ub = prow * 64 + ((((j * 2 + (lr >> 3)) ^ (prow & 7)) << 3) | (lr & 7));
                unsigned int pk = split_pack(p);
                Ph[wave][ub] = (unsigned short)pk; Pm[wave][ub] = (unsigned short)(pk >> 16);
            }
        }
        #pragma unroll
        for (int rr = 0; rr < 4; ++rr) {
            float t = rsum[rr];
            #pragma unroll
            for (int off = 1; off < 16; off <<= 1) t += __shfl_xor(t, off);
            l_run[rr] = l_run[rr] * alpha[rr] + t;
            O[0][rr] *= alpha[rr]; O[1][rr] *= alpha[rr];
            O[2][rr] *= alpha[rr]; O[3][rr] *= alpha[rr];
        }
        #pragma unroll
        for (int kk = 0; kk < 2; ++kk) {
            int up = lr * 64 + ((((kk << 2) + g) ^ (lr & 7)) << 3);
            v8bf aph = *reinterpret_cast<const v8bf*>(&Ph[wave][up]);
            v8bf apm = *reinterpret_cast<const v8bf*>(&Pm[wave][up]);
            #pragma unroll
            for (int j = 0; j < 4; ++j) {
                int vrow = j * 16 + lr;
                int uv = vrow * 64 + ((((kk << 2) + g) ^ (vrow & 7)) << 3);
                v8bf bvh = *reinterpret_cast<const v8bf*>(&Vh[uv]);
                v8bf bvm = *reinterpret_cast<const v8bf*>(&Vm[uv]);
                O[j] = __builtin_amdgcn_mfma_f32_16x16x32_bf16(aph, bvh, O[j], 0, 0, 0);
                O[j] = __builtin_amdgcn_mfma_f32_16x16x32_bf16(aph, bvm, O[j], 0, 0, 0);
                O[j] = __builtin_amdgcn_mfma_f32_16x16x32_bf16(apm, bvh, O[j], 0, 0, 0);
            }
        }
    }
    #pragma unroll
    for (int j = 0; j < 4; ++j) {
        int d = j * 16 + lr;
        #pragma unroll
        for (int rr = 0; rr < 4; ++rr) {
            size_t tok = rowbase + qt * 64 + wave * 16 + 4 * g + rr;
            unsigned int pk = split_pack(O[j][rr] / l_run[rr]);
            ohp[tok * HD + h * 64 + d] = (unsigned short)pk;
            omp[tok * HD + h * 64 + d] = (unsigned short)(pk >> 16);
        }
    }
}

// ---------------------------------------------------------------------------
// x = LayerNorm((xh+xm) + t) * g + b -> (xh, xm). One wave per token.
// ---------------------------------------------------------------------------
__global__ __launch_bounds__(256)
void ln_residual_kernel(unsigned short* __restrict__ xh, unsigned short* __restrict__ xm,
                        const float* __restrict__ t,
                        const float* __restrict__ gamma, const float* __restrict__ beta)
{
    int tok = blockIdx.x * 4 + (threadIdx.x >> 6);
    int lane = threadIdx.x & 63;
    float v[12];
    float s = 0.0f;
    #pragma unroll
    for (int j = 0; j < 12; ++j) {
        size_t c = (size_t)tok * HD + j * 64 + lane;
        v[j] = bf2f(xh[c]) + bf2f(xm[c]) + t[c];
        s += v[j];
    }
    #pragma unroll
    for (int off = 32; off; off >>= 1) s += __shfl_xor(s, off);
    float mean = s * (1.0f / 768.0f);
    float vs = 0.0f;
    #pragma unroll
    for (int j = 0; j < 12; ++j) { float d = v[j] - mean; vs += d * d; }
    #pragma unroll
    for (int off = 32; off; off >>= 1) vs += __shfl_xor(vs, off);
    float rstd = rsqrtf(vs * (1.0f / 768.0f) + 1e-5f);
    #pragma unroll
    for (int j = 0; j < 12; ++j) {
        size_t c = (size_t)tok * HD + j * 64 + lane;
        float y = (v[j] - mean) * rstd * gamma[j * 64 + lane] + beta[j * 64 + lane];
        unsigned int pk = split_pack(y);
        xh[c] = (unsigned short)pk; xm[c] = (unsigned short)(pk >> 16);
    }
}

__global__ __launch_bounds__(256)
void embed_kernel(const int* __restrict__ ids, const float* __restrict__ emb,
                  unsigned short* __restrict__ xh, unsigned short* __restrict__ xm)
{
    int f4 = blockIdx.x * 256 + threadIdx.x;     // 8192*192 float4
    int tok = f4 / 192, c = f4 % 192;
    float4 v = *reinterpret_cast<const float4*>(emb + (size_t)ids[tok] * HD + c * 4);
    us4 hv, mv; unsigned int p;
    p = split_pack(v.x); hv[0] = (unsigned short)p; mv[0] = (unsigned short)(p >> 16);
    p = split_pack(v.y); hv[1] = (unsigned short)p; mv[1] = (unsigned short)(p >> 16);
    p = split_pack(v.z); hv[2] = (unsigned short)p; mv[2] = (unsigned short)(p >> 16);
    p = split_pack(v.w); hv[3] = (unsigned short)p; mv[3] = (unsigned short)(p >> 16);
    *reinterpret_cast<us4*>(&xh[(size_t)tok * HD + c * 4]) = hv;
    *reinterpret_cast<us4*>(&xm[(size_t)tok * HD + c * 4]) = mv;
}

// logits f32 = xh + xm
__global__ __launch_bounds__(256)
void out_logits_kernel(const unsigned short* __restrict__ xh, const unsigned short* __restrict__ xm,
                       float* __restrict__ out)
{
    int i = blockIdx.x * 256 + threadIdx.x;      // 8192*192 groups of 4
    us4 hv = reinterpret_cast<const us4*>(xh)[i];
    us4 mv = reinterpret_cast<const us4*>(xm)[i];
    float4 o;
    o.x = bf2f(hv[0]) + bf2f(mv[0]);
    o.y = bf2f(hv[1]) + bf2f(mv[1]);
    o.z = bf2f(hv[2]) + bf2f(mv[2]);
    o.w = bf2f(hv[3]) + bf2f(mv[3]);
    reinterpret_cast<float4*>(out)[i] = o;
}

// emis[tok][t] = dot768(x[tok], head_w[t]) + head_b[t] — wave per token
__global__ __launch_bounds__(256)
void emis_kernel(const unsigned short* __restrict__ xh, const unsigned short* __restrict__ xm,
                 const float* __restrict__ hw, const float* __restrict__ hb,
                 float* __restrict__ emis)
{
    int tok = blockIdx.x * 4 + (threadIdx.x >> 6);
    int lane = threadIdx.x & 63;
    float xv[12];
    #pragma unroll
    for (int j = 0; j < 12; ++j) {
        size_t c = (size_t)tok * HD + j * 64 + lane;
        xv[j] = bf2f(xh[c]) + bf2f(xm[c]);
    }
    for (int t = 0; t < TT; ++t) {
        float a = 0.0f;
        #pragma unroll
        for (int j = 0; j < 12; ++j) a += xv[j] * hw[t * HD + j * 64 + lane];
        #pragma unroll
        for (int off = 32; off; off >>= 1) a += __shfl_xor(a, off);
        if (lane == 0) emis[(size_t)tok * TT + t] = a + hb[t];
    }
}

__global__ void crf_num_kernel(const float* __restrict__ emis, const int* __restrict__ labels,
                               const float* __restrict__ start, const float* __restrict__ end,
                               const float* __restrict__ trans, float* __restrict__ num)
{
    int b = blockIdx.x, lane = threadIdx.x;   // blockDim 64
    float a = 0.0f;
    for (int s = lane; s < 512; s += 64) {
        int lab = labels[b * 512 + s];
        a += emis[(size_t)(b * 512 + s) * TT + lab];
        if (s > 0) a += trans[labels[b * 512 + s - 1] * TT + lab];
        else a += start[lab];
        if (s == 511) a += end[lab];
    }
    #pragma unroll
    for (int off = 32; off; off >>= 1) a += __shfl_xor(a, off);
    if (lane == 0) num[b] = a;
}

// ---------------------------------------------------------------------------
// Fused CRF forward + viterbi with 8-step register prefetch of emissions.
// Grid 32 x 64: blocks 0..15 forward (batch b), 16..31 viterbi (b-16).
// ---------------------------------------------------------------------------
__global__ __launch_bounds__(64)
void crf_path_kernel(const float* __restrict__ emis, const float* __restrict__ start,
                     const float* __restrict__ end, const float* __restrict__ trans,
                     float* __restrict__ logZ, float* __restrict__ out_tags)
{
    const int mode = blockIdx.x >> 4;
    const int b = blockIdx.x & 15;
    const int lane = threadIdx.x;
    const int j = lane & 31;
    const int h = lane >> 5;
    const int hbase = h << 4;
    __shared__ unsigned char hist[511][32];
    __shared__ float sval[32];
    __shared__ int path[512];

    const float* eb = emis + (size_t)b * 512 * TT;

    float cur[8], nxt[8];
    #pragma unroll
    for (int i = 0; i < 8; ++i) cur[i] = eb[(1 + i) * TT + j];

    if (mode == 0) {
        float Ecol[16];
        #pragma unroll
        for (int ii = 0; ii < 16; ++ii) Ecol[ii] = __expf(trans[(hbase + ii) * TT + j]);
        float sc = start[j] + eb[j];
        for (int base = 1; base < 512; base += 8) {
            #pragma unroll
            for (int i = 0; i < 8; ++i) {
                int s = base + 8 + i;
                nxt[i] = eb[(s < 512 ? s : 511) * TT + j];
            }
            #pragma unroll
            for (int i = 0; i < 8; ++i) {
                if (base + i < 512) {
                    float r = __shfl(sc, 0);
                    float p = __expf(sc - r);
                    float dot = 0.0f;
                    #pragma unroll
                    for (int ii = 0; ii < 16; ++ii)
                        dot = fmaf(__shfl(p, hbase + ii), Ecol[ii], dot);
                    dot += __shfl_xor(dot, 32);
                    sc = r + __logf(dot) + cur[i];
                }
            }
            #pragma unroll
            for (int i = 0; i < 8; ++i) cur[i] = nxt[i];
        }
        float v = sc + end[j];
        float mx = v;
        #pragma unroll
        for (int off = 1; off < 32; off <<= 1) mx = fmaxf(mx, __shfl_xor(mx, off));
        float p = __expf(v - mx);
        float sm = p;
        #pragma unroll
        for (int off = 1; off < 32; off <<= 1) sm += __shfl_xor(sm, off);
        if (lane == 0) logZ[b] = mx + __logf(sm);
    } else {
        float tcol[16];
        #pragma unroll
        for (int ii = 0; ii < 16; ++ii) tcol[ii] = trans[(hbase + ii) * TT + j];
        float sc = start[j] + eb[j];
        for (int base = 1; base < 512; base += 8) {
            #pragma unroll
            for (int i = 0; i < 8; ++i) {
                int s = base + 8 + i;
                nxt[i] = eb[(s < 512 ? s : 511) * TT + j];
            }
            #pragma unroll
            for (int i = 0; i < 8; ++i) {
                if (base + i < 512) {
                    int s = base + i;
                    float best = __shfl(sc, hbase) + tcol[0];
                    int arg = hbase;
                    #pragma unroll
                    for (int ii = 1; ii < 16; ++ii) {
                        float c = __shfl(sc, hbase + ii) + tcol[ii];
                        if (c > best) { best = c; arg = hbase + ii; }
                    }
                    float vo = __shfl_xor(best, 32);
                    int   ao = __shfl_xor(arg, 32);
                    bool take = h ? !(best > vo) : (vo > best);   // first-max: lower i wins
                    if (take) { best = vo; arg = ao; }
                    if (h == 0) hist[s - 1][j] = (unsigned char)arg;
                    sc = best + cur[i];
                }
            }
            #pragma unroll
            for (int i = 0; i < 8; ++i) cur[i] = nxt[i];
        }
        if (h == 0) sval[j] = sc + end[j];
        __syncthreads();
        if (lane == 0) {
            float best = sval[0]; int arg = 0;
            for (int i = 1; i < TT; ++i)
                if (sval[i] > best) { best = sval[i]; arg = i; }
            int t = arg; path[511] = t;
            for (int s = 510; s >= 0; --s) { t = hist[s][t]; path[s] = t; }
        }
        __syncthreads();
        for (int s = lane; s < 512; s += 64)
            out_tags[(size_t)b * 512 + s] = (float)path[s];
    }
}

__global__ void crf_loss_kernel(const float* __restrict__ num, const float* __restrict__ logZ,
                                float* __restrict__ out)
{
    if (threadIdx.x == 0) {
        float s = 0.0f;
        for (int b = 0; b < 16; ++b) s += num[b] - logZ[b];
        out[0] = -s / 10000.0f;
    }
}

extern "C" void kernel_launch(void* const* d_in, const int* in_sizes, int n_in,
                              void* d_out, int out_size, void* d_ws, size_t ws_size,
                              hipStream_t stream)
{
    (void)in_sizes; (void)n_in; (void)out_size; (void)ws_size;
    const int*   input_ids = (const int*)d_in[0];
    const int*   labels    = (const int*)d_in[1];
    const float* emb   = (const float*)d_in[3];
    const float* in_w  = (const float*)d_in[4];
    const float* in_b  = (const float*)d_in[5];
    const float* out_w = (const float*)d_in[6];
    const float* out_b = (const float*)d_in[7];
    const float* ln1g  = (const float*)d_in[8];
    const float* ln1b  = (const float*)d_in[9];
    const float* ln2g  = (const float*)d_in[10];
    const float* ln2b  = (const float*)d_in[11];
    const float* w1    = (const float*)d_in[12];
    const float* b1    = (const float*)d_in[13];
    const float* w2    = (const float*)d_in[14];
    const float* b2    = (const float*)d_in[15];
    const float* hw    = (const float*)d_in[16];
    const float* hb    = (const float*)d_in[17];
    const float* cs    = (const float*)d_in[18];
    const float* ce    = (const float*)d_in[19];
    const float* ct    = (const float*)d_in[20];
    float* out = (float*)d_out;

    char* ws = (char*)d_ws;
    unsigned short* xh   = (unsigned short*)(ws);
    unsigned short* xm   = (unsigned short*)(ws + 12582912);
    unsigned short* qkvh = (unsigned short*)(ws + 25165824);
    unsigned short* qkvm = (unsigned short*)(ws + 62914560);
    unsigned short* ohb  = (unsigned short*)(ws + 100663296);
    unsigned short* omb  = (unsigned short*)(ws + 113246208);
    float*          tmp  = (float*)(ws + 125829120);
    unsigned short* wih  = (unsigned short*)(ws + 150994944);
    unsigned short* wim  = (unsigned short*)(ws + 154533888);
    unsigned short* woh  = (unsigned short*)(ws + 158072832);
    unsigned short* wom  = (unsigned short*)(ws + 159252480);
    unsigned short* w1h  = (unsigned short*)(ws + 160432128);
    unsigned short* w1m  = (unsigned short*)(ws + 161611776);
    unsigned short* w2h  = (unsigned short*)(ws + 162791424);
    unsigned short* w2m  = (unsigned short*)(ws + 163971072);
    unsigned short* f1h  = qkvh;   // qkv dead after attn
    unsigned short* f1m  = qkvm;
    float* emis = (float*)(ws + 100663296);                // alias oh (dead post-encoder)
    float* numb = (float*)(ws + 100663296 + 1048576);
    float* logZ = numb + 16;

    embed_kernel<<<MTOK * 192 / 256, 256, 0, stream>>>(input_ids, emb, xh, xm);

    for (int l = 0; l < NL; ++l) {
        wsplit_kernel<<<1728, 256, 0, stream>>>(in_w + (size_t)l * H3 * HD, wih, wim, H3 * HD / 4);
        wsplit_kernel<<<576, 256, 0, stream>>>(out_w + (size_t)l * HD * HD, woh, wom, HD * HD / 4);
        wsplit_kernel<<<576, 256, 0, stream>>>(w1 + (size_t)l * HD * HD, w1h, w1m, HD * HD / 4);
        wsplit_kernel<<<576, 256, 0, stream>>>(w2 + (size_t)l * HD * HD, w2h, w2m, HD * HD / 4);

        gemm_pair_kernel<false, true><<<dim3(18, 64), 256, 0, stream>>>(
            xh, xm, wih, wim, in_b + (size_t)l * H3, nullptr, qkvh, qkvm, H3);
        attn_kernel<<<dim3(8, 192), 256, 0, stream>>>(qkvh, qkvm, ohb, omb);
        gemm_pair_kernel<false, false><<<dim3(6, 64), 256, 0, stream>>>(
            ohb, omb, woh, wom, out_b + (size_t)l * HD, tmp, nullptr, nullptr, HD);
        ln_residual_kernel<<<2048, 256, 0, stream>>>(xh, xm, tmp, ln1g + l * HD, ln1b + l * HD);
        gemm_pair_kernel<true, true><<<dim3(6, 64), 256, 0, stream>>>(
            xh, xm, w1h, w1m, b1 + (size_t)l * HD, nullptr, f1h, f1m, HD);
        gemm_pair_kernel<false, false><<<dim3(6, 64), 256, 0, stream>>>(
            f1h, f1m, w2h, w2m, b2 + (size_t)l * HD, tmp, nullptr, nullptr, HD);
        ln_residual_kernel<<<2048, 256, 0, stream>>>(xh, xm, tmp, ln2g + l * HD, ln2b + l * HD);
    }

    out_logits_kernel<<<MTOK * 192 / 256, 256, 0, stream>>>(xh, xm, out);

    emis_kernel<<<2048, 256, 0, stream>>>(xh, xm, hw, hb, emis);
    crf_num_kernel<<<16, 64, 0, stream>>>(emis, labels, cs, ce, ct, numb);
    crf_path_kernel<<<32, 64, 0, stream>>>(emis, cs, ce, ct, logZ, out + 6291457);
    crf_loss_kernel<<<1, 64, 0, stream>>>(numb, logZ, out + 6291456);
}

// Round 6
// 2580.261 us; speedup vs baseline: 2.6060x; 1.8633x over previous
//
#include <hip/hip_runtime.h>

#define MTOK 8192      // B*S
#define HD   768
#define H3   2304
#define NL   6
#define TT   32        // CRF tags (reference: T = 32)

typedef __attribute__((ext_vector_type(4))) float f32x4;
typedef __attribute__((ext_vector_type(8))) short v8bf;     // 8 bf16 in 4 VGPRs
typedef __attribute__((ext_vector_type(4))) unsigned short us4;
typedef __attribute__((ext_vector_type(8))) unsigned short us8;

__device__ __forceinline__ unsigned short bf16rne(float v) {
    unsigned int u = __float_as_uint(v);
    u += 0x7FFFu + ((u >> 16) & 1u);
    return (unsigned short)(u >> 16);
}
__device__ __forceinline__ float bf2f(unsigned short h) {
    return __uint_as_float(((unsigned int)h) << 16);
}
// hi bf16 in low 16 bits, mid (residual) bf16 in high 16 bits
__device__ __forceinline__ unsigned int split_pack(float v) {
    unsigned short h = bf16rne(v);
    unsigned short m = bf16rne(v - bf2f(h));
    return (unsigned int)h | ((unsigned int)m << 16);
}

// async global->LDS, 16B per lane, LDS dest = wave-uniform base + lane*16
__device__ __forceinline__ void gload16(const unsigned short* g, unsigned short* l) {
    __builtin_amdgcn_global_load_lds(
        (const __attribute__((address_space(1))) unsigned int*)g,
        (__attribute__((address_space(3))) unsigned int*)l, 16, 0, 0);
}

// ---------------------------------------------------------------------------
// Weight split: f32 -> (hi, mid) bf16 arrays. 4 elems/thread.
// ---------------------------------------------------------------------------
__global__ __launch_bounds__(256)
void wsplit_kernel(const float* __restrict__ src, unsigned short* __restrict__ h,
                   unsigned short* __restrict__ m, int n4)
{
    int i = blockIdx.x * 256 + threadIdx.x;
    if (i >= n4) return;
    float4 v = reinterpret_cast<const float4*>(src)[i];
    us4 hv, mv; unsigned int p;
    p = split_pack(v.x); hv[0] = (unsigned short)p; mv[0] = (unsigned short)(p >> 16);
    p = split_pack(v.y); hv[1] = (unsigned short)p; mv[1] = (unsigned short)(p >> 16);
    p = split_pack(v.z); hv[2] = (unsigned short)p; mv[2] = (unsigned short)(p >> 16);
    p = split_pack(v.w); hv[3] = (unsigned short)p; mv[3] = (unsigned short)(p >> 16);
    reinterpret_cast<us4*>(h)[i] = hv;
    reinterpret_cast<us4*>(m)[i] = mv;
}

// ---------------------------------------------------------------------------
// GEMM on pre-split operands (unchanged from round 5).
// ---------------------------------------------------------------------------
template<bool RELU, bool SPLITOUT>
__global__ __launch_bounds__(256)
void gemm_pair_kernel(const unsigned short* __restrict__ Ahg, const unsigned short* __restrict__ Amg,
                      const unsigned short* __restrict__ Bhg, const unsigned short* __restrict__ Bmg,
                      const float* __restrict__ bias, float* __restrict__ Cf,
                      unsigned short* __restrict__ Ch, unsigned short* __restrict__ Cm, int N)
{
    __shared__ unsigned short lds[4][128 * 64];   // Ah, Am, Bh, Bm tiles (64 KB)
    const int tid = threadIdx.x;
    const int lane = tid & 63, wave = tid >> 6;
    const int wm = wave >> 1, wn = wave & 1;
    const int bn = blockIdx.x, bm = blockIdx.y;
    const int g = lane >> 4, lr = lane & 15;

    const int srow = lane >> 3;
    const int schunk = ((lane & 7) ^ srow) * 8;   // pre-swizzled source chunk (shorts)
    const size_t aoff = ((size_t)(bm * 128 + wave * 32 + srow)) * HD + schunk;
    const size_t boff = ((size_t)(bn * 128 + wave * 32 + srow)) * HD + schunk;

    f32x4 acc[4][4] = {};

    for (int kt = 0; kt < 12; ++kt) {
        __syncthreads();
        const int k64 = kt * 64;
        #pragma unroll
        for (int i = 0; i < 4; ++i) {
            const size_t ra = aoff + (size_t)i * 8 * HD + k64;
            const size_t rb = boff + (size_t)i * 8 * HD + k64;
            unsigned short* lb = (unsigned short*)&lds[0][(wave * 32 + i * 8) * 64];
            gload16(Ahg + ra, lb);
            gload16(Amg + ra, lb + 8192);
            gload16(Bhg + rb, lb + 16384);
            gload16(Bmg + rb, lb + 24576);
        }
        __syncthreads();
        #pragma unroll
        for (int kk = 0; kk < 2; ++kk) {
            v8bf ah[4], am[4], bh[4], bmv[4];
            #pragma unroll
            for (int i = 0; i < 4; ++i) {
                int row = wm * 64 + i * 16 + lr;
                int ub = row * 64 + ((((kk << 2) + g) ^ (row & 7)) << 3);
                ah[i] = *reinterpret_cast<const v8bf*>(&lds[0][ub]);
                am[i] = *reinterpret_cast<const v8bf*>(&lds[1][ub]);
            }
            #pragma unroll
            for (int i = 0; i < 4; ++i) {
                int row = wn * 64 + i * 16 + lr;
                int ub = row * 64 + ((((kk << 2) + g) ^ (row & 7)) << 3);
                bh[i]  = *reinterpret_cast<const v8bf*>(&lds[2][ub]);
                bmv[i] = *reinterpret_cast<const v8bf*>(&lds[3][ub]);
            }
            #pragma unroll
            for (int i = 0; i < 4; ++i)
                #pragma unroll
                for (int j = 0; j < 4; ++j) {
                    acc[i][j] = __builtin_amdgcn_mfma_f32_16x16x32_bf16(ah[i], bh[j],  acc[i][j], 0, 0, 0);
                    acc[i][j] = __builtin_amdgcn_mfma_f32_16x16x32_bf16(ah[i], bmv[j], acc[i][j], 0, 0, 0);
                    acc[i][j] = __builtin_amdgcn_mfma_f32_16x16x32_bf16(am[i], bh[j],  acc[i][j], 0, 0, 0);
                    acc[i][j] = __builtin_amdgcn_mfma_f32_16x16x32_bf16(am[i], bmv[j], acc[i][j], 0, 0, 0);
                }
        }
    }
    #pragma unroll
    for (int j = 0; j < 4; ++j) {
        int n = bn * 128 + wn * 64 + j * 16 + lr;
        float bv = bias[n];
        #pragma unroll
        for (int i = 0; i < 4; ++i) {
            int mr = bm * 128 + wm * 64 + i * 16 + 4 * g;
            #pragma unroll
            for (int r = 0; r < 4; ++r) {
                float y = acc[i][j][r] + bv;
                if (RELU) y = fmaxf(y, 0.0f);
                size_t idx = (size_t)(mr + r) * N + n;
                if (SPLITOUT) {
                    unsigned int pk = split_pack(y);
                    Ch[idx] = (unsigned short)pk;
                    Cm[idx] = (unsigned short)(pk >> 16);
                } else {
                    Cf[idx] = y;
                }
            }
        }
    }
}

// ---------------------------------------------------------------------------
// V transpose: qkv V-part [tok][h*64+d] -> vt[bh][d][s]. Grid (8 kt, 192 bh).
// LDS XOR-swizzled 64x64 tile transpose, vectorized both sides.
// ---------------------------------------------------------------------------
__global__ __launch_bounds__(256)
void vtrans_kernel(const unsigned short* __restrict__ qh, const unsigned short* __restrict__ qm,
                   unsigned short* __restrict__ vth, unsigned short* __restrict__ vtm)
{
    __shared__ unsigned short Th[4096], Tm[4096];
    const int kt = blockIdx.x, bh = blockIdx.y;
    const int b = bh / 12, h = bh % 12;
    const int tid = threadIdx.x;
    #pragma unroll
    for (int is = 0; is < 2; ++is) {
        int c = is * 256 + tid;
        int r = c >> 3, dc = c & 7;
        size_t src = ((size_t)b * 512 + kt * 64 + r) * H3 + 1536 + h * 64 + dc * 8;
        int swz = (dc ^ (r & 7) ^ (r >> 3)) * 8;
        *reinterpret_cast<us8*>(&Th[r * 64 + swz]) = *reinterpret_cast<const us8*>(&qh[src]);
        *reinterpret_cast<us8*>(&Tm[r * 64 + swz]) = *reinterpret_cast<const us8*>(&qm[src]);
    }
    __syncthreads();
    #pragma unroll
    for (int is = 0; is < 2; ++is) {
        int c = is * 256 + tid;
        int d = c >> 3, rg = c & 7;
        us8 vh, vm;
        #pragma unroll
        for (int e = 0; e < 8; ++e) {
            int r = rg * 8 + e;
            int addr = r * 64 + (((d >> 3) ^ (r & 7) ^ (r >> 3)) * 8) + (d & 7);
            vh[e] = Th[addr]; vm[e] = Tm[addr];
        }
        size_t dst = ((size_t)bh * 64 + d) * 512 + kt * 64 + rg * 8;
        *reinterpret_cast<us8*>(&vth[dst]) = vh;
        *reinterpret_cast<us8*>(&vtm[dst]) = vm;
    }
}

// ---------------------------------------------------------------------------
// Flash attention v2. Grid (2 q-halves, 192 bh), 4 waves; wave owns 64 q-rows.
// Q fragments in registers; K and V^T staged via global_load_lds per K-tile.
// ---------------------------------------------------------------------------
__global__ __launch_bounds__(256, 2)
void attn_kernel(const unsigned short* __restrict__ qh, const unsigned short* __restrict__ qm,
                 const unsigned short* __restrict__ vth, const unsigned short* __restrict__ vtm,
                 unsigned short* __restrict__ ohp, unsigned short* __restrict__ omp)
{
    __shared__ unsigned short Kh[4096], Km[4096], Vh[4096], Vm[4096];
    __shared__ unsigned short Ph[4][1024], Pm[4][1024];
    const int qhalf = blockIdx.x;
    const int bh = blockIdx.y;
    const int b = bh / 12, h = bh % 12;
    const int tid = threadIdx.x, lane = tid & 63, wave = tid >> 6;
    const int g = lane >> 4, lr = lane & 15;
    const size_t rowbase = (size_t)b * 512;
    const int qbase = qhalf * 256 + wave * 64;

    // Q fragments (hi, mid) in registers — loaded once
    v8bf aqh[4][2], aqm[4][2];
    #pragma unroll
    for (int i = 0; i < 4; ++i)
        #pragma unroll
        for (int kk = 0; kk < 2; ++kk) {
            size_t a = (rowbase + qbase + i * 16 + lr) * H3 + h * 64 + (kk * 4 + g) * 8;
            aqh[i][kk] = *reinterpret_cast<const v8bf*>(&qh[a]);
            aqm[i][kk] = *reinterpret_cast<const v8bf*>(&qm[a]);
        }

    float m_run[4][4], l_run[4][4];
    f32x4 O[4][4];
    #pragma unroll
    for (int i = 0; i < 4; ++i)
        #pragma unroll
        for (int r = 0; r < 4; ++r) {
            m_run[i][r] = -__builtin_inff(); l_run[i][r] = 0.0f;
            O[i][r] = (f32x4){0.0f, 0.0f, 0.0f, 0.0f};
        }

    const int srow = lane >> 3;
    const int schunk = ((lane & 7) ^ srow) * 8;

    for (int kt = 0; kt < 8; ++kt) {
        __syncthreads();
        #pragma unroll
        for (int is = 0; is < 2; ++is) {
            int rowg = is * 32 + wave * 8;
            size_t ksrc = (rowbase + kt * 64 + rowg + srow) * H3 + 768 + h * 64 + schunk;
            size_t vsrc = ((size_t)bh * 64 + rowg + srow) * 512 + kt * 64 + schunk;
            gload16(qh + ksrc, &Kh[rowg * 64]);
            gload16(qm + ksrc, &Km[rowg * 64]);
            gload16(vth + vsrc, &Vh[rowg * 64]);
            gload16(vtm + vsrc, &Vm[rowg * 64]);
        }
        __syncthreads();

        #pragma unroll
        for (int i = 0; i < 4; ++i) {
            // S = Q K^T (3 products: hh, hm, mh)
            f32x4 s[4] = {};
            #pragma unroll
            for (int kk = 0; kk < 2; ++kk) {
                #pragma unroll
                for (int j = 0; j < 4; ++j) {
                    int krow = j * 16 + lr;
                    int uk = krow * 64 + (((kk * 4 + g) ^ (krow & 7)) * 8);
                    v8bf bkh = *reinterpret_cast<const v8bf*>(&Kh[uk]);
                    v8bf bkm = *reinterpret_cast<const v8bf*>(&Km[uk]);
                    s[j] = __builtin_amdgcn_mfma_f32_16x16x32_bf16(aqh[i][kk], bkh, s[j], 0, 0, 0);
                    s[j] = __builtin_amdgcn_mfma_f32_16x16x32_bf16(aqh[i][kk], bkm, s[j], 0, 0, 0);
                    s[j] = __builtin_amdgcn_mfma_f32_16x16x32_bf16(aqm[i][kk], bkh, s[j], 0, 0, 0);
                }
            }
            // online softmax (q-row = 4*g + rr; 16 lr lanes hold k)
            float mnew[4], alpha[4], rsum[4];
            #pragma unroll
            for (int rr = 0; rr < 4; ++rr) {
                float t = fmaxf(fmaxf(s[0][rr], s[1][rr]), fmaxf(s[2][rr], s[3][rr])) * 0.125f;
                #pragma unroll
                for (int off = 1; off < 16; off <<= 1) t = fmaxf(t, __shfl_xor(t, off));
                mnew[rr] = fmaxf(m_run[i][rr], t);
                alpha[rr] = __expf(m_run[i][rr] - mnew[rr]);
                m_run[i][rr] = mnew[rr];
                rsum[rr] = 0.0f;
            }
            #pragma unroll
            for (int j = 0; j < 4; ++j) {
                #pragma unroll
                for (int rr = 0; rr < 4; ++rr) {
                    float p = __expf(s[j][rr] * 0.125f - mnew[rr]);
                    rsum[rr] += p;
                    int prow = 4 * g + rr;
                    int ub = prow * 64 + ((((j * 2 + (lr >> 3)) ^ (prow & 7)) << 3) | (lr & 7));
                    unsigned int pk = split_pack(p);
                    Ph[wave][ub] = (unsigned short)pk; Pm[wave][ub] = (unsigned short)(pk >> 16);
                }
            }
            #pragma unroll
            for (int rr = 0; rr < 4; ++rr) {
                float t = rsum[rr];
                #pragma unroll
                for (int off = 1; off < 16; off <<= 1) t += __shfl_xor(t, off);
                l_run[i][rr] = l_run[i][rr] * alpha[rr] + t;
                O[i][0][rr] *= alpha[rr]; O[i][1][rr] *= alpha[rr];
                O[i][2][rr] *= alpha[rr]; O[i][3][rr] *= alpha[rr];
            }
            // O += P V (3 products)
            #pragma unroll
            for (int kk = 0; kk < 2; ++kk) {
                int up = lr * 64 + (((kk * 4 + g) ^ (lr & 7)) * 8);
                v8bf aph = *reinterpret_cast<const v8bf*>(&Ph[wave][up]);
                v8bf apm = *reinterpret_cast<const v8bf*>(&Pm[wave][up]);
                #pragma unroll
                for (int j = 0; j < 4; ++j) {
                    int vrow = j * 16 + lr;
                    int uv = vrow * 64 + (((kk * 4 + g) ^ (vrow & 7)) * 8);
                    v8bf bvh = *reinterpret_cast<const v8bf*>(&Vh[uv]);
                    v8bf bvm = *reinterpret_cast<const v8bf*>(&Vm[uv]);
                    O[i][j] = __builtin_amdgcn_mfma_f32_16x16x32_bf16(aph, bvh, O[i][j], 0, 0, 0);
                    O[i][j] = __builtin_amdgcn_mfma_f32_16x16x32_bf16(aph, bvm, O[i][j], 0, 0, 0);
                    O[i][j] = __builtin_amdgcn_mfma_f32_16x16x32_bf16(apm, bvh, O[i][j], 0, 0, 0);
                }
            }
        }
    }
    #pragma unroll
    for (int i = 0; i < 4; ++i)
        #pragma unroll
        for (int j = 0; j < 4; ++j) {
            int d = j * 16 + lr;
            #pragma unroll
            for (int rr = 0; rr < 4; ++rr) {
                size_t tok = rowbase + qbase + i * 16 + 4 * g + rr;
                unsigned int pk = split_pack(O[i][j][rr] / l_run[i][rr]);
                ohp[tok * HD + h * 64 + d] = (unsigned short)pk;
                omp[tok * HD + h * 64 + d] = (unsigned short)(pk >> 16);
            }
        }
}

// ---------------------------------------------------------------------------
// x = LayerNorm((xh+xm) + t) * g + b -> (xh, xm). One wave per token.
// ---------------------------------------------------------------------------
__global__ __launch_bounds__(256)
void ln_residual_kernel(unsigned short* __restrict__ xh, unsigned short* __restrict__ xm,
                        const float* __restrict__ t,
                        const float* __restrict__ gamma, const float* __restrict__ beta)
{
    int tok = blockIdx.x * 4 + (threadIdx.x >> 6);
    int lane = threadIdx.x & 63;
    float v[12];
    float s = 0.0f;
    #pragma unroll
    for (int j = 0; j < 12; ++j) {
        size_t c = (size_t)tok * HD + j * 64 + lane;
        v[j] = bf2f(xh[c]) + bf2f(xm[c]) + t[c];
        s += v[j];
    }
    #pragma unroll
    for (int off = 32; off; off >>= 1) s += __shfl_xor(s, off);
    float mean = s * (1.0f / 768.0f);
    float vs = 0.0f;
    #pragma unroll
    for (int j = 0; j < 12; ++j) { float d = v[j] - mean; vs += d * d; }
    #pragma unroll
    for (int off = 32; off; off >>= 1) vs += __shfl_xor(vs, off);
    float rstd = rsqrtf(vs * (1.0f / 768.0f) + 1e-5f);
    #pragma unroll
    for (int j = 0; j < 12; ++j) {
        size_t c = (size_t)tok * HD + j * 64 + lane;
        float y = (v[j] - mean) * rstd * gamma[j * 64 + lane] + beta[j * 64 + lane];
        unsigned int pk = split_pack(y);
        xh[c] = (unsigned short)pk; xm[c] = (unsigned short)(pk >> 16);
    }
}

__global__ __launch_bounds__(256)
void embed_kernel(const int* __restrict__ ids, const float* __restrict__ emb,
                  unsigned short* __restrict__ xh, unsigned short* __restrict__ xm)
{
    int f4 = blockIdx.x * 256 + threadIdx.x;     // 8192*192 float4
    int tok = f4 / 192, c = f4 % 192;
    float4 v = *reinterpret_cast<const float4*>(emb + (size_t)ids[tok] * HD + c * 4);
    us4 hv, mv; unsigned int p;
    p = split_pack(v.x); hv[0] = (unsigned short)p; mv[0] = (unsigned short)(p >> 16);
    p = split_pack(v.y); hv[1] = (unsigned short)p; mv[1] = (unsigned short)(p >> 16);
    p = split_pack(v.z); hv[2] = (unsigned short)p; mv[2] = (unsigned short)(p >> 16);
    p = split_pack(v.w); hv[3] = (unsigned short)p; mv[3] = (unsigned short)(p >> 16);
    *reinterpret_cast<us4*>(&xh[(size_t)tok * HD + c * 4]) = hv;
    *reinterpret_cast<us4*>(&xm[(size_t)tok * HD + c * 4]) = mv;
}

// logits f32 = xh + xm
__global__ __launch_bounds__(256)
void out_logits_kernel(const unsigned short* __restrict__ xh, const unsigned short* __restrict__ xm,
                       float* __restrict__ out)
{
    int i = blockIdx.x * 256 + threadIdx.x;
    us4 hv = reinterpret_cast<const us4*>(xh)[i];
    us4 mv = reinterpret_cast<const us4*>(xm)[i];
    float4 o;
    o.x = bf2f(hv[0]) + bf2f(mv[0]);
    o.y = bf2f(hv[1]) + bf2f(mv[1]);
    o.z = bf2f(hv[2]) + bf2f(mv[2]);
    o.w = bf2f(hv[3]) + bf2f(mv[3]);
    reinterpret_cast<float4*>(out)[i] = o;
}

// emis[tok][t] = dot768(x[tok], head_w[t]) + head_b[t] — wave per token
__global__ __launch_bounds__(256)
void emis_kernel(const unsigned short* __restrict__ xh, const unsigned short* __restrict__ xm,
                 const float* __restrict__ hw, const float* __restrict__ hb,
                 float* __restrict__ emis)
{
    int tok = blockIdx.x * 4 + (threadIdx.x >> 6);
    int lane = threadIdx.x & 63;
    float xv[12];
    #pragma unroll
    for (int j = 0; j < 12; ++j) {
        size_t c = (size_t)tok * HD + j * 64 + lane;
        xv[j] = bf2f(xh[c]) + bf2f(xm[c]);
    }
    for (int t = 0; t < TT; ++t) {
        float a = 0.0f;
        #pragma unroll
        for (int j = 0; j < 12; ++j) a += xv[j] * hw[t * HD + j * 64 + lane];
        #pragma unroll
        for (int off = 32; off; off >>= 1) a += __shfl_xor(a, off);
        if (lane == 0) emis[(size_t)tok * TT + t] = a + hb[t];
    }
}

__global__ void crf_num_kernel(const float* __restrict__ emis, const int* __restrict__ labels,
                               const float* __restrict__ start, const float* __restrict__ end,
                               const float* __restrict__ trans, float* __restrict__ num)
{
    int b = blockIdx.x, lane = threadIdx.x;   // blockDim 64
    float a = 0.0f;
    for (int s = lane; s < 512; s += 64) {
        int lab = labels[b * 512 + s];
        a += emis[(size_t)(b * 512 + s) * TT + lab];
        if (s > 0) a += trans[labels[b * 512 + s - 1] * TT + lab];
        else a += start[lab];
        if (s == 511) a += end[lab];
    }
    #pragma unroll
    for (int off = 32; off; off >>= 1) a += __shfl_xor(a, off);
    if (lane == 0) num[b] = a;
}

// ---------------------------------------------------------------------------
// Fused CRF forward + viterbi with 8-step register prefetch of emissions.
// ---------------------------------------------------------------------------
__global__ __launch_bounds__(64)
void crf_path_kernel(const float* __restrict__ emis, const float* __restrict__ start,
                     const float* __restrict__ end, const float* __restrict__ trans,
                     float* __restrict__ logZ, float* __restrict__ out_tags)
{
    const int mode = blockIdx.x >> 4;
    const int b = blockIdx.x & 15;
    const int lane = threadIdx.x;
    const int j = lane & 31;
    const int h = lane >> 5;
    const int hbase = h << 4;
    __shared__ unsigned char hist[511][32];
    __shared__ float sval[32];
    __shared__ int path[512];

    const float* eb = emis + (size_t)b * 512 * TT;

    float cur[8], nxt[8];
    #pragma unroll
    for (int i = 0; i < 8; ++i) cur[i] = eb[(1 + i) * TT + j];

    if (mode == 0) {
        float Ecol[16];
        #pragma unroll
        for (int ii = 0; ii < 16; ++ii) Ecol[ii] = __expf(trans[(hbase + ii) * TT + j]);
        float sc = start[j] + eb[j];
        for (int base = 1; base < 512; base += 8) {
            #pragma unroll
            for (int i = 0; i < 8; ++i) {
                int s = base + 8 + i;
                nxt[i] = eb[(s < 512 ? s : 511) * TT + j];
            }
            #pragma unroll
            for (int i = 0; i < 8; ++i) {
                if (base + i < 512) {
                    float r = __shfl(sc, 0);
                    float p = __expf(sc - r);
                    float dot = 0.0f;
                    #pragma unroll
                    for (int ii = 0; ii < 16; ++ii)
                        dot = fmaf(__shfl(p, hbase + ii), Ecol[ii], dot);
                    dot += __shfl_xor(dot, 32);
                    sc = r + __logf(dot) + cur[i];
                }
            }
            #pragma unroll
            for (int i = 0; i < 8; ++i) cur[i] = nxt[i];
        }
        float v = sc + end[j];
        float mx = v;
        #pragma unroll
        for (int off = 1; off < 32; off <<= 1) mx = fmaxf(mx, __shfl_xor(mx, off));
        float p = __expf(v - mx);
        float sm = p;
        #pragma unroll
        for (int off = 1; off < 32; off <<= 1) sm += __shfl_xor(sm, off);
        if (lane == 0) logZ[b] = mx + __logf(sm);
    } else {
        float tcol[16];
        #pragma unroll
        for (int ii = 0; ii < 16; ++ii) tcol[ii] = trans[(hbase + ii) * TT + j];
        float sc = start[j] + eb[j];
        for (int base = 1; base < 512; base += 8) {
            #pragma unroll
            for (int i = 0; i < 8; ++i) {
                int s = base + 8 + i;
                nxt[i] = eb[(s < 512 ? s : 511) * TT + j];
            }
            #pragma unroll
            for (int i = 0; i < 8; ++i) {
                if (base + i < 512) {
                    int s = base + i;
                    float best = __shfl(sc, hbase) + tcol[0];
                    int arg = hbase;
                    #pragma unroll
                    for (int ii = 1; ii < 16; ++ii) {
                        float c = __shfl(sc, hbase + ii) + tcol[ii];
                        if (c > best) { best = c; arg = hbase + ii; }
                    }
                    float vo = __shfl_xor(best, 32);
                    int   ao = __shfl_xor(arg, 32);
                    bool take = h ? !(best > vo) : (vo > best);
                    if (take) { best = vo; arg = ao; }
                    if (h == 0) hist[s - 1][j] = (unsigned char)arg;
                    sc = best + cur[i];
                }
            }
            #pragma unroll
            for (int i = 0; i < 8; ++i) cur[i] = nxt[i];
        }
        if (h == 0) sval[j] = sc + end[j];
        __syncthreads();
        if (lane == 0) {
            float best = sval[0]; int arg = 0;
            for (int i = 1; i < TT; ++i)
                if (sval[i] > best) { best = sval[i]; arg = i; }
            int t = arg; path[511] = t;
            for (int s = 510; s >= 0; --s) { t = hist[s][t]; path[s] = t; }
        }
        __syncthreads();
        for (int s = lane; s < 512; s += 64)
            out_tags[(size_t)b * 512 + s] = (float)path[s];
    }
}

__global__ void crf_loss_kernel(const float* __restrict__ num, const float* __restrict__ logZ,
                                float* __restrict__ out)
{
    if (threadIdx.x == 0) {
        float s = 0.0f;
        for (int b = 0; b < 16; ++b) s += num[b] - logZ[b];
        out[0] = -s / 10000.0f;
    }
}

extern "C" void kernel_launch(void* const* d_in, const int* in_sizes, int n_in,
                              void* d_out, int out_size, void* d_ws, size_t ws_size,
                              hipStream_t stream)
{
    (void)in_sizes; (void)n_in; (void)out_size; (void)ws_size;
    const int*   input_ids = (const int*)d_in[0];
    const int*   labels    = (const int*)d_in[1];
    const float* emb   = (const float*)d_in[3];
    const float* in_w  = (const float*)d_in[4];
    const float* in_b  = (const float*)d_in[5];
    const float* out_w = (const float*)d_in[6];
    const float* out_b = (const float*)d_in[7];
    const float* ln1g  = (const float*)d_in[8];
    const float* ln1b  = (const float*)d_in[9];
    const float* ln2g  = (const float*)d_in[10];
    const float* ln2b  = (const float*)d_in[11];
    const float* w1    = (const float*)d_in[12];
    const float* b1    = (const float*)d_in[13];
    const float* w2    = (const float*)d_in[14];
    const float* b2    = (const float*)d_in[15];
    const float* hw    = (const float*)d_in[16];
    const float* hb    = (const float*)d_in[17];
    const float* cs    = (const float*)d_in[18];
    const float* ce    = (const float*)d_in[19];
    const float* ct    = (const float*)d_in[20];
    float* out = (float*)d_out;

    char* ws = (char*)d_ws;
    unsigned short* xh   = (unsigned short*)(ws);
    unsigned short* xm   = (unsigned short*)(ws + 12582912);
    unsigned short* qkvh = (unsigned short*)(ws + 25165824);
    unsigned short* qkvm = (unsigned short*)(ws + 62914560);
    unsigned short* ohb  = (unsigned short*)(ws + 100663296);
    unsigned short* omb  = (unsigned short*)(ws + 113246208);
    float*          tmp  = (float*)(ws + 125829120);
    unsigned short* vth  = (unsigned short*)(ws + 125829120);  // alias tmp (disjoint lifetime)
    unsigned short* vtm  = (unsigned short*)(ws + 138412032);
    unsigned short* wih  = (unsigned short*)(ws + 150994944);
    unsigned short* wim  = (unsigned short*)(ws + 154533888);
    unsigned short* woh  = (unsigned short*)(ws + 158072832);
    unsigned short* wom  = (unsigned short*)(ws + 159252480);
    unsigned short* w1h  = (unsigned short*)(ws + 160432128);
    unsigned short* w1m  = (unsigned short*)(ws + 161611776);
    unsigned short* w2h  = (unsigned short*)(ws + 162791424);
    unsigned short* w2m  = (unsigned short*)(ws + 163971072);
    unsigned short* f1h  = qkvh;   // qkv dead after attn
    unsigned short* f1m  = qkvm;
    float* emis = (float*)(ws + 100663296);                // alias ohb (dead post-encoder)
    float* numb = (float*)(ws + 100663296 + 1048576);
    float* logZ = numb + 16;

    embed_kernel<<<MTOK * 192 / 256, 256, 0, stream>>>(input_ids, emb, xh, xm);

    for (int l = 0; l < NL; ++l) {
        wsplit_kernel<<<1728, 256, 0, stream>>>(in_w + (size_t)l * H3 * HD, wih, wim, H3 * HD / 4);
        wsplit_kernel<<<576, 256, 0, stream>>>(out_w + (size_t)l * HD * HD, woh, wom, HD * HD / 4);
        wsplit_kernel<<<576, 256, 0, stream>>>(w1 + (size_t)l * HD * HD, w1h, w1m, HD * HD / 4);
        wsplit_kernel<<<576, 256, 0, stream>>>(w2 + (size_t)l * HD * HD, w2h, w2m, HD * HD / 4);

        gemm_pair_kernel<false, true><<<dim3(18, 64), 256, 0, stream>>>(
            xh, xm, wih, wim, in_b + (size_t)l * H3, nullptr, qkvh, qkvm, H3);
        vtrans_kernel<<<dim3(8, 192), 256, 0, stream>>>(qkvh, qkvm, vth, vtm);
        attn_kernel<<<dim3(2, 192), 256, 0, stream>>>(qkvh, qkvm, vth, vtm, ohb, omb);
        gemm_pair_kernel<false, false><<<dim3(6, 64), 256, 0, stream>>>(
            ohb, omb, woh, wom, out_b + (size_t)l * HD, tmp, nullptr, nullptr, HD);
        ln_residual_kernel<<<2048, 256, 0, stream>>>(xh, xm, tmp, ln1g + l * HD, ln1b + l * HD);
        gemm_pair_kernel<true, true><<<dim3(6, 64), 256, 0, stream>>>(
            xh, xm, w1h, w1m, b1 + (size_t)l * HD, nullptr, f1h, f1m, HD);
        gemm_pair_kernel<false, false><<<dim3(6, 64), 256, 0, stream>>>(
            f1h, f1m, w2h, w2m, b2 + (size_t)l * HD, tmp, nullptr, nullptr, HD);
        ln_residual_kernel<<<2048, 256, 0, stream>>>(xh, xm, tmp, ln2g + l * HD, ln2b + l * HD);
    }

    out_logits_kernel<<<MTOK * 192 / 256, 256, 0, stream>>>(xh, xm, out);

    emis_kernel<<<2048, 256, 0, stream>>>(xh, xm, hw, hb, emis);
    crf_num_kernel<<<16, 64, 0, stream>>>(emis, labels, cs, ce, ct, numb);
    crf_path_kernel<<<32, 64, 0, stream>>>(emis, cs, ce, ct, logZ, out + 6291457);
    crf_loss_kernel<<<1, 64, 0, stream>>>(numb, logZ, out + 6291456);
}

// Round 7
// 2360.430 us; speedup vs baseline: 2.8487x; 1.0931x over previous
//
#include <hip/hip_runtime.h>

#define MTOK 8192      // B*S
#define HD   768
#define H3   2304
#define NL   6
#define TT   32        // CRF tags (reference: T = 32)

typedef __attribute__((ext_vector_type(4))) float f32x4;
typedef __attribute__((ext_vector_type(8))) short v8bf;     // 8 bf16 in 4 VGPRs
typedef __attribute__((ext_vector_type(4))) unsigned short us4;
typedef __attribute__((ext_vector_type(8))) unsigned short us8;

__device__ __forceinline__ unsigned short bf16rne(float v) {
    unsigned int u = __float_as_uint(v);
    u += 0x7FFFu + ((u >> 16) & 1u);
    return (unsigned short)(u >> 16);
}
__device__ __forceinline__ float bf2f(unsigned short h) {
    return __uint_as_float(((unsigned int)h) << 16);
}
// hi bf16 in low 16 bits, mid (residual) bf16 in high 16 bits
__device__ __forceinline__ unsigned int split_pack(float v) {
    unsigned short h = bf16rne(v);
    unsigned short m = bf16rne(v - bf2f(h));
    return (unsigned int)h | ((unsigned int)m << 16);
}

// async global->LDS, 16B per lane, LDS dest = wave-uniform base + lane*16
__device__ __forceinline__ void gload16(const unsigned short* g, unsigned short* l) {
    __builtin_amdgcn_global_load_lds(
        (const __attribute__((address_space(1))) unsigned int*)g,
        (__attribute__((address_space(3))) unsigned int*)l, 16, 0, 0);
}

// ---------------------------------------------------------------------------
// Fused weight split for one layer: in_w (2304x768), out_w, w1, w2 (768x768).
// ---------------------------------------------------------------------------
__global__ __launch_bounds__(256)
void wsplit4_kernel(const float* __restrict__ inw, const float* __restrict__ outw,
                    const float* __restrict__ w1, const float* __restrict__ w2,
                    unsigned short* __restrict__ wih, unsigned short* __restrict__ wim,
                    unsigned short* __restrict__ woh, unsigned short* __restrict__ wom,
                    unsigned short* __restrict__ w1h, unsigned short* __restrict__ w1m,
                    unsigned short* __restrict__ w2h, unsigned short* __restrict__ w2m)
{
    int i = blockIdx.x * 256 + threadIdx.x;      // 884736 float4 total
    const float* src; unsigned short* dh; unsigned short* dm; int off;
    if (i < 442368)      { src = inw;  dh = wih; dm = wim; off = i; }
    else if (i < 589824) { src = outw; dh = woh; dm = wom; off = i - 442368; }
    else if (i < 737280) { src = w1;   dh = w1h; dm = w1m; off = i - 589824; }
    else                 { src = w2;   dh = w2h; dm = w2m; off = i - 737280; }
    float4 v = reinterpret_cast<const float4*>(src)[off];
    us4 hv, mv; unsigned int p;
    p = split_pack(v.x); hv[0] = (unsigned short)p; mv[0] = (unsigned short)(p >> 16);
    p = split_pack(v.y); hv[1] = (unsigned short)p; mv[1] = (unsigned short)(p >> 16);
    p = split_pack(v.z); hv[2] = (unsigned short)p; mv[2] = (unsigned short)(p >> 16);
    p = split_pack(v.w); hv[3] = (unsigned short)p; mv[3] = (unsigned short)(p >> 16);
    reinterpret_cast<us4*>(dh)[off] = hv;
    reinterpret_cast<us4*>(dm)[off] = mv;
}

// ---------------------------------------------------------------------------
// GEMM on pre-split operands, 3 products (hh, hm, mh — mm dropped, <=2^-16).
// ---------------------------------------------------------------------------
template<bool RELU, bool SPLITOUT>
__global__ __launch_bounds__(256)
void gemm_pair_kernel(const unsigned short* __restrict__ Ahg, const unsigned short* __restrict__ Amg,
                      const unsigned short* __restrict__ Bhg, const unsigned short* __restrict__ Bmg,
                      const float* __restrict__ bias, float* __restrict__ Cf,
                      unsigned short* __restrict__ Ch, unsigned short* __restrict__ Cm, int N)
{
    __shared__ unsigned short lds[4][128 * 64];   // Ah, Am, Bh, Bm tiles (64 KB)
    const int tid = threadIdx.x;
    const int lane = tid & 63, wave = tid >> 6;
    const int wm = wave >> 1, wn = wave & 1;
    const int bn = blockIdx.x, bm = blockIdx.y;
    const int g = lane >> 4, lr = lane & 15;

    const int srow = lane >> 3;
    const int schunk = ((lane & 7) ^ srow) * 8;   // pre-swizzled source chunk (shorts)
    const size_t aoff = ((size_t)(bm * 128 + wave * 32 + srow)) * HD + schunk;
    const size_t boff = ((size_t)(bn * 128 + wave * 32 + srow)) * HD + schunk;

    f32x4 acc[4][4] = {};

    for (int kt = 0; kt < 12; ++kt) {
        __syncthreads();
        const int k64 = kt * 64;
        #pragma unroll
        for (int i = 0; i < 4; ++i) {
            const size_t ra = aoff + (size_t)i * 8 * HD + k64;
            const size_t rb = boff + (size_t)i * 8 * HD + k64;
            unsigned short* lb = (unsigned short*)&lds[0][(wave * 32 + i * 8) * 64];
            gload16(Ahg + ra, lb);
            gload16(Amg + ra, lb + 8192);
            gload16(Bhg + rb, lb + 16384);
            gload16(Bmg + rb, lb + 24576);
        }
        __syncthreads();
        #pragma unroll
        for (int kk = 0; kk < 2; ++kk) {
            v8bf ah[4], am[4], bh[4], bmv[4];
            #pragma unroll
            for (int i = 0; i < 4; ++i) {
                int row = wm * 64 + i * 16 + lr;
                int ub = row * 64 + ((((kk << 2) + g) ^ (row & 7)) << 3);
                ah[i] = *reinterpret_cast<const v8bf*>(&lds[0][ub]);
                am[i] = *reinterpret_cast<const v8bf*>(&lds[1][ub]);
            }
            #pragma unroll
            for (int i = 0; i < 4; ++i) {
                int row = wn * 64 + i * 16 + lr;
                int ub = row * 64 + ((((kk << 2) + g) ^ (row & 7)) << 3);
                bh[i]  = *reinterpret_cast<const v8bf*>(&lds[2][ub]);
                bmv[i] = *reinterpret_cast<const v8bf*>(&lds[3][ub]);
            }
            #pragma unroll
            for (int i = 0; i < 4; ++i)
                #pragma unroll
                for (int j = 0; j < 4; ++j) {
                    acc[i][j] = __builtin_amdgcn_mfma_f32_16x16x32_bf16(ah[i], bh[j],  acc[i][j], 0, 0, 0);
                    acc[i][j] = __builtin_amdgcn_mfma_f32_16x16x32_bf16(ah[i], bmv[j], acc[i][j], 0, 0, 0);
                    acc[i][j] = __builtin_amdgcn_mfma_f32_16x16x32_bf16(am[i], bh[j],  acc[i][j], 0, 0, 0);
                }
        }
    }
    #pragma unroll
    for (int j = 0; j < 4; ++j) {
        int n = bn * 128 + wn * 64 + j * 16 + lr;
        float bv = bias[n];
        #pragma unroll
        for (int i = 0; i < 4; ++i) {
            int mr = bm * 128 + wm * 64 + i * 16 + 4 * g;
            #pragma unroll
            for (int r = 0; r < 4; ++r) {
                float y = acc[i][j][r] + bv;
                if (RELU) y = fmaxf(y, 0.0f);
                size_t idx = (size_t)(mr + r) * N + n;
                if (SPLITOUT) {
                    unsigned int pk = split_pack(y);
                    Ch[idx] = (unsigned short)pk;
                    Cm[idx] = (unsigned short)(pk >> 16);
                } else {
                    Cf[idx] = y;
                }
            }
        }
    }
}

// ---------------------------------------------------------------------------
// V transpose: qkv V-part [tok][h*64+d] -> vt[bh][d][s]. Grid (8 kt, 192 bh).
// ---------------------------------------------------------------------------
__global__ __launch_bounds__(256)
void vtrans_kernel(const unsigned short* __restrict__ qh, const unsigned short* __restrict__ qm,
                   unsigned short* __restrict__ vth, unsigned short* __restrict__ vtm)
{
    __shared__ unsigned short Th[4096], Tm[4096];
    const int kt = blockIdx.x, bh = blockIdx.y;
    const int b = bh / 12, h = bh % 12;
    const int tid = threadIdx.x;
    #pragma unroll
    for (int is = 0; is < 2; ++is) {
        int c = is * 256 + tid;
        int r = c >> 3, dc = c & 7;
        size_t src = ((size_t)b * 512 + kt * 64 + r) * H3 + 1536 + h * 64 + dc * 8;
        int swz = (dc ^ (r & 7) ^ (r >> 3)) * 8;
        *reinterpret_cast<us8*>(&Th[r * 64 + swz]) = *reinterpret_cast<const us8*>(&qh[src]);
        *reinterpret_cast<us8*>(&Tm[r * 64 + swz]) = *reinterpret_cast<const us8*>(&qm[src]);
    }
    __syncthreads();
    #pragma unroll
    for (int is = 0; is < 2; ++is) {
        int c = is * 256 + tid;
        int d = c >> 3, rg = c & 7;
        us8 vh, vm;
        #pragma unroll
        for (int e = 0; e < 8; ++e) {
            int r = rg * 8 + e;
            int addr = r * 64 + (((d >> 3) ^ (r & 7) ^ (r >> 3)) * 8) + (d & 7);
            vh[e] = Th[addr]; vm[e] = Tm[addr];
        }
        size_t dst = ((size_t)bh * 64 + d) * 512 + kt * 64 + rg * 8;
        *reinterpret_cast<us8*>(&vth[dst]) = vh;
        *reinterpret_cast<us8*>(&vtm[dst]) = vm;
    }
}

// ---------------------------------------------------------------------------
// Flash attention v2. Grid (2 q-halves, 192 bh), 4 waves; wave owns 64 q-rows.
// ---------------------------------------------------------------------------
__global__ __launch_bounds__(256, 2)
void attn_kernel(const unsigned short* __restrict__ qh, const unsigned short* __restrict__ qm,
                 const unsigned short* __restrict__ vth, const unsigned short* __restrict__ vtm,
                 unsigned short* __restrict__ ohp, unsigned short* __restrict__ omp)
{
    __shared__ unsigned short Kh[4096], Km[4096], Vh[4096], Vm[4096];
    __shared__ unsigned short Ph[4][1024], Pm[4][1024];
    const int qhalf = blockIdx.x;
    const int bh = blockIdx.y;
    const int b = bh / 12, h = bh % 12;
    const int tid = threadIdx.x, lane = tid & 63, wave = tid >> 6;
    const int g = lane >> 4, lr = lane & 15;
    const size_t rowbase = (size_t)b * 512;
    const int qbase = qhalf * 256 + wave * 64;

    v8bf aqh[4][2], aqm[4][2];
    #pragma unroll
    for (int i = 0; i < 4; ++i)
        #pragma unroll
        for (int kk = 0; kk < 2; ++kk) {
            size_t a = (rowbase + qbase + i * 16 + lr) * H3 + h * 64 + (kk * 4 + g) * 8;
            aqh[i][kk] = *reinterpret_cast<const v8bf*>(&qh[a]);
            aqm[i][kk] = *reinterpret_cast<const v8bf*>(&qm[a]);
        }

    float m_run[4][4], l_run[4][4];
    f32x4 O[4][4];
    #pragma unroll
    for (int i = 0; i < 4; ++i)
        #pragma unroll
        for (int r = 0; r < 4; ++r) {
            m_run[i][r] = -__builtin_inff(); l_run[i][r] = 0.0f;
            O[i][r] = (f32x4){0.0f, 0.0f, 0.0f, 0.0f};
        }

    const int srow = lane >> 3;
    const int schunk = ((lane & 7) ^ srow) * 8;

    for (int kt = 0; kt < 8; ++kt) {
        __syncthreads();
        #pragma unroll
        for (int is = 0; is < 2; ++is) {
            int rowg = is * 32 + wave * 8;
            size_t ksrc = (rowbase + kt * 64 + rowg + srow) * H3 + 768 + h * 64 + schunk;
            size_t vsrc = ((size_t)bh * 64 + rowg + srow) * 512 + kt * 64 + schunk;
            gload16(qh + ksrc, &Kh[rowg * 64]);
            gload16(qm + ksrc, &Km[rowg * 64]);
            gload16(vth + vsrc, &Vh[rowg * 64]);
            gload16(vtm + vsrc, &Vm[rowg * 64]);
        }
        __syncthreads();

        #pragma unroll
        for (int i = 0; i < 4; ++i) {
            f32x4 s[4] = {};
            #pragma unroll
            for (int kk = 0; kk < 2; ++kk) {
                #pragma unroll
                for (int j = 0; j < 4; ++j) {
                    int krow = j * 16 + lr;
                    int uk = krow * 64 + (((kk * 4 + g) ^ (krow & 7)) * 8);
                    v8bf bkh = *reinterpret_cast<const v8bf*>(&Kh[uk]);
                    v8bf bkm = *reinterpret_cast<const v8bf*>(&Km[uk]);
                    s[j] = __builtin_amdgcn_mfma_f32_16x16x32_bf16(aqh[i][kk], bkh, s[j], 0, 0, 0);
                    s[j] = __builtin_amdgcn_mfma_f32_16x16x32_bf16(aqh[i][kk], bkm, s[j], 0, 0, 0);
                    s[j] = __builtin_amdgcn_mfma_f32_16x16x32_bf16(aqm[i][kk], bkh, s[j], 0, 0, 0);
                }
            }
            float mnew[4], alpha[4], rsum[4];
            #pragma unroll
            for (int rr = 0; rr < 4; ++rr) {
                float t = fmaxf(fmaxf(s[0][rr], s[1][rr]), fmaxf(s[2][rr], s[3][rr])) * 0.125f;
                #pragma unroll
                for (int off = 1; off < 16; off <<= 1) t = fmaxf(t, __shfl_xor(t, off));
                mnew[rr] = fmaxf(m_run[i][rr], t);
                alpha[rr] = __expf(m_run[i][rr] - mnew[rr]);
                m_run[i][rr] = mnew[rr];
                rsum[rr] = 0.0f;
            }
            #pragma unroll
            for (int j = 0; j < 4; ++j) {
                #pragma unroll
                for (int rr = 0; rr < 4; ++rr) {
                    float p = __expf(s[j][rr] * 0.125f - mnew[rr]);
                    rsum[rr] += p;
                    int prow = 4 * g + rr;
                    int ub = prow * 64 + ((((j * 2 + (lr >> 3)) ^ (prow & 7)) << 3) | (lr & 7));
                    unsigned int pk = split_pack(p);
                    Ph[wave][ub] = (unsigned short)pk; Pm[wave][ub] = (unsigned short)(pk >> 16);
                }
            }
            #pragma unroll
            for (int rr = 0; rr < 4; ++rr) {
                float t = rsum[rr];
                #pragma unroll
                for (int off = 1; off < 16; off <<= 1) t += __shfl_xor(t, off);
                l_run[i][rr] = l_run[i][rr] * alpha[rr] + t;
                O[i][0][rr] *= alpha[rr]; O[i][1][rr] *= alpha[rr];
                O[i][2][rr] *= alpha[rr]; O[i][3][rr] *= alpha[rr];
            }
            #pragma unroll
            for (int kk = 0; kk < 2; ++kk) {
                int up = lr * 64 + (((kk * 4 + g) ^ (lr & 7)) * 8);
                v8bf aph = *reinterpret_cast<const v8bf*>(&Ph[wave][up]);
                v8bf apm = *reinterpret_cast<const v8bf*>(&Pm[wave][up]);
                #pragma unroll
                for (int j = 0; j < 4; ++j) {
                    int vrow = j * 16 + lr;
                    int uv = vrow * 64 + (((kk * 4 + g) ^ (vrow & 7)) * 8);
                    v8bf bvh = *reinterpret_cast<const v8bf*>(&Vh[uv]);
                    v8bf bvm = *reinterpret_cast<const v8bf*>(&Vm[uv]);
                    O[i][j] = __builtin_amdgcn_mfma_f32_16x16x32_bf16(aph, bvh, O[i][j], 0, 0, 0);
                    O[i][j] = __builtin_amdgcn_mfma_f32_16x16x32_bf16(aph, bvm, O[i][j], 0, 0, 0);
                    O[i][j] = __builtin_amdgcn_mfma_f32_16x16x32_bf16(apm, bvh, O[i][j], 0, 0, 0);
                }
            }
        }
    }
    #pragma unroll
    for (int i = 0; i < 4; ++i)
        #pragma unroll
        for (int j = 0; j < 4; ++j) {
            int d = j * 16 + lr;
            #pragma unroll
            for (int rr = 0; rr < 4; ++rr) {
                size_t tok = rowbase + qbase + i * 16 + 4 * g + rr;
                unsigned int pk = split_pack(O[i][j][rr] / l_run[i][rr]);
                ohp[tok * HD + h * 64 + d] = (unsigned short)pk;
                omp[tok * HD + h * 64 + d] = (unsigned short)(pk >> 16);
            }
        }
}

// ---------------------------------------------------------------------------
// x = LayerNorm((xh+xm) + t) * g + b -> (xh, xm). One wave per token.
// ---------------------------------------------------------------------------
__global__ __launch_bounds__(256)
void ln_residual_kernel(unsigned short* __restrict__ xh, unsigned short* __restrict__ xm,
                        const float* __restrict__ t,
                        const float* __restrict__ gamma, const float* __restrict__ beta)
{
    int tok = blockIdx.x * 4 + (threadIdx.x >> 6);
    int lane = threadIdx.x & 63;
    float v[12];
    float s = 0.0f;
    #pragma unroll
    for (int j = 0; j < 12; ++j) {
        size_t c = (size_t)tok * HD + j * 64 + lane;
        v[j] = bf2f(xh[c]) + bf2f(xm[c]) + t[c];
        s += v[j];
    }
    #pragma unroll
    for (int off = 32; off; off >>= 1) s += __shfl_xor(s, off);
    float mean = s * (1.0f / 768.0f);
    float vs = 0.0f;
    #pragma unroll
    for (int j = 0; j < 12; ++j) { float d = v[j] - mean; vs += d * d; }
    #pragma unroll
    for (int off = 32; off; off >>= 1) vs += __shfl_xor(vs, off);
    float rstd = rsqrtf(vs * (1.0f / 768.0f) + 1e-5f);
    #pragma unroll
    for (int j = 0; j < 12; ++j) {
        size_t c = (size_t)tok * HD + j * 64 + lane;
        float y = (v[j] - mean) * rstd * gamma[j * 64 + lane] + beta[j * 64 + lane];
        unsigned int pk = split_pack(y);
        xh[c] = (unsigned short)pk; xm[c] = (unsigned short)(pk >> 16);
    }
}

__global__ __launch_bounds__(256)
void embed_kernel(const int* __restrict__ ids, const float* __restrict__ emb,
                  unsigned short* __restrict__ xh, unsigned short* __restrict__ xm)
{
    int f4 = blockIdx.x * 256 + threadIdx.x;     // 8192*192 float4
    int tok = f4 / 192, c = f4 % 192;
    float4 v = *reinterpret_cast<const float4*>(emb + (size_t)ids[tok] * HD + c * 4);
    us4 hv, mv; unsigned int p;
    p = split_pack(v.x); hv[0] = (unsigned short)p; mv[0] = (unsigned short)(p >> 16);
    p = split_pack(v.y); hv[1] = (unsigned short)p; mv[1] = (unsigned short)(p >> 16);
    p = split_pack(v.z); hv[2] = (unsigned short)p; mv[2] = (unsigned short)(p >> 16);
    p = split_pack(v.w); hv[3] = (unsigned short)p; mv[3] = (unsigned short)(p >> 16);
    *reinterpret_cast<us4*>(&xh[(size_t)tok * HD + c * 4]) = hv;
    *reinterpret_cast<us4*>(&xm[(size_t)tok * HD + c * 4]) = mv;
}

// logits f32 = xh + xm
__global__ __launch_bounds__(256)
void out_logits_kernel(const unsigned short* __restrict__ xh, const unsigned short* __restrict__ xm,
                       float* __restrict__ out)
{
    int i = blockIdx.x * 256 + threadIdx.x;
    us4 hv = reinterpret_cast<const us4*>(xh)[i];
    us4 mv = reinterpret_cast<const us4*>(xm)[i];
    float4 o;
    o.x = bf2f(hv[0]) + bf2f(mv[0]);
    o.y = bf2f(hv[1]) + bf2f(mv[1]);
    o.z = bf2f(hv[2]) + bf2f(mv[2]);
    o.w = bf2f(hv[3]) + bf2f(mv[3]);
    reinterpret_cast<float4*>(out)[i] = o;
}

// emis[tok][t] = dot768(x[tok], head_w[t]) + head_b[t] — wave per token
__global__ __launch_bounds__(256)
void emis_kernel(const unsigned short* __restrict__ xh, const unsigned short* __restrict__ xm,
                 const float* __restrict__ hw, const float* __restrict__ hb,
                 float* __restrict__ emis)
{
    int tok = blockIdx.x * 4 + (threadIdx.x >> 6);
    int lane = threadIdx.x & 63;
    float xv[12];
    #pragma unroll
    for (int j = 0; j < 12; ++j) {
        size_t c = (size_t)tok * HD + j * 64 + lane;
        xv[j] = bf2f(xh[c]) + bf2f(xm[c]);
    }
    for (int t = 0; t < TT; ++t) {
        float a = 0.0f;
        #pragma unroll
        for (int j = 0; j < 12; ++j) a += xv[j] * hw[t * HD + j * 64 + lane];
        #pragma unroll
        for (int off = 32; off; off >>= 1) a += __shfl_xor(a, off);
        if (lane == 0) emis[(size_t)tok * TT + t] = a + hb[t];
    }
}

__global__ void crf_num_kernel(const float* __restrict__ emis, const int* __restrict__ labels,
                               const float* __restrict__ start, const float* __restrict__ end,
                               const float* __restrict__ trans, float* __restrict__ num)
{
    int b = blockIdx.x, lane = threadIdx.x;   // blockDim 64
    float a = 0.0f;
    for (int s = lane; s < 512; s += 64) {
        int lab = labels[b * 512 + s];
        a += emis[(size_t)(b * 512 + s) * TT + lab];
        if (s > 0) a += trans[labels[b * 512 + s - 1] * TT + lab];
        else a += start[lab];
        if (s == 511) a += end[lab];
    }
    #pragma unroll
    for (int off = 32; off; off >>= 1) a += __shfl_xor(a, off);
    if (lane == 0) num[b] = a;
}

// ---------------------------------------------------------------------------
// Fused CRF forward + viterbi. LDS same-address-broadcast instead of shfl
// (ds_bpermute chains were the round-5 bottleneck: 18 shfl/step ~1400cy).
// Blocks 0..15: forward (batch b), lanes 0..31 active, state j = lane.
// Blocks 16..31: viterbi. 8-step register prefetch of emissions retained.
// ---------------------------------------------------------------------------
__global__ __launch_bounds__(64)
void crf_path_kernel(const float* __restrict__ emis, const float* __restrict__ start,
                     const float* __restrict__ end, const float* __restrict__ trans,
                     float* __restrict__ logZ, float* __restrict__ out_tags)
{
    const int mode = blockIdx.x >> 4;
    const int b = blockIdx.x & 15;
    const int lane = threadIdx.x;
    const int j = lane & 31;
    __shared__ float xch[32];
    __shared__ unsigned char hist[511][32];
    __shared__ float sval[32];
    __shared__ int path[512];

    const float* eb = emis + (size_t)b * 512 * TT;

    if (mode == 0) {
        if (lane < 32) {
            float Ecol[32];
            #pragma unroll
            for (int ii = 0; ii < 32; ++ii) Ecol[ii] = __expf(trans[ii * TT + j]);
            float cur[8], nxt[8];
            #pragma unroll
            for (int i = 0; i < 8; ++i) cur[i] = eb[(1 + i) * TT + j];
            float sc = start[j] + eb[j];
            for (int base = 1; base < 512; base += 8) {
                #pragma unroll
                for (int i = 0; i < 8; ++i) {
                    int s = base + 8 + i;
                    nxt[i] = eb[(s < 512 ? s : 511) * TT + j];
                }
                #pragma unroll
                for (int i = 0; i < 8; ++i) {
                    if (base + i < 512) {
                        xch[j] = sc;
                        asm volatile("s_waitcnt lgkmcnt(0)" ::: "memory");
                        float r = xch[0];                       // broadcast read
                        float p = __expf(sc - r);
                        asm volatile("" ::: "memory");
                        xch[j] = p;
                        asm volatile("s_waitcnt lgkmcnt(0)" ::: "memory");
                        float dot = 0.0f;
                        #pragma unroll
                        for (int q = 0; q < 8; ++q) {
                            f32x4 t4 = *reinterpret_cast<const f32x4*>(&xch[q * 4]);
                            dot = fmaf(t4[0], Ecol[q * 4 + 0], dot);
                            dot = fmaf(t4[1], Ecol[q * 4 + 1], dot);
                            dot = fmaf(t4[2], Ecol[q * 4 + 2], dot);
                            dot = fmaf(t4[3], Ecol[q * 4 + 3], dot);
                        }
                        asm volatile("" ::: "memory");
                        sc = r + __logf(dot) + cur[i];
                    }
                }
                #pragma unroll
                for (int i = 0; i < 8; ++i) cur[i] = nxt[i];
            }
            float v = sc + end[j];
            float mx = v;
            #pragma unroll
            for (int off = 1; off < 32; off <<= 1) mx = fmaxf(mx, __shfl_xor(mx, off));
            float p = __expf(v - mx);
            float sm = p;
            #pragma unroll
            for (int off = 1; off < 32; off <<= 1) sm += __shfl_xor(sm, off);
            if (lane == 0) logZ[b] = mx + __logf(sm);
        }
    } else {
        if (lane < 32) {
            float tcol[32];
            #pragma unroll
            for (int ii = 0; ii < 32; ++ii) tcol[ii] = trans[ii * TT + j];
            float cur[8], nxt[8];
            #pragma unroll
            for (int i = 0; i < 8; ++i) cur[i] = eb[(1 + i) * TT + j];
            float sc = start[j] + eb[j];
            for (int base = 1; base < 512; base += 8) {
                #pragma unroll
                for (int i = 0; i < 8; ++i) {
                    int s = base + 8 + i;
                    nxt[i] = eb[(s < 512 ? s : 511) * TT + j];
                }
                #pragma unroll
                for (int i = 0; i < 8; ++i) {
                    if (base + i < 512) {
                        int s = base + i;
                        xch[j] = sc;
                        asm volatile("s_waitcnt lgkmcnt(0)" ::: "memory");
                        float c[32];
                        #pragma unroll
                        for (int q = 0; q < 8; ++q) {
                            f32x4 t4 = *reinterpret_cast<const f32x4*>(&xch[q * 4]);
                            c[q * 4 + 0] = t4[0] + tcol[q * 4 + 0];
                            c[q * 4 + 1] = t4[1] + tcol[q * 4 + 1];
                            c[q * 4 + 2] = t4[2] + tcol[q * 4 + 2];
                            c[q * 4 + 3] = t4[3] + tcol[q * 4 + 3];
                        }
                        asm volatile("" ::: "memory");
                        float best = c[0]; int arg = 0;
                        #pragma unroll
                        for (int ii = 1; ii < 32; ++ii)
                            if (c[ii] > best) { best = c[ii]; arg = ii; }   // first-max
                        hist[s - 1][j] = (unsigned char)arg;
                        sc = best + cur[i];
                    }
                }
                #pragma unroll
                for (int i = 0; i < 8; ++i) cur[i] = nxt[i];
            }
            sval[j] = sc + end[j];
        }
        __syncthreads();
        if (lane == 0) {
            float best = sval[0]; int arg = 0;
            for (int i = 1; i < TT; ++i)
                if (sval[i] > best) { best = sval[i]; arg = i; }
            int t = arg; path[511] = t;
            for (int s = 510; s >= 0; --s) { t = hist[s][t]; path[s] = t; }
        }
        __syncthreads();
        for (int s = lane; s < 512; s += 64)
            out_tags[(size_t)b * 512 + s] = (float)path[s];
    }
}

__global__ void crf_loss_kernel(const float* __restrict__ num, const float* __restrict__ logZ,
                                float* __restrict__ out)
{
    if (threadIdx.x == 0) {
        float s = 0.0f;
        for (int b = 0; b < 16; ++b) s += num[b] - logZ[b];
        out[0] = -s / 10000.0f;
    }
}

extern "C" void kernel_launch(void* const* d_in, const int* in_sizes, int n_in,
                              void* d_out, int out_size, void* d_ws, size_t ws_size,
                              hipStream_t stream)
{
    (void)in_sizes; (void)n_in; (void)out_size; (void)ws_size;
    const int*   input_ids = (const int*)d_in[0];
    const int*   labels    = (const int*)d_in[1];
    const float* emb   = (const float*)d_in[3];
    const float* in_w  = (const float*)d_in[4];
    const float* in_b  = (const float*)d_in[5];
    const float* out_w = (const float*)d_in[6];
    const float* out_b = (const float*)d_in[7];
    const float* ln1g  = (const float*)d_in[8];
    const float* ln1b  = (const float*)d_in[9];
    const float* ln2g  = (const float*)d_in[10];
    const float* ln2b  = (const float*)d_in[11];
    const float* w1    = (const float*)d_in[12];
    const float* b1    = (const float*)d_in[13];
    const float* w2    = (const float*)d_in[14];
    const float* b2    = (const float*)d_in[15];
    const float* hw    = (const float*)d_in[16];
    const float* hb    = (const float*)d_in[17];
    const float* cs    = (const float*)d_in[18];
    const float* ce    = (const float*)d_in[19];
    const float* ct    = (const float*)d_in[20];
    float* out = (float*)d_out;

    char* ws = (char*)d_ws;
    unsigned short* xh   = (unsigned short*)(ws);
    unsigned short* xm   = (unsigned short*)(ws + 12582912);
    unsigned short* qkvh = (unsigned short*)(ws + 25165824);
    unsigned short* qkvm = (unsigned short*)(ws + 62914560);
    unsigned short* ohb  = (unsigned short*)(ws + 100663296);
    unsigned short* omb  = (unsigned short*)(ws + 113246208);
    float*          tmp  = (float*)(ws + 125829120);
    unsigned short* vth  = (unsigned short*)(ws + 125829120);  // alias tmp (disjoint lifetime)
    unsigned short* vtm  = (unsigned short*)(ws + 138412032);
    unsigned short* wih  = (unsigned short*)(ws + 150994944);
    unsigned short* wim  = (unsigned short*)(ws + 154533888);
    unsigned short* woh  = (unsigned short*)(ws + 158072832);
    unsigned short* wom  = (unsigned short*)(ws + 159252480);
    unsigned short* w1h  = (unsigned short*)(ws + 160432128);
    unsigned short* w1m  = (unsigned short*)(ws + 161611776);
    unsigned short* w2h  = (unsigned short*)(ws + 162791424);
    unsigned short* w2m  = (unsigned short*)(ws + 163971072);
    unsigned short* f1h  = qkvh;   // qkv dead after attn
    unsigned short* f1m  = qkvm;
    float* emis = (float*)(ws + 100663296);                // alias ohb (dead post-encoder)
    float* numb = (float*)(ws + 100663296 + 1048576);
    float* logZ = numb + 16;

    embed_kernel<<<MTOK * 192 / 256, 256, 0, stream>>>(input_ids, emb, xh, xm);

    for (int l = 0; l < NL; ++l) {
        wsplit4_kernel<<<3456, 256, 0, stream>>>(
            in_w + (size_t)l * H3 * HD, out_w + (size_t)l * HD * HD,
            w1 + (size_t)l * HD * HD, w2 + (size_t)l * HD * HD,
            wih, wim, woh, wom, w1h, w1m, w2h, w2m);

        gemm_pair_kernel<false, true><<<dim3(18, 64), 256, 0, stream>>>(
            xh, xm, wih, wim, in_b + (size_t)l * H3, nullptr, qkvh, qkvm, H3);
        vtrans_kernel<<<dim3(8, 192), 256, 0, stream>>>(qkvh, qkvm, vth, vtm);
        attn_kernel<<<dim3(2, 192), 256, 0, stream>>>(qkvh, qkvm, vth, vtm, ohb, omb);
        gemm_pair_kernel<false, false><<<dim3(6, 64), 256, 0, stream>>>(
            ohb, omb, woh, wom, out_b + (size_t)l * HD, tmp, nullptr, nullptr, HD);
        ln_residual_kernel<<<2048, 256, 0, stream>>>(xh, xm, tmp, ln1g + l * HD, ln1b + l * HD);
        gemm_pair_kernel<true, true><<<dim3(6, 64), 256, 0, stream>>>(
            xh, xm, w1h, w1m, b1 + (size_t)l * HD, nullptr, f1h, f1m, HD);
        gemm_pair_kernel<false, false><<<dim3(6, 64), 256, 0, stream>>>(
            f1h, f1m, w2h, w2m, b2 + (size_t)l * HD, tmp, nullptr, nullptr, HD);
        ln_residual_kernel<<<2048, 256, 0, stream>>>(xh, xm, tmp, ln2g + l * HD, ln2b + l * HD);
    }

    out_logits_kernel<<<MTOK * 192 / 256, 256, 0, stream>>>(xh, xm, out);

    emis_kernel<<<2048, 256, 0, stream>>>(xh, xm, hw, hb, emis);
    crf_num_kernel<<<16, 64, 0, stream>>>(emis, labels, cs, ce, ct, numb);
    crf_path_kernel<<<32, 64, 0, stream>>>(emis, cs, ce, ct, logZ, out + 6291457);
    crf_loss_kernel<<<1, 64, 0, stream>>>(numb, logZ, out + 6291456);
}

// Round 8
// 2296.113 us; speedup vs baseline: 2.9285x; 1.0280x over previous
//
#include <hip/hip_runtime.h>

#define MTOK 8192      // B*S
#define HD   768
#define H3   2304
#define NL   6
#define TT   32        // CRF tags (reference: T = 32)

typedef __attribute__((ext_vector_type(4))) float f32x4;
typedef __attribute__((ext_vector_type(8))) short v8bf;     // 8 bf16 in 4 VGPRs
typedef __attribute__((ext_vector_type(4))) unsigned short us4;
typedef __attribute__((ext_vector_type(8))) unsigned short us8;

__device__ __forceinline__ unsigned short bf16rne(float v) {
    unsigned int u = __float_as_uint(v);
    u += 0x7FFFu + ((u >> 16) & 1u);
    return (unsigned short)(u >> 16);
}
__device__ __forceinline__ float bf2f(unsigned short h) {
    return __uint_as_float(((unsigned int)h) << 16);
}
// hi bf16 in low 16 bits, mid (residual) bf16 in high 16 bits
__device__ __forceinline__ unsigned int split_pack(float v) {
    unsigned short h = bf16rne(v);
    unsigned short m = bf16rne(v - bf2f(h));
    return (unsigned int)h | ((unsigned int)m << 16);
}

// async global->LDS, 16B per lane, LDS dest = wave-uniform base + lane*16
__device__ __forceinline__ void gload16(const unsigned short* g, unsigned short* l) {
    __builtin_amdgcn_global_load_lds(
        (const __attribute__((address_space(1))) unsigned int*)g,
        (__attribute__((address_space(3))) unsigned int*)l, 16, 0, 0);
}

// ---------------------------------------------------------------------------
// Fused weight split for one layer: in_w (2304x768), out_w, w1, w2 (768x768).
// ---------------------------------------------------------------------------
__global__ __launch_bounds__(256)
void wsplit4_kernel(const float* __restrict__ inw, const float* __restrict__ outw,
                    const float* __restrict__ w1, const float* __restrict__ w2,
                    unsigned short* __restrict__ wih, unsigned short* __restrict__ wim,
                    unsigned short* __restrict__ woh, unsigned short* __restrict__ wom,
                    unsigned short* __restrict__ w1h, unsigned short* __restrict__ w1m,
                    unsigned short* __restrict__ w2h, unsigned short* __restrict__ w2m)
{
    int i = blockIdx.x * 256 + threadIdx.x;      // 884736 float4 total
    const float* src; unsigned short* dh; unsigned short* dm; int off;
    if (i < 442368)      { src = inw;  dh = wih; dm = wim; off = i; }
    else if (i < 589824) { src = outw; dh = woh; dm = wom; off = i - 442368; }
    else if (i < 737280) { src = w1;   dh = w1h; dm = w1m; off = i - 589824; }
    else                 { src = w2;   dh = w2h; dm = w2m; off = i - 737280; }
    float4 v = reinterpret_cast<const float4*>(src)[off];
    us4 hv, mv; unsigned int p;
    p = split_pack(v.x); hv[0] = (unsigned short)p; mv[0] = (unsigned short)(p >> 16);
    p = split_pack(v.y); hv[1] = (unsigned short)p; mv[1] = (unsigned short)(p >> 16);
    p = split_pack(v.z); hv[2] = (unsigned short)p; mv[2] = (unsigned short)(p >> 16);
    p = split_pack(v.w); hv[3] = (unsigned short)p; mv[3] = (unsigned short)(p >> 16);
    reinterpret_cast<us4*>(dh)[off] = hv;
    reinterpret_cast<us4*>(dm)[off] = mv;
}

// ---------------------------------------------------------------------------
// GEMM on pre-split operands, 3 products (hh, hm, mh). XCD-swizzled grid.
// ---------------------------------------------------------------------------
template<bool RELU, bool SPLITOUT>
__global__ __launch_bounds__(256)
void gemm_pair_kernel(const unsigned short* __restrict__ Ahg, const unsigned short* __restrict__ Amg,
                      const unsigned short* __restrict__ Bhg, const unsigned short* __restrict__ Bmg,
                      const float* __restrict__ bias, float* __restrict__ Cf,
                      unsigned short* __restrict__ Ch, unsigned short* __restrict__ Cm, int N)
{
    __shared__ unsigned short lds[4][128 * 64];   // Ah, Am, Bh, Bm tiles (64 KB)
    const int tid = threadIdx.x;
    const int lane = tid & 63, wave = tid >> 6;
    const int wm = wave >> 1, wn = wave & 1;
    // bijective XCD swizzle (grid total % 8 == 0)
    const int nbx = gridDim.x;
    const int total = nbx * gridDim.y;
    const int flat = blockIdx.y * nbx + blockIdx.x;
    const int sw = (flat & 7) * (total >> 3) + (flat >> 3);
    const int bn = sw % nbx, bm = sw / nbx;
    const int g = lane >> 4, lr = lane & 15;

    const int srow = lane >> 3;
    const int schunk = ((lane & 7) ^ srow) * 8;   // pre-swizzled source chunk (shorts)
    const size_t aoff = ((size_t)(bm * 128 + wave * 32 + srow)) * HD + schunk;
    const size_t boff = ((size_t)(bn * 128 + wave * 32 + srow)) * HD + schunk;

    f32x4 acc[4][4] = {};

    for (int kt = 0; kt < 12; ++kt) {
        __syncthreads();
        const int k64 = kt * 64;
        #pragma unroll
        for (int i = 0; i < 4; ++i) {
            const size_t ra = aoff + (size_t)i * 8 * HD + k64;
            const size_t rb = boff + (size_t)i * 8 * HD + k64;
            unsigned short* lb = (unsigned short*)&lds[0][(wave * 32 + i * 8) * 64];
            gload16(Ahg + ra, lb);
            gload16(Amg + ra, lb + 8192);
            gload16(Bhg + rb, lb + 16384);
            gload16(Bmg + rb, lb + 24576);
        }
        __syncthreads();
        #pragma unroll
        for (int kk = 0; kk < 2; ++kk) {
            v8bf ah[4], am[4], bh[4], bmv[4];
            #pragma unroll
            for (int i = 0; i < 4; ++i) {
                int row = wm * 64 + i * 16 + lr;
                int ub = row * 64 + ((((kk << 2) + g) ^ (row & 7)) << 3);
                ah[i] = *reinterpret_cast<const v8bf*>(&lds[0][ub]);
                am[i] = *reinterpret_cast<const v8bf*>(&lds[1][ub]);
            }
            #pragma unroll
            for (int i = 0; i < 4; ++i) {
                int row = wn * 64 + i * 16 + lr;
                int ub = row * 64 + ((((kk << 2) + g) ^ (row & 7)) << 3);
                bh[i]  = *reinterpret_cast<const v8bf*>(&lds[2][ub]);
                bmv[i] = *reinterpret_cast<const v8bf*>(&lds[3][ub]);
            }
            #pragma unroll
            for (int i = 0; i < 4; ++i)
                #pragma unroll
                for (int j = 0; j < 4; ++j) {
                    acc[i][j] = __builtin_amdgcn_mfma_f32_16x16x32_bf16(ah[i], bh[j],  acc[i][j], 0, 0, 0);
                    acc[i][j] = __builtin_amdgcn_mfma_f32_16x16x32_bf16(ah[i], bmv[j], acc[i][j], 0, 0, 0);
                    acc[i][j] = __builtin_amdgcn_mfma_f32_16x16x32_bf16(am[i], bh[j],  acc[i][j], 0, 0, 0);
                }
        }
    }
    #pragma unroll
    for (int j = 0; j < 4; ++j) {
        int n = bn * 128 + wn * 64 + j * 16 + lr;
        float bv = bias[n];
        #pragma unroll
        for (int i = 0; i < 4; ++i) {
            int mr = bm * 128 + wm * 64 + i * 16 + 4 * g;
            #pragma unroll
            for (int r = 0; r < 4; ++r) {
                float y = acc[i][j][r] + bv;
                if (RELU) y = fmaxf(y, 0.0f);
                size_t idx = (size_t)(mr + r) * N + n;
                if (SPLITOUT) {
                    unsigned int pk = split_pack(y);
                    Ch[idx] = (unsigned short)pk;
                    Cm[idx] = (unsigned short)(pk >> 16);
                } else {
                    Cf[idx] = y;
                }
            }
        }
    }
}

// ---------------------------------------------------------------------------
// V transpose: qkv V-part [tok][h*64+d] -> vt[bh][d][s]. Grid (8 kt, 192 bh).
// ---------------------------------------------------------------------------
__global__ __launch_bounds__(256)
void vtrans_kernel(const unsigned short* __restrict__ qh, const unsigned short* __restrict__ qm,
                   unsigned short* __restrict__ vth, unsigned short* __restrict__ vtm)
{
    __shared__ unsigned short Th[4096], Tm[4096];
    const int kt = blockIdx.x, bh = blockIdx.y;
    const int b = bh / 12, h = bh % 12;
    const int tid = threadIdx.x;
    #pragma unroll
    for (int is = 0; is < 2; ++is) {
        int c = is * 256 + tid;
        int r = c >> 3, dc = c & 7;
        size_t src = ((size_t)b * 512 + kt * 64 + r) * H3 + 1536 + h * 64 + dc * 8;
        int swz = (dc ^ (r & 7) ^ (r >> 3)) * 8;
        *reinterpret_cast<us8*>(&Th[r * 64 + swz]) = *reinterpret_cast<const us8*>(&qh[src]);
        *reinterpret_cast<us8*>(&Tm[r * 64 + swz]) = *reinterpret_cast<const us8*>(&qm[src]);
    }
    __syncthreads();
    #pragma unroll
    for (int is = 0; is < 2; ++is) {
        int c = is * 256 + tid;
        int d = c >> 3, rg = c & 7;
        us8 vh, vm;
        #pragma unroll
        for (int e = 0; e < 8; ++e) {
            int r = rg * 8 + e;
            int addr = r * 64 + (((d >> 3) ^ (r & 7) ^ (r >> 3)) * 8) + (d & 7);
            vh[e] = Th[addr]; vm[e] = Tm[addr];
        }
        size_t dst = ((size_t)bh * 64 + d) * 512 + kt * 64 + rg * 8;
        *reinterpret_cast<us8*>(&vth[dst]) = vh;
        *reinterpret_cast<us8*>(&vtm[dst]) = vm;
    }
}

// ---------------------------------------------------------------------------
// Flash attention v2. Grid (2 q-halves, 192 bh), 4 waves; wave owns 64 q-rows.
// ---------------------------------------------------------------------------
__global__ __launch_bounds__(256, 2)
void attn_kernel(const unsigned short* __restrict__ qh, const unsigned short* __restrict__ qm,
                 const unsigned short* __restrict__ vth, const unsigned short* __restrict__ vtm,
                 unsigned short* __restrict__ ohp, unsigned short* __restrict__ omp)
{
    __shared__ unsigned short Kh[4096], Km[4096], Vh[4096], Vm[4096];
    __shared__ unsigned short Ph[4][1024], Pm[4][1024];
    const int qhalf = blockIdx.x;
    const int bh = blockIdx.y;
    const int b = bh / 12, h = bh % 12;
    const int tid = threadIdx.x, lane = tid & 63, wave = tid >> 6;
    const int g = lane >> 4, lr = lane & 15;
    const size_t rowbase = (size_t)b * 512;
    const int qbase = qhalf * 256 + wave * 64;

    v8bf aqh[4][2], aqm[4][2];
    #pragma unroll
    for (int i = 0; i < 4; ++i)
        #pragma unroll
        for (int kk = 0; kk < 2; ++kk) {
            size_t a = (rowbase + qbase + i * 16 + lr) * H3 + h * 64 + (kk * 4 + g) * 8;
            aqh[i][kk] = *reinterpret_cast<const v8bf*>(&qh[a]);
            aqm[i][kk] = *reinterpret_cast<const v8bf*>(&qm[a]);
        }

    float m_run[4][4], l_run[4][4];
    f32x4 O[4][4];
    #pragma unroll
    for (int i = 0; i < 4; ++i)
        #pragma unroll
        for (int r = 0; r < 4; ++r) {
            m_run[i][r] = -__builtin_inff(); l_run[i][r] = 0.0f;
            O[i][r] = (f32x4){0.0f, 0.0f, 0.0f, 0.0f};
        }

    const int srow = lane >> 3;
    const int schunk = ((lane & 7) ^ srow) * 8;

    for (int kt = 0; kt < 8; ++kt) {
        __syncthreads();
        #pragma unroll
        for (int is = 0; is < 2; ++is) {
            int rowg = is * 32 + wave * 8;
            size_t ksrc = (rowbase + kt * 64 + rowg + srow) * H3 + 768 + h * 64 + schunk;
            size_t vsrc = ((size_t)bh * 64 + rowg + srow) * 512 + kt * 64 + schunk;
            gload16(qh + ksrc, &Kh[rowg * 64]);
            gload16(qm + ksrc, &Km[rowg * 64]);
            gload16(vth + vsrc, &Vh[rowg * 64]);
            gload16(vtm + vsrc, &Vm[rowg * 64]);
        }
        __syncthreads();

        #pragma unroll
        for (int i = 0; i < 4; ++i) {
            f32x4 s[4] = {};
            #pragma unroll
            for (int kk = 0; kk < 2; ++kk) {
                #pragma unroll
                for (int j = 0; j < 4; ++j) {
                    int krow = j * 16 + lr;
                    int uk = krow * 64 + (((kk * 4 + g) ^ (krow & 7)) * 8);
                    v8bf bkh = *reinterpret_cast<const v8bf*>(&Kh[uk]);
                    v8bf bkm = *reinterpret_cast<const v8bf*>(&Km[uk]);
                    s[j] = __builtin_amdgcn_mfma_f32_16x16x32_bf16(aqh[i][kk], bkh, s[j], 0, 0, 0);
                    s[j] = __builtin_amdgcn_mfma_f32_16x16x32_bf16(aqh[i][kk], bkm, s[j], 0, 0, 0);
                    s[j] = __builtin_amdgcn_mfma_f32_16x16x32_bf16(aqm[i][kk], bkh, s[j], 0, 0, 0);
                }
            }
            float mnew[4], alpha[4], rsum[4];
            #pragma unroll
            for (int rr = 0; rr < 4; ++rr) {
                float t = fmaxf(fmaxf(s[0][rr], s[1][rr]), fmaxf(s[2][rr], s[3][rr])) * 0.125f;
                #pragma unroll
                for (int off = 1; off < 16; off <<= 1) t = fmaxf(t, __shfl_xor(t, off));
                mnew[rr] = fmaxf(m_run[i][rr], t);
                alpha[rr] = __expf(m_run[i][rr] - mnew[rr]);
                m_run[i][rr] = mnew[rr];
                rsum[rr] = 0.0f;
            }
            #pragma unroll
            for (int j = 0; j < 4; ++j) {
                #pragma unroll
                for (int rr = 0; rr < 4; ++rr) {
                    float p = __expf(s[j][rr] * 0.125f - mnew[rr]);
                    rsum[rr] += p;
                    int prow = 4 * g + rr;
                    int ub = prow * 64 + ((((j * 2 + (lr >> 3)) ^ (prow & 7)) << 3) | (lr & 7));
                    unsigned int pk = split_pack(p);
                    Ph[wave][ub] = (unsigned short)pk; Pm[wave][ub] = (unsigned short)(pk >> 16);
                }
            }
            #pragma unroll
            for (int rr = 0; rr < 4; ++rr) {
                float t = rsum[rr];
                #pragma unroll
                for (int off = 1; off < 16; off <<= 1) t += __shfl_xor(t, off);
                l_run[i][rr] = l_run[i][rr] * alpha[rr] + t;
                O[i][0][rr] *= alpha[rr]; O[i][1][rr] *= alpha[rr];
                O[i][2][rr] *= alpha[rr]; O[i][3][rr] *= alpha[rr];
            }
            #pragma unroll
            for (int kk = 0; kk < 2; ++kk) {
                int up = lr * 64 + (((kk * 4 + g) ^ (lr & 7)) * 8);
                v8bf aph = *reinterpret_cast<const v8bf*>(&Ph[wave][up]);
                v8bf apm = *reinterpret_cast<const v8bf*>(&Pm[wave][up]);
                #pragma unroll
                for (int j = 0; j < 4; ++j) {
                    int vrow = j * 16 + lr;
                    int uv = vrow * 64 + (((kk * 4 + g) ^ (vrow & 7)) * 8);
                    v8bf bvh = *reinterpret_cast<const v8bf*>(&Vh[uv]);
                    v8bf bvm = *reinterpret_cast<const v8bf*>(&Vm[uv]);
                    O[i][j] = __builtin_amdgcn_mfma_f32_16x16x32_bf16(aph, bvh, O[i][j], 0, 0, 0);
                    O[i][j] = __builtin_amdgcn_mfma_f32_16x16x32_bf16(aph, bvm, O[i][j], 0, 0, 0);
                    O[i][j] = __builtin_amdgcn_mfma_f32_16x16x32_bf16(apm, bvh, O[i][j], 0, 0, 0);
                }
            }
        }
    }
    #pragma unroll
    for (int i = 0; i < 4; ++i)
        #pragma unroll
        for (int j = 0; j < 4; ++j) {
            int d = j * 16 + lr;
            #pragma unroll
            for (int rr = 0; rr < 4; ++rr) {
                size_t tok = rowbase + qbase + i * 16 + 4 * g + rr;
                unsigned int pk = split_pack(O[i][j][rr] / l_run[i][rr]);
                ohp[tok * HD + h * 64 + d] = (unsigned short)pk;
                omp[tok * HD + h * 64 + d] = (unsigned short)(pk >> 16);
            }
        }
}

// ---------------------------------------------------------------------------
// x = LayerNorm((xh+xm) + t) * g + b -> (xh, xm). One wave per token.
// Lane owns 12 CONTIGUOUS columns (vectorized us4/f32x4 loads).
// ---------------------------------------------------------------------------
__global__ __launch_bounds__(256)
void ln_residual_kernel(unsigned short* __restrict__ xh, unsigned short* __restrict__ xm,
                        const float* __restrict__ t,
                        const float* __restrict__ gamma, const float* __restrict__ beta)
{
    int tok = blockIdx.x * 4 + (threadIdx.x >> 6);
    int lane = threadIdx.x & 63;
    size_t base = (size_t)tok * HD + lane * 12;
    int cb = lane * 12;
    us4 h4[3], m4[3]; f32x4 t4[3];
    #pragma unroll
    for (int q = 0; q < 3; ++q) {
        h4[q] = *reinterpret_cast<const us4*>(&xh[base + q * 4]);
        m4[q] = *reinterpret_cast<const us4*>(&xm[base + q * 4]);
        t4[q] = *reinterpret_cast<const f32x4*>(&t[base + q * 4]);
    }
    float v[12];
    float s = 0.0f;
    #pragma unroll
    for (int k = 0; k < 12; ++k) {
        v[k] = bf2f(h4[k >> 2][k & 3]) + bf2f(m4[k >> 2][k & 3]) + t4[k >> 2][k & 3];
        s += v[k];
    }
    #pragma unroll
    for (int off = 32; off; off >>= 1) s += __shfl_xor(s, off);
    float mean = s * (1.0f / 768.0f);
    float vs = 0.0f;
    #pragma unroll
    for (int k = 0; k < 12; ++k) { float d = v[k] - mean; vs += d * d; }
    #pragma unroll
    for (int off = 32; off; off >>= 1) vs += __shfl_xor(vs, off);
    float rstd = rsqrtf(vs * (1.0f / 768.0f) + 1e-5f);
    f32x4 ga[3], be[3];
    #pragma unroll
    for (int q = 0; q < 3; ++q) {
        ga[q] = *reinterpret_cast<const f32x4*>(&gamma[cb + q * 4]);
        be[q] = *reinterpret_cast<const f32x4*>(&beta[cb + q * 4]);
    }
    us4 oh[3], om[3];
    #pragma unroll
    for (int k = 0; k < 12; ++k) {
        float y = (v[k] - mean) * rstd * ga[k >> 2][k & 3] + be[k >> 2][k & 3];
        unsigned int pk = split_pack(y);
        oh[k >> 2][k & 3] = (unsigned short)pk;
        om[k >> 2][k & 3] = (unsigned short)(pk >> 16);
    }
    #pragma unroll
    for (int q = 0; q < 3; ++q) {
        *reinterpret_cast<us4*>(&xh[base + q * 4]) = oh[q];
        *reinterpret_cast<us4*>(&xm[base + q * 4]) = om[q];
    }
}

__global__ __launch_bounds__(256)
void embed_kernel(const int* __restrict__ ids, const float* __restrict__ emb,
                  unsigned short* __restrict__ xh, unsigned short* __restrict__ xm)
{
    int f4 = blockIdx.x * 256 + threadIdx.x;     // 8192*192 float4
    int tok = f4 / 192, c = f4 % 192;
    float4 v = *reinterpret_cast<const float4*>(emb + (size_t)ids[tok] * HD + c * 4);
    us4 hv, mv; unsigned int p;
    p = split_pack(v.x); hv[0] = (unsigned short)p; mv[0] = (unsigned short)(p >> 16);
    p = split_pack(v.y); hv[1] = (unsigned short)p; mv[1] = (unsigned short)(p >> 16);
    p = split_pack(v.z); hv[2] = (unsigned short)p; mv[2] = (unsigned short)(p >> 16);
    p = split_pack(v.w); hv[3] = (unsigned short)p; mv[3] = (unsigned short)(p >> 16);
    *reinterpret_cast<us4*>(&xh[(size_t)tok * HD + c * 4]) = hv;
    *reinterpret_cast<us4*>(&xm[(size_t)tok * HD + c * 4]) = mv;
}

// logits f32 = xh + xm
__global__ __launch_bounds__(256)
void out_logits_kernel(const unsigned short* __restrict__ xh, const unsigned short* __restrict__ xm,
                       float* __restrict__ out)
{
    int i = blockIdx.x * 256 + threadIdx.x;
    us4 hv = reinterpret_cast<const us4*>(xh)[i];
    us4 mv = reinterpret_cast<const us4*>(xm)[i];
    float4 o;
    o.x = bf2f(hv[0]) + bf2f(mv[0]);
    o.y = bf2f(hv[1]) + bf2f(mv[1]);
    o.z = bf2f(hv[2]) + bf2f(mv[2]);
    o.w = bf2f(hv[3]) + bf2f(mv[3]);
    reinterpret_cast<float4*>(out)[i] = o;
}

// emis[tok][t] = dot768(x[tok], head_w[t]) + head_b[t] — wave per token
__global__ __launch_bounds__(256)
void emis_kernel(const unsigned short* __restrict__ xh, const unsigned short* __restrict__ xm,
                 const float* __restrict__ hw, const float* __restrict__ hb,
                 float* __restrict__ emis)
{
    int tok = blockIdx.x * 4 + (threadIdx.x >> 6);
    int lane = threadIdx.x & 63;
    size_t base = (size_t)tok * HD + lane * 12;
    int cb = lane * 12;
    us4 h4[3], m4[3];
    #pragma unroll
    for (int q = 0; q < 3; ++q) {
        h4[q] = *reinterpret_cast<const us4*>(&xh[base + q * 4]);
        m4[q] = *reinterpret_cast<const us4*>(&xm[base + q * 4]);
    }
    float xv[12];
    #pragma unroll
    for (int k = 0; k < 12; ++k)
        xv[k] = bf2f(h4[k >> 2][k & 3]) + bf2f(m4[k >> 2][k & 3]);
    for (int t = 0; t < TT; ++t) {
        f32x4 w4[3];
        #pragma unroll
        for (int q = 0; q < 3; ++q)
            w4[q] = *reinterpret_cast<const f32x4*>(&hw[t * HD + cb + q * 4]);
        float a = 0.0f;
        #pragma unroll
        for (int k = 0; k < 12; ++k) a += xv[k] * w4[k >> 2][k & 3];
        #pragma unroll
        for (int off = 32; off; off >>= 1) a += __shfl_xor(a, off);
        if (lane == 0) emis[(size_t)tok * TT + t] = a + hb[t];
    }
}

__global__ void crf_num_kernel(const float* __restrict__ emis, const int* __restrict__ labels,
                               const float* __restrict__ start, const float* __restrict__ end,
                               const float* __restrict__ trans, float* __restrict__ num)
{
    int b = blockIdx.x, lane = threadIdx.x;   // blockDim 64
    float a = 0.0f;
    for (int s = lane; s < 512; s += 64) {
        int lab = labels[b * 512 + s];
        a += emis[(size_t)(b * 512 + s) * TT + lab];
        if (s > 0) a += trans[labels[b * 512 + s - 1] * TT + lab];
        else a += start[lab];
        if (s == 511) a += end[lab];
    }
    #pragma unroll
    for (int off = 32; off; off >>= 1) a += __shfl_xor(a, off);
    if (lane == 0) num[b] = a;
}

// ---------------------------------------------------------------------------
// Fused CRF forward + viterbi v3. ONE LDS round-trip per step.
// Forward: tree-sum of exp(sc_i - r)*E_ij (logZ tolerance is huge).
// Viterbi: exact max tree with (a>=b)?left:right -> first-max argmax,
// bit-identical to the serial reference scan.
// ---------------------------------------------------------------------------
__global__ __launch_bounds__(64)
void crf_path_kernel(const float* __restrict__ emis, const float* __restrict__ start,
                     const float* __restrict__ end, const float* __restrict__ trans,
                     float* __restrict__ logZ, float* __restrict__ out_tags)
{
    const int mode = blockIdx.x >> 4;
    const int b = blockIdx.x & 15;
    const int lane = threadIdx.x;
    const int j = lane & 31;
    __shared__ float xch[32];
    __shared__ unsigned char hist[511][32];
    __shared__ float sval[32];
    __shared__ int path[512];

    const float* eb = emis + (size_t)b * 512 * TT;

    if (mode == 0) {
        if (lane < 32) {
            float Ecol[32];
            #pragma unroll
            for (int ii = 0; ii < 32; ++ii) Ecol[ii] = __expf(trans[ii * TT + j]);
            float cur[8], nxt[8];
            #pragma unroll
            for (int i = 0; i < 8; ++i) cur[i] = eb[(1 + i) * TT + j];
            float sc = start[j] + eb[j];
            for (int base = 1; base < 512; base += 8) {
                #pragma unroll
                for (int i = 0; i < 8; ++i) {
                    int s = base + 8 + i;
                    nxt[i] = eb[(s < 512 ? s : 511) * TT + j];
                }
                #pragma unroll
                for (int i = 0; i < 8; ++i) {
                    if (base + i < 512) {
                        xch[j] = sc;
                        asm volatile("s_waitcnt lgkmcnt(0)" ::: "memory");
                        f32x4 tt[8];
                        #pragma unroll
                        for (int q = 0; q < 8; ++q)
                            tt[q] = *reinterpret_cast<const f32x4*>(&xch[q * 4]);
                        asm volatile("" ::: "memory");
                        float r = tt[0][0];
                        float m[32];
                        #pragma unroll
                        for (int ii = 0; ii < 32; ++ii)
                            m[ii] = __expf(tt[ii >> 2][ii & 3] - r) * Ecol[ii];
                        float s16[16];
                        #pragma unroll
                        for (int q = 0; q < 16; ++q) s16[q] = m[2 * q] + m[2 * q + 1];
                        float s8[8];
                        #pragma unroll
                        for (int q = 0; q < 8; ++q) s8[q] = s16[2 * q] + s16[2 * q + 1];
                        float sA[4];
                        #pragma unroll
                        for (int q = 0; q < 4; ++q) sA[q] = s8[2 * q] + s8[2 * q + 1];
                        float dot = (sA[0] + sA[1]) + (sA[2] + sA[3]);
                        sc = r + __logf(dot) + cur[i];
                    }
                }
                #pragma unroll
                for (int i = 0; i < 8; ++i) cur[i] = nxt[i];
            }
            float v = sc + end[j];
            float mx = v;
            #pragma unroll
            for (int off = 1; off < 32; off <<= 1) mx = fmaxf(mx, __shfl_xor(mx, off));
            float p = __expf(v - mx);
            float sm = p;
            #pragma unroll
            for (int off = 1; off < 32; off <<= 1) sm += __shfl_xor(sm, off);
            if (lane == 0) logZ[b] = mx + __logf(sm);
        }
    } else {
        if (lane < 32) {
            float tcol[32];
            #pragma unroll
            for (int ii = 0; ii < 32; ++ii) tcol[ii] = trans[ii * TT + j];
            float cur[8], nxt[8];
            #pragma unroll
            for (int i = 0; i < 8; ++i) cur[i] = eb[(1 + i) * TT + j];
            float sc = start[j] + eb[j];
            for (int base = 1; base < 512; base += 8) {
                #pragma unroll
                for (int i = 0; i < 8; ++i) {
                    int s = base + 8 + i;
                    nxt[i] = eb[(s < 512 ? s : 511) * TT + j];
                }
                #pragma unroll
                for (int i = 0; i < 8; ++i) {
                    if (base + i < 512) {
                        int s = base + i;
                        xch[j] = sc;
                        asm volatile("s_waitcnt lgkmcnt(0)" ::: "memory");
                        f32x4 tt[8];
                        #pragma unroll
                        for (int q = 0; q < 8; ++q)
                            tt[q] = *reinterpret_cast<const f32x4*>(&xch[q * 4]);
                        asm volatile("" ::: "memory");
                        float c[32];
                        #pragma unroll
                        for (int ii = 0; ii < 32; ++ii)
                            c[ii] = tt[ii >> 2][ii & 3] + tcol[ii];
                        // exact first-max argmax tree: left subtree = lower indices,
                        // (a >= b) keeps the left (earlier) argmax on ties.
                        float v1[16]; int a1[16];
                        #pragma unroll
                        for (int q = 0; q < 16; ++q) {
                            bool ge = c[2 * q] >= c[2 * q + 1];
                            v1[q] = ge ? c[2 * q] : c[2 * q + 1];
                            a1[q] = ge ? 2 * q : 2 * q + 1;
                        }
                        float v2[8]; int a2[8];
                        #pragma unroll
                        for (int q = 0; q < 8; ++q) {
                            bool ge = v1[2 * q] >= v1[2 * q + 1];
                            v2[q] = ge ? v1[2 * q] : v1[2 * q + 1];
                            a2[q] = ge ? a1[2 * q] : a1[2 * q + 1];
                        }
                        float v3[4]; int a3[4];
                        #pragma unroll
                        for (int q = 0; q < 4; ++q) {
                            bool ge = v2[2 * q] >= v2[2 * q + 1];
                            v3[q] = ge ? v2[2 * q] : v2[2 * q + 1];
                            a3[q] = ge ? a2[2 * q] : a2[2 * q + 1];
                        }
                        float v4[2]; int a4[2];
                        #pragma unroll
                        for (int q = 0; q < 2; ++q) {
                            bool ge = v3[2 * q] >= v3[2 * q + 1];
                            v4[q] = ge ? v3[2 * q] : v3[2 * q + 1];
                            a4[q] = ge ? a3[2 * q] : a3[2 * q + 1];
                        }
                        bool ge = v4[0] >= v4[1];
                        float best = ge ? v4[0] : v4[1];
                        int arg = ge ? a4[0] : a4[1];
                        hist[s - 1][j] = (unsigned char)arg;
                        sc = best + cur[i];
                    }
                }
                #pragma unroll
                for (int i = 0; i < 8; ++i) cur[i] = nxt[i];
            }
            sval[j] = sc + end[j];
        }
        __syncthreads();
        if (lane == 0) {
            float best = sval[0]; int arg = 0;
            for (int i = 1; i < TT; ++i)
                if (sval[i] > best) { best = sval[i]; arg = i; }
            int t = arg; path[511] = t;
            for (int s = 510; s >= 0; --s) { t = hist[s][t]; path[s] = t; }
        }
        __syncthreads();
        for (int s = lane; s < 512; s += 64)
            out_tags[(size_t)b * 512 + s] = (float)path[s];
    }
}

__global__ void crf_loss_kernel(const float* __restrict__ num, const float* __restrict__ logZ,
                                float* __restrict__ out)
{
    if (threadIdx.x == 0) {
        float s = 0.0f;
        for (int b = 0; b < 16; ++b) s += num[b] - logZ[b];
        out[0] = -s / 10000.0f;
    }
}

extern "C" void kernel_launch(void* const* d_in, const int* in_sizes, int n_in,
                              void* d_out, int out_size, void* d_ws, size_t ws_size,
                              hipStream_t stream)
{
    (void)in_sizes; (void)n_in; (void)out_size; (void)ws_size;
    const int*   input_ids = (const int*)d_in[0];
    const int*   labels    = (const int*)d_in[1];
    const float* emb   = (const float*)d_in[3];
    const float* in_w  = (const float*)d_in[4];
    const float* in_b  = (const float*)d_in[5];
    const float* out_w = (const float*)d_in[6];
    const float* out_b = (const float*)d_in[7];
    const float* ln1g  = (const float*)d_in[8];
    const float* ln1b  = (const float*)d_in[9];
    const float* ln2g  = (const float*)d_in[10];
    const float* ln2b  = (const float*)d_in[11];
    const float* w1    = (const float*)d_in[12];
    const float* b1    = (const float*)d_in[13];
    const float* w2    = (const float*)d_in[14];
    const float* b2    = (const float*)d_in[15];
    const float* hw    = (const float*)d_in[16];
    const float* hb    = (const float*)d_in[17];
    const float* cs    = (const float*)d_in[18];
    const float* ce    = (const float*)d_in[19];
    const float* ct    = (const float*)d_in[20];
    float* out = (float*)d_out;

    char* ws = (char*)d_ws;
    unsigned short* xh   = (unsigned short*)(ws);
    unsigned short* xm   = (unsigned short*)(ws + 12582912);
    unsigned short* qkvh = (unsigned short*)(ws + 25165824);
    unsigned short* qkvm = (unsigned short*)(ws + 62914560);
    unsigned short* ohb  = (unsigned short*)(ws + 100663296);
    unsigned short* omb  = (unsigned short*)(ws + 113246208);
    float*          tmp  = (float*)(ws + 125829120);
    unsigned short* vth  = (unsigned short*)(ws + 125829120);  // alias tmp (disjoint lifetime)
    unsigned short* vtm  = (unsigned short*)(ws + 138412032);
    unsigned short* wih  = (unsigned short*)(ws + 150994944);
    unsigned short* wim  = (unsigned short*)(ws + 154533888);
    unsigned short* woh  = (unsigned short*)(ws + 158072832);
    unsigned short* wom  = (unsigned short*)(ws + 159252480);
    unsigned short* w1h  = (unsigned short*)(ws + 160432128);
    unsigned short* w1m  = (unsigned short*)(ws + 161611776);
    unsigned short* w2h  = (unsigned short*)(ws + 162791424);
    unsigned short* w2m  = (unsigned short*)(ws + 163971072);
    unsigned short* f1h  = qkvh;   // qkv dead after attn
    unsigned short* f1m  = qkvm;
    float* emis = (float*)(ws + 100663296);                // alias ohb (dead post-encoder)
    float* numb = (float*)(ws + 100663296 + 1048576);
    float* logZ = numb + 16;

    embed_kernel<<<MTOK * 192 / 256, 256, 0, stream>>>(input_ids, emb, xh, xm);

    for (int l = 0; l < NL; ++l) {
        wsplit4_kernel<<<3456, 256, 0, stream>>>(
            in_w + (size_t)l * H3 * HD, out_w + (size_t)l * HD * HD,
            w1 + (size_t)l * HD * HD, w2 + (size_t)l * HD * HD,
            wih, wim, woh, wom, w1h, w1m, w2h, w2m);

        gemm_pair_kernel<false, true><<<dim3(18, 64), 256, 0, stream>>>(
            xh, xm, wih, wim, in_b + (size_t)l * H3, nullptr, qkvh, qkvm, H3);
        vtrans_kernel<<<dim3(8, 192), 256, 0, stream>>>(qkvh, qkvm, vth, vtm);
        attn_kernel<<<dim3(2, 192), 256, 0, stream>>>(qkvh, qkvm, vth, vtm, ohb, omb);
        gemm_pair_kernel<false, false><<<dim3(6, 64), 256, 0, stream>>>(
            ohb, omb, woh, wom, out_b + (size_t)l * HD, tmp, nullptr, nullptr, HD);
        ln_residual_kernel<<<2048, 256, 0, stream>>>(xh, xm, tmp, ln1g + l * HD, ln1b + l * HD);
        gemm_pair_kernel<true, true><<<dim3(6, 64), 256, 0, stream>>>(
            xh, xm, w1h, w1m, b1 + (size_t)l * HD, nullptr, f1h, f1m, HD);
        gemm_pair_kernel<false, false><<<dim3(6, 64), 256, 0, stream>>>(
            f1h, f1m, w2h, w2m, b2 + (size_t)l * HD, tmp, nullptr, nullptr, HD);
        ln_residual_kernel<<<2048, 256, 0, stream>>>(xh, xm, tmp, ln2g + l * HD, ln2b + l * HD);
    }

    out_logits_kernel<<<MTOK * 192 / 256, 256, 0, stream>>>(xh, xm, out);

    emis_kernel<<<2048, 256, 0, stream>>>(xh, xm, hw, hb, emis);
    crf_num_kernel<<<16, 64, 0, stream>>>(emis, labels, cs, ce, ct, numb);
    crf_path_kernel<<<32, 64, 0, stream>>>(emis, cs, ce, ct, logZ, out + 6291457);
    crf_loss_kernel<<<1, 64, 0, stream>>>(numb, logZ, out + 6291456);
}

// Round 9
// 2238.647 us; speedup vs baseline: 3.0037x; 1.0257x over previous
//
#include <hip/hip_runtime.h>

#define MTOK 8192      // B*S
#define HD   768
#define H3   2304
#define NL   6
#define TT   32        // CRF tags (reference: T = 32)

typedef __attribute__((ext_vector_type(4))) float f32x4;
typedef __attribute__((ext_vector_type(8))) short v8bf;     // 8 bf16 in 4 VGPRs
typedef __attribute__((ext_vector_type(4))) unsigned short us4;
typedef __attribute__((ext_vector_type(8))) unsigned short us8;

__device__ __forceinline__ unsigned short bf16rne(float v) {
    unsigned int u = __float_as_uint(v);
    u += 0x7FFFu + ((u >> 16) & 1u);
    return (unsigned short)(u >> 16);
}
__device__ __forceinline__ float bf2f(unsigned short h) {
    return __uint_as_float(((unsigned int)h) << 16);
}
// hi bf16 in low 16 bits, mid (residual) bf16 in high 16 bits
__device__ __forceinline__ unsigned int split_pack(float v) {
    unsigned short h = bf16rne(v);
    unsigned short m = bf16rne(v - bf2f(h));
    return (unsigned int)h | ((unsigned int)m << 16);
}

// async global->LDS, 16B per lane, LDS dest = wave-uniform base + lane*16
__device__ __forceinline__ void gload16(const unsigned short* g, unsigned short* l) {
    __builtin_amdgcn_global_load_lds(
        (const __attribute__((address_space(1))) unsigned int*)g,
        (__attribute__((address_space(3))) unsigned int*)l, 16, 0, 0);
}

// ---------------------------------------------------------------------------
// Fused weight split for one layer: in_w (2304x768), out_w, w1, w2 (768x768).
// ---------------------------------------------------------------------------
__global__ __launch_bounds__(256)
void wsplit4_kernel(const float* __restrict__ inw, const float* __restrict__ outw,
                    const float* __restrict__ w1, const float* __restrict__ w2,
                    unsigned short* __restrict__ wih, unsigned short* __restrict__ wim,
                    unsigned short* __restrict__ woh, unsigned short* __restrict__ wom,
                    unsigned short* __restrict__ w1h, unsigned short* __restrict__ w1m,
                    unsigned short* __restrict__ w2h, unsigned short* __restrict__ w2m)
{
    int i = blockIdx.x * 256 + threadIdx.x;      // 884736 float4 total
    const float* src; unsigned short* dh; unsigned short* dm; int off;
    if (i < 442368)      { src = inw;  dh = wih; dm = wim; off = i; }
    else if (i < 589824) { src = outw; dh = woh; dm = wom; off = i - 442368; }
    else if (i < 737280) { src = w1;   dh = w1h; dm = w1m; off = i - 589824; }
    else                 { src = w2;   dh = w2h; dm = w2m; off = i - 737280; }
    float4 v = reinterpret_cast<const float4*>(src)[off];
    us4 hv, mv; unsigned int p;
    p = split_pack(v.x); hv[0] = (unsigned short)p; mv[0] = (unsigned short)(p >> 16);
    p = split_pack(v.y); hv[1] = (unsigned short)p; mv[1] = (unsigned short)(p >> 16);
    p = split_pack(v.z); hv[2] = (unsigned short)p; mv[2] = (unsigned short)(p >> 16);
    p = split_pack(v.w); hv[3] = (unsigned short)p; mv[3] = (unsigned short)(p >> 16);
    reinterpret_cast<us4*>(dh)[off] = hv;
    reinterpret_cast<us4*>(dm)[off] = mv;
}

// ---------------------------------------------------------------------------
// GEMM on pre-split operands, 3 products (hh, hm, mh). XCD-swizzled grid.
// ---------------------------------------------------------------------------
template<bool RELU, bool SPLITOUT>
__global__ __launch_bounds__(256)
void gemm_pair_kernel(const unsigned short* __restrict__ Ahg, const unsigned short* __restrict__ Amg,
                      const unsigned short* __restrict__ Bhg, const unsigned short* __restrict__ Bmg,
                      const float* __restrict__ bias, float* __restrict__ Cf,
                      unsigned short* __restrict__ Ch, unsigned short* __restrict__ Cm, int N)
{
    __shared__ unsigned short lds[4][128 * 64];   // Ah, Am, Bh, Bm tiles (64 KB)
    const int tid = threadIdx.x;
    const int lane = tid & 63, wave = tid >> 6;
    const int wm = wave >> 1, wn = wave & 1;
    // bijective XCD swizzle (grid total % 8 == 0)
    const int nbx = gridDim.x;
    const int total = nbx * gridDim.y;
    const int flat = blockIdx.y * nbx + blockIdx.x;
    const int sw = (flat & 7) * (total >> 3) + (flat >> 3);
    const int bn = sw % nbx, bm = sw / nbx;
    const int g = lane >> 4, lr = lane & 15;

    const int srow = lane >> 3;
    const int schunk = ((lane & 7) ^ srow) * 8;   // pre-swizzled source chunk (shorts)
    const size_t aoff = ((size_t)(bm * 128 + wave * 32 + srow)) * HD + schunk;
    const size_t boff = ((size_t)(bn * 128 + wave * 32 + srow)) * HD + schunk;

    f32x4 acc[4][4] = {};

    for (int kt = 0; kt < 12; ++kt) {
        __syncthreads();
        const int k64 = kt * 64;
        #pragma unroll
        for (int i = 0; i < 4; ++i) {
            const size_t ra = aoff + (size_t)i * 8 * HD + k64;
            const size_t rb = boff + (size_t)i * 8 * HD + k64;
            unsigned short* lb = (unsigned short*)&lds[0][(wave * 32 + i * 8) * 64];
            gload16(Ahg + ra, lb);
            gload16(Amg + ra, lb + 8192);
            gload16(Bhg + rb, lb + 16384);
            gload16(Bmg + rb, lb + 24576);
        }
        __syncthreads();
        #pragma unroll
        for (int kk = 0; kk < 2; ++kk) {
            v8bf ah[4], am[4], bh[4], bmv[4];
            #pragma unroll
            for (int i = 0; i < 4; ++i) {
                int row = wm * 64 + i * 16 + lr;
                int ub = row * 64 + ((((kk << 2) + g) ^ (row & 7)) << 3);
                ah[i] = *reinterpret_cast<const v8bf*>(&lds[0][ub]);
                am[i] = *reinterpret_cast<const v8bf*>(&lds[1][ub]);
            }
            #pragma unroll
            for (int i = 0; i < 4; ++i) {
                int row = wn * 64 + i * 16 + lr;
                int ub = row * 64 + ((((kk << 2) + g) ^ (row & 7)) << 3);
                bh[i]  = *reinterpret_cast<const v8bf*>(&lds[2][ub]);
                bmv[i] = *reinterpret_cast<const v8bf*>(&lds[3][ub]);
            }
            #pragma unroll
            for (int i = 0; i < 4; ++i)
                #pragma unroll
                for (int j = 0; j < 4; ++j) {
                    acc[i][j] = __builtin_amdgcn_mfma_f32_16x16x32_bf16(ah[i], bh[j],  acc[i][j], 0, 0, 0);
                    acc[i][j] = __builtin_amdgcn_mfma_f32_16x16x32_bf16(ah[i], bmv[j], acc[i][j], 0, 0, 0);
                    acc[i][j] = __builtin_amdgcn_mfma_f32_16x16x32_bf16(am[i], bh[j],  acc[i][j], 0, 0, 0);
                }
        }
    }
    #pragma unroll
    for (int j = 0; j < 4; ++j) {
        int n = bn * 128 + wn * 64 + j * 16 + lr;
        float bv = bias[n];
        #pragma unroll
        for (int i = 0; i < 4; ++i) {
            int mr = bm * 128 + wm * 64 + i * 16 + 4 * g;
            #pragma unroll
            for (int r = 0; r < 4; ++r) {
                float y = acc[i][j][r] + bv;
                if (RELU) y = fmaxf(y, 0.0f);
                size_t idx = (size_t)(mr + r) * N + n;
                if (SPLITOUT) {
                    unsigned int pk = split_pack(y);
                    Ch[idx] = (unsigned short)pk;
                    Cm[idx] = (unsigned short)(pk >> 16);
                } else {
                    Cf[idx] = y;
                }
            }
        }
    }
}

// ---------------------------------------------------------------------------
// V transpose: qkv V-part [tok][h*64+d] -> vt[bh][d][s]. Grid (8 kt, 192 bh).
// ---------------------------------------------------------------------------
__global__ __launch_bounds__(256)
void vtrans_kernel(const unsigned short* __restrict__ qh, const unsigned short* __restrict__ qm,
                   unsigned short* __restrict__ vth, unsigned short* __restrict__ vtm)
{
    __shared__ unsigned short Th[4096], Tm[4096];
    const int kt = blockIdx.x, bh = blockIdx.y;
    const int b = bh / 12, h = bh % 12;
    const int tid = threadIdx.x;
    #pragma unroll
    for (int is = 0; is < 2; ++is) {
        int c = is * 256 + tid;
        int r = c >> 3, dc = c & 7;
        size_t src = ((size_t)b * 512 + kt * 64 + r) * H3 + 1536 + h * 64 + dc * 8;
        int swz = (dc ^ (r & 7) ^ (r >> 3)) * 8;
        *reinterpret_cast<us8*>(&Th[r * 64 + swz]) = *reinterpret_cast<const us8*>(&qh[src]);
        *reinterpret_cast<us8*>(&Tm[r * 64 + swz]) = *reinterpret_cast<const us8*>(&qm[src]);
    }
    __syncthreads();
    #pragma unroll
    for (int is = 0; is < 2; ++is) {
        int c = is * 256 + tid;
        int d = c >> 3, rg = c & 7;
        us8 vh, vm;
        #pragma unroll
        for (int e = 0; e < 8; ++e) {
            int r = rg * 8 + e;
            int addr = r * 64 + (((d >> 3) ^ (r & 7) ^ (r >> 3)) * 8) + (d & 7);
            vh[e] = Th[addr]; vm[e] = Tm[addr];
        }
        size_t dst = ((size_t)bh * 64 + d) * 512 + kt * 64 + rg * 8;
        *reinterpret_cast<us8*>(&vth[dst]) = vh;
        *reinterpret_cast<us8*>(&vtm[dst]) = vm;
    }
}

// ---------------------------------------------------------------------------
// Flash attention v2. Grid (2 q-halves, 192 bh), 4 waves; wave owns 64 q-rows.
// ---------------------------------------------------------------------------
__global__ __launch_bounds__(256, 2)
void attn_kernel(const unsigned short* __restrict__ qh, const unsigned short* __restrict__ qm,
                 const unsigned short* __restrict__ vth, const unsigned short* __restrict__ vtm,
                 unsigned short* __restrict__ ohp, unsigned short* __restrict__ omp)
{
    __shared__ unsigned short Kh[4096], Km[4096], Vh[4096], Vm[4096];
    __shared__ unsigned short Ph[4][1024], Pm[4][1024];
    const int qhalf = blockIdx.x;
    const int bh = blockIdx.y;
    const int b = bh / 12, h = bh % 12;
    const int tid = threadIdx.x, lane = tid & 63, wave = tid >> 6;
    const int g = lane >> 4, lr = lane & 15;
    const size_t rowbase = (size_t)b * 512;
    const int qbase = qhalf * 256 + wave * 64;

    v8bf aqh[4][2], aqm[4][2];
    #pragma unroll
    for (int i = 0; i < 4; ++i)
        #pragma unroll
        for (int kk = 0; kk < 2; ++kk) {
            size_t a = (rowbase + qbase + i * 16 + lr) * H3 + h * 64 + (kk * 4 + g) * 8;
            aqh[i][kk] = *reinterpret_cast<const v8bf*>(&qh[a]);
            aqm[i][kk] = *reinterpret_cast<const v8bf*>(&qm[a]);
        }

    float m_run[4][4], l_run[4][4];
    f32x4 O[4][4];
    #pragma unroll
    for (int i = 0; i < 4; ++i)
        #pragma unroll
        for (int r = 0; r < 4; ++r) {
            m_run[i][r] = -__builtin_inff(); l_run[i][r] = 0.0f;
            O[i][r] = (f32x4){0.0f, 0.0f, 0.0f, 0.0f};
        }

    const int srow = lane >> 3;
    const int schunk = ((lane & 7) ^ srow) * 8;

    for (int kt = 0; kt < 8; ++kt) {
        __syncthreads();
        #pragma unroll
        for (int is = 0; is < 2; ++is) {
            int rowg = is * 32 + wave * 8;
            size_t ksrc = (rowbase + kt * 64 + rowg + srow) * H3 + 768 + h * 64 + schunk;
            size_t vsrc = ((size_t)bh * 64 + rowg + srow) * 512 + kt * 64 + schunk;
            gload16(qh + ksrc, &Kh[rowg * 64]);
            gload16(qm + ksrc, &Km[rowg * 64]);
            gload16(vth + vsrc, &Vh[rowg * 64]);
            gload16(vtm + vsrc, &Vm[rowg * 64]);
        }
        __syncthreads();

        #pragma unroll
        for (int i = 0; i < 4; ++i) {
            f32x4 s[4] = {};
            #pragma unroll
            for (int kk = 0; kk < 2; ++kk) {
                #pragma unroll
                for (int j = 0; j < 4; ++j) {
                    int krow = j * 16 + lr;
                    int uk = krow * 64 + (((kk * 4 + g) ^ (krow & 7)) * 8);
                    v8bf bkh = *reinterpret_cast<const v8bf*>(&Kh[uk]);
                    v8bf bkm = *reinterpret_cast<const v8bf*>(&Km[uk]);
                    s[j] = __builtin_amdgcn_mfma_f32_16x16x32_bf16(aqh[i][kk], bkh, s[j], 0, 0, 0);
                    s[j] = __builtin_amdgcn_mfma_f32_16x16x32_bf16(aqh[i][kk], bkm, s[j], 0, 0, 0);
                    s[j] = __builtin_amdgcn_mfma_f32_16x16x32_bf16(aqm[i][kk], bkh, s[j], 0, 0, 0);
                }
            }
            float mnew[4], alpha[4], rsum[4];
            #pragma unroll
            for (int rr = 0; rr < 4; ++rr) {
                float t = fmaxf(fmaxf(s[0][rr], s[1][rr]), fmaxf(s[2][rr], s[3][rr])) * 0.125f;
                #pragma unroll
                for (int off = 1; off < 16; off <<= 1) t = fmaxf(t, __shfl_xor(t, off));
                mnew[rr] = fmaxf(m_run[i][rr], t);
                alpha[rr] = __expf(m_run[i][rr] - mnew[rr]);
                m_run[i][rr] = mnew[rr];
                rsum[rr] = 0.0f;
            }
            #pragma unroll
            for (int j = 0; j < 4; ++j) {
                #pragma unroll
                for (int rr = 0; rr < 4; ++rr) {
                    float p = __expf(s[j][rr] * 0.125f - mnew[rr]);
                    rsum[rr] += p;
                    int prow = 4 * g + rr;
                    int ub = prow * 64 + ((((j * 2 + (lr >> 3)) ^ (prow & 7)) << 3) | (lr & 7));
                    unsigned int pk = split_pack(p);
                    Ph[wave][ub] = (unsigned short)pk; Pm[wave][ub] = (unsigned short)(pk >> 16);
                }
            }
            #pragma unroll
            for (int rr = 0; rr < 4; ++rr) {
                float t = rsum[rr];
                #pragma unroll
                for (int off = 1; off < 16; off <<= 1) t += __shfl_xor(t, off);
                l_run[i][rr] = l_run[i][rr] * alpha[rr] + t;
                O[i][0][rr] *= alpha[rr]; O[i][1][rr] *= alpha[rr];
                O[i][2][rr] *= alpha[rr]; O[i][3][rr] *= alpha[rr];
            }
            #pragma unroll
            for (int kk = 0; kk < 2; ++kk) {
                int up = lr * 64 + (((kk * 4 + g) ^ (lr & 7)) * 8);
                v8bf aph = *reinterpret_cast<const v8bf*>(&Ph[wave][up]);
                v8bf apm = *reinterpret_cast<const v8bf*>(&Pm[wave][up]);
                #pragma unroll
                for (int j = 0; j < 4; ++j) {
                    int vrow = j * 16 + lr;
                    int uv = vrow * 64 + (((kk * 4 + g) ^ (vrow & 7)) * 8);
                    v8bf bvh = *reinterpret_cast<const v8bf*>(&Vh[uv]);
                    v8bf bvm = *reinterpret_cast<const v8bf*>(&Vm[uv]);
                    O[i][j] = __builtin_amdgcn_mfma_f32_16x16x32_bf16(aph, bvh, O[i][j], 0, 0, 0);
                    O[i][j] = __builtin_amdgcn_mfma_f32_16x16x32_bf16(aph, bvm, O[i][j], 0, 0, 0);
                    O[i][j] = __builtin_amdgcn_mfma_f32_16x16x32_bf16(apm, bvh, O[i][j], 0, 0, 0);
                }
            }
        }
    }
    #pragma unroll
    for (int i = 0; i < 4; ++i)
        #pragma unroll
        for (int j = 0; j < 4; ++j) {
            int d = j * 16 + lr;
            #pragma unroll
            for (int rr = 0; rr < 4; ++rr) {
                size_t tok = rowbase + qbase + i * 16 + 4 * g + rr;
                unsigned int pk = split_pack(O[i][j][rr] / l_run[i][rr]);
                ohp[tok * HD + h * 64 + d] = (unsigned short)pk;
                omp[tok * HD + h * 64 + d] = (unsigned short)(pk >> 16);
            }
        }
}

// ---------------------------------------------------------------------------
// x = LayerNorm((xh+xm) + t) * g + b -> (xh, xm). One wave per token.
// ---------------------------------------------------------------------------
__global__ __launch_bounds__(256)
void ln_residual_kernel(unsigned short* __restrict__ xh, unsigned short* __restrict__ xm,
                        const float* __restrict__ t,
                        const float* __restrict__ gamma, const float* __restrict__ beta)
{
    int tok = blockIdx.x * 4 + (threadIdx.x >> 6);
    int lane = threadIdx.x & 63;
    size_t base = (size_t)tok * HD + lane * 12;
    int cb = lane * 12;
    us4 h4[3], m4[3]; f32x4 t4[3];
    #pragma unroll
    for (int q = 0; q < 3; ++q) {
        h4[q] = *reinterpret_cast<const us4*>(&xh[base + q * 4]);
        m4[q] = *reinterpret_cast<const us4*>(&xm[base + q * 4]);
        t4[q] = *reinterpret_cast<const f32x4*>(&t[base + q * 4]);
    }
    float v[12];
    float s = 0.0f;
    #pragma unroll
    for (int k = 0; k < 12; ++k) {
        v[k] = bf2f(h4[k >> 2][k & 3]) + bf2f(m4[k >> 2][k & 3]) + t4[k >> 2][k & 3];
        s += v[k];
    }
    #pragma unroll
    for (int off = 32; off; off >>= 1) s += __shfl_xor(s, off);
    float mean = s * (1.0f / 768.0f);
    float vs = 0.0f;
    #pragma unroll
    for (int k = 0; k < 12; ++k) { float d = v[k] - mean; vs += d * d; }
    #pragma unroll
    for (int off = 32; off; off >>= 1) vs += __shfl_xor(vs, off);
    float rstd = rsqrtf(vs * (1.0f / 768.0f) + 1e-5f);
    f32x4 ga[3], be[3];
    #pragma unroll
    for (int q = 0; q < 3; ++q) {
        ga[q] = *reinterpret_cast<const f32x4*>(&gamma[cb + q * 4]);
        be[q] = *reinterpret_cast<const f32x4*>(&beta[cb + q * 4]);
    }
    us4 oh[3], om[3];
    #pragma unroll
    for (int k = 0; k < 12; ++k) {
        float y = (v[k] - mean) * rstd * ga[k >> 2][k & 3] + be[k >> 2][k & 3];
        unsigned int pk = split_pack(y);
        oh[k >> 2][k & 3] = (unsigned short)pk;
        om[k >> 2][k & 3] = (unsigned short)(pk >> 16);
    }
    #pragma unroll
    for (int q = 0; q < 3; ++q) {
        *reinterpret_cast<us4*>(&xh[base + q * 4]) = oh[q];
        *reinterpret_cast<us4*>(&xm[base + q * 4]) = om[q];
    }
}

__global__ __launch_bounds__(256)
void embed_kernel(const int* __restrict__ ids, const float* __restrict__ emb,
                  unsigned short* __restrict__ xh, unsigned short* __restrict__ xm)
{
    int f4 = blockIdx.x * 256 + threadIdx.x;     // 8192*192 float4
    int tok = f4 / 192, c = f4 % 192;
    float4 v = *reinterpret_cast<const float4*>(emb + (size_t)ids[tok] * HD + c * 4);
    us4 hv, mv; unsigned int p;
    p = split_pack(v.x); hv[0] = (unsigned short)p; mv[0] = (unsigned short)(p >> 16);
    p = split_pack(v.y); hv[1] = (unsigned short)p; mv[1] = (unsigned short)(p >> 16);
    p = split_pack(v.z); hv[2] = (unsigned short)p; mv[2] = (unsigned short)(p >> 16);
    p = split_pack(v.w); hv[3] = (unsigned short)p; mv[3] = (unsigned short)(p >> 16);
    *reinterpret_cast<us4*>(&xh[(size_t)tok * HD + c * 4]) = hv;
    *reinterpret_cast<us4*>(&xm[(size_t)tok * HD + c * 4]) = mv;
}

// logits f32 = xh + xm
__global__ __launch_bounds__(256)
void out_logits_kernel(const unsigned short* __restrict__ xh, const unsigned short* __restrict__ xm,
                       float* __restrict__ out)
{
    int i = blockIdx.x * 256 + threadIdx.x;
    us4 hv = reinterpret_cast<const us4*>(xh)[i];
    us4 mv = reinterpret_cast<const us4*>(xm)[i];
    float4 o;
    o.x = bf2f(hv[0]) + bf2f(mv[0]);
    o.y = bf2f(hv[1]) + bf2f(mv[1]);
    o.z = bf2f(hv[2]) + bf2f(mv[2]);
    o.w = bf2f(hv[3]) + bf2f(mv[3]);
    reinterpret_cast<float4*>(out)[i] = o;
}

// emis[tok][t] = dot768(x[tok], head_w[t]) + head_b[t] — wave per token
__global__ __launch_bounds__(256)
void emis_kernel(const unsigned short* __restrict__ xh, const unsigned short* __restrict__ xm,
                 const float* __restrict__ hw, const float* __restrict__ hb,
                 float* __restrict__ emis)
{
    int tok = blockIdx.x * 4 + (threadIdx.x >> 6);
    int lane = threadIdx.x & 63;
    size_t base = (size_t)tok * HD + lane * 12;
    int cb = lane * 12;
    us4 h4[3], m4[3];
    #pragma unroll
    for (int q = 0; q < 3; ++q) {
        h4[q] = *reinterpret_cast<const us4*>(&xh[base + q * 4]);
        m4[q] = *reinterpret_cast<const us4*>(&xm[base + q * 4]);
    }
    float xv[12];
    #pragma unroll
    for (int k = 0; k < 12; ++k)
        xv[k] = bf2f(h4[k >> 2][k & 3]) + bf2f(m4[k >> 2][k & 3]);
    for (int t = 0; t < TT; ++t) {
        f32x4 w4[3];
        #pragma unroll
        for (int q = 0; q < 3; ++q)
            w4[q] = *reinterpret_cast<const f32x4*>(&hw[t * HD + cb + q * 4]);
        float a = 0.0f;
        #pragma unroll
        for (int k = 0; k < 12; ++k) a += xv[k] * w4[k >> 2][k & 3];
        #pragma unroll
        for (int off = 32; off; off >>= 1) a += __shfl_xor(a, off);
        if (lane == 0) emis[(size_t)tok * TT + t] = a + hb[t];
    }
}

__global__ void crf_num_kernel(const float* __restrict__ emis, const int* __restrict__ labels,
                               const float* __restrict__ start, const float* __restrict__ end,
                               const float* __restrict__ trans, float* __restrict__ num)
{
    int b = blockIdx.x, lane = threadIdx.x;   // blockDim 64
    float a = 0.0f;
    for (int s = lane; s < 512; s += 64) {
        int lab = labels[b * 512 + s];
        a += emis[(size_t)(b * 512 + s) * TT + lab];
        if (s > 0) a += trans[labels[b * 512 + s - 1] * TT + lab];
        else a += start[lab];
        if (s == 511) a += end[lab];
    }
    #pragma unroll
    for (int off = 32; off; off >>= 1) a += __shfl_xor(a, off);
    if (lane == 0) num[b] = a;
}

// ---------------------------------------------------------------------------
// Fused CRF forward + viterbi v4.
// Forward: r via readfirstlane (no LDS trip), 1 exp/lane, 1 LDS trip, tree dot.
// Viterbi: hot loop = value-max only (exact) + score history in LDS;
//          phase 2 computes the argmax table fully parallel (64 lanes);
//          lane-0 backtrack. Same first-max semantics as the serial reference.
// ---------------------------------------------------------------------------
__global__ __launch_bounds__(64)
void crf_path_kernel(const float* __restrict__ emis, const float* __restrict__ start,
                     const float* __restrict__ end, const float* __restrict__ trans,
                     float* __restrict__ logZ, float* __restrict__ out_tags)
{
    const int mode = blockIdx.x >> 4;
    const int b = blockIdx.x & 15;
    const int lane = threadIdx.x;
    const int j = lane & 31;
    __shared__ float xch[32];
    __shared__ float shist[512 * 32];            // viterbi score history (64 KB)
    __shared__ unsigned char hist[511][32];
    __shared__ float sval[32];
    __shared__ int path[512];

    const float* eb = emis + (size_t)b * 512 * TT;

    if (mode == 0) {
        if (lane < 32) {
            float Ecol[32];
            #pragma unroll
            for (int ii = 0; ii < 32; ++ii) Ecol[ii] = __expf(trans[ii * TT + j]);
            float cur[8], nxt[8];
            #pragma unroll
            for (int i = 0; i < 8; ++i) cur[i] = eb[(1 + i) * TT + j];
            float sc = start[j] + eb[j];
            for (int base = 1; base < 512; base += 8) {
                #pragma unroll
                for (int i = 0; i < 8; ++i) {
                    int s = base + 8 + i;
                    nxt[i] = eb[(s < 512 ? s : 511) * TT + j];
                }
                #pragma unroll
                for (int i = 0; i < 8; ++i) {
                    if (base + i < 512) {
                        float r = __uint_as_float(
                            __builtin_amdgcn_readfirstlane(__float_as_uint(sc)));
                        float p = __expf(sc - r);
                        xch[j] = p;
                        asm volatile("s_waitcnt lgkmcnt(0)" ::: "memory");
                        f32x4 tt[8];
                        #pragma unroll
                        for (int q = 0; q < 8; ++q)
                            tt[q] = *reinterpret_cast<const f32x4*>(&xch[q * 4]);
                        asm volatile("" ::: "memory");
                        float mm[16];
                        #pragma unroll
                        for (int q = 0; q < 16; ++q)
                            mm[q] = fmaf(tt[(2 * q + 1) >> 2][(2 * q + 1) & 3], Ecol[2 * q + 1],
                                         tt[(2 * q) >> 2][(2 * q) & 3] * Ecol[2 * q]);
                        float s8[8];
                        #pragma unroll
                        for (int q = 0; q < 8; ++q) s8[q] = mm[2 * q] + mm[2 * q + 1];
                        float s4[4];
                        #pragma unroll
                        for (int q = 0; q < 4; ++q) s4[q] = s8[2 * q] + s8[2 * q + 1];
                        float dot = (s4[0] + s4[1]) + (s4[2] + s4[3]);
                        sc = r + __logf(dot) + cur[i];
                    }
                }
                #pragma unroll
                for (int i = 0; i < 8; ++i) cur[i] = nxt[i];
            }
            float v = sc + end[j];
            float mx = v;
            #pragma unroll
            for (int off = 1; off < 32; off <<= 1) mx = fmaxf(mx, __shfl_xor(mx, off));
            float p = __expf(v - mx);
            float sm = p;
            #pragma unroll
            for (int off = 1; off < 32; off <<= 1) sm += __shfl_xor(sm, off);
            if (lane == 0) logZ[b] = mx + __logf(sm);
        }
    } else {
        // all 64 lanes preload trans column j (lanes j and j+32 share j)
        float tcol[32];
        #pragma unroll
        for (int ii = 0; ii < 32; ++ii) tcol[ii] = trans[ii * TT + j];

        // phase 1 (lanes 0..31): value-max recursion, store score history
        if (lane < 32) {
            float cur[8], nxt[8];
            #pragma unroll
            for (int i = 0; i < 8; ++i) cur[i] = eb[(1 + i) * TT + j];
            float sc = start[j] + eb[j];
            shist[0 * 32 + j] = sc;
            for (int base = 1; base < 512; base += 8) {
                #pragma unroll
                for (int i = 0; i < 8; ++i) {
                    int s = base + 8 + i;
                    nxt[i] = eb[(s < 512 ? s : 511) * TT + j];
                }
                #pragma unroll
                for (int i = 0; i < 8; ++i) {
                    if (base + i < 512) {
                        xch[j] = sc;
                        asm volatile("s_waitcnt lgkmcnt(0)" ::: "memory");
                        f32x4 tt[8];
                        #pragma unroll
                        for (int q = 0; q < 8; ++q)
                            tt[q] = *reinterpret_cast<const f32x4*>(&xch[q * 4]);
                        asm volatile("" ::: "memory");
                        float c[32];
                        #pragma unroll
                        for (int ii = 0; ii < 32; ++ii)
                            c[ii] = tt[ii >> 2][ii & 3] + tcol[ii];
                        float v1[16];
                        #pragma unroll
                        for (int q = 0; q < 16; ++q) v1[q] = fmaxf(c[2 * q], c[2 * q + 1]);
                        float v2[8];
                        #pragma unroll
                        for (int q = 0; q < 8; ++q) v2[q] = fmaxf(v1[2 * q], v1[2 * q + 1]);
                        float v3[4];
                        #pragma unroll
                        for (int q = 0; q < 4; ++q) v3[q] = fmaxf(v2[2 * q], v2[2 * q + 1]);
                        float best = fmaxf(fmaxf(v3[0], v3[1]), fmaxf(v3[2], v3[3]));
                        sc = best + cur[i];
                        shist[(base + i) * 32 + j] = sc;
                    }
                }
                #pragma unroll
                for (int i = 0; i < 8; ++i) cur[i] = nxt[i];
            }
            sval[j] = sc + end[j];
        }
        __syncthreads();

        // phase 2 (all 64 lanes): argmax table, first-max semantics
        const int h = lane >> 5;
        for (int it = 0; it < 256; ++it) {
            int s = 1 + 2 * it + h;
            if (s < 512) {
                const float* pr = &shist[(s - 1) * 32];
                float c[32];
                #pragma unroll
                for (int q = 0; q < 8; ++q) {
                    f32x4 t4 = *reinterpret_cast<const f32x4*>(&pr[q * 4]);
                    c[q * 4 + 0] = t4[0] + tcol[q * 4 + 0];
                    c[q * 4 + 1] = t4[1] + tcol[q * 4 + 1];
                    c[q * 4 + 2] = t4[2] + tcol[q * 4 + 2];
                    c[q * 4 + 3] = t4[3] + tcol[q * 4 + 3];
                }
                float v1[16]; int a1[16];
                #pragma unroll
                for (int q = 0; q < 16; ++q) {
                    bool ge = c[2 * q] >= c[2 * q + 1];
                    v1[q] = ge ? c[2 * q] : c[2 * q + 1];
                    a1[q] = ge ? 2 * q : 2 * q + 1;
                }
                float v2[8]; int a2[8];
                #pragma unroll
                for (int q = 0; q < 8; ++q) {
                    bool ge = v1[2 * q] >= v1[2 * q + 1];
                    v2[q] = ge ? v1[2 * q] : v1[2 * q + 1];
                    a2[q] = ge ? a1[2 * q] : a1[2 * q + 1];
                }
                float v3[4]; int a3[4];
                #pragma unroll
                for (int q = 0; q < 4; ++q) {
                    bool ge = v2[2 * q] >= v2[2 * q + 1];
                    v3[q] = ge ? v2[2 * q] : v2[2 * q + 1];
                    a3[q] = ge ? a2[2 * q] : a2[2 * q + 1];
                }
                float v4[2]; int a4[2];
                #pragma unroll
                for (int q = 0; q < 2; ++q) {
                    bool ge = v3[2 * q] >= v3[2 * q + 1];
                    v4[q] = ge ? v3[2 * q] : v3[2 * q + 1];
                    a4[q] = ge ? a3[2 * q] : a3[2 * q + 1];
                }
                bool ge = v4[0] >= v4[1];
                int arg = ge ? a4[0] : a4[1];
                hist[s - 1][j] = (unsigned char)arg;
            }
        }
        __syncthreads();

        if (lane == 0) {
            float best = sval[0]; int arg = 0;
            for (int i = 1; i < TT; ++i)
                if (sval[i] > best) { best = sval[i]; arg = i; }
            int t = arg; path[511] = t;
            for (int s = 510; s >= 0; --s) { t = hist[s][t]; path[s] = t; }
        }
        __syncthreads();
        for (int s = lane; s < 512; s += 64)
            out_tags[(size_t)b * 512 + s] = (float)path[s];
    }
}

__global__ void crf_loss_kernel(const float* __restrict__ num, const float* __restrict__ logZ,
                                float* __restrict__ out)
{
    if (threadIdx.x == 0) {
        float s = 0.0f;
        for (int b = 0; b < 16; ++b) s += num[b] - logZ[b];
        out[0] = -s / 10000.0f;
    }
}

extern "C" void kernel_launch(void* const* d_in, const int* in_sizes, int n_in,
                              void* d_out, int out_size, void* d_ws, size_t ws_size,
                              hipStream_t stream)
{
    (void)in_sizes; (void)n_in; (void)out_size; (void)ws_size;
    const int*   input_ids = (const int*)d_in[0];
    const int*   labels    = (const int*)d_in[1];
    const float* emb   = (const float*)d_in[3];
    const float* in_w  = (const float*)d_in[4];
    const float* in_b  = (const float*)d_in[5];
    const float* out_w = (const float*)d_in[6];
    const float* out_b = (const float*)d_in[7];
    const float* ln1g  = (const float*)d_in[8];
    const float* ln1b  = (const float*)d_in[9];
    const float* ln2g  = (const float*)d_in[10];
    const float* ln2b  = (const float*)d_in[11];
    const float* w1    = (const float*)d_in[12];
    const float* b1    = (const float*)d_in[13];
    const float* w2    = (const float*)d_in[14];
    const float* b2    = (const float*)d_in[15];
    const float* hw    = (const float*)d_in[16];
    const float* hb    = (const float*)d_in[17];
    const float* cs    = (const float*)d_in[18];
    const float* ce    = (const float*)d_in[19];
    const float* ct    = (const float*)d_in[20];
    float* out = (float*)d_out;

    char* ws = (char*)d_ws;
    unsigned short* xh   = (unsigned short*)(ws);
    unsigned short* xm   = (unsigned short*)(ws + 12582912);
    unsigned short* qkvh = (unsigned short*)(ws + 25165824);
    unsigned short* qkvm = (unsigned short*)(ws + 62914560);
    unsigned short* ohb  = (unsigned short*)(ws + 100663296);
    unsigned short* omb  = (unsigned short*)(ws + 113246208);
    float*          tmp  = (float*)(ws + 125829120);
    unsigned short* vth  = (unsigned short*)(ws + 125829120);  // alias tmp (disjoint lifetime)
    unsigned short* vtm  = (unsigned short*)(ws + 138412032);
    unsigned short* wih  = (unsigned short*)(ws + 150994944);
    unsigned short* wim  = (unsigned short*)(ws + 154533888);
    unsigned short* woh  = (unsigned short*)(ws + 158072832);
    unsigned short* wom  = (unsigned short*)(ws + 159252480);
    unsigned short* w1h  = (unsigned short*)(ws + 160432128);
    unsigned short* w1m  = (unsigned short*)(ws + 161611776);
    unsigned short* w2h  = (unsigned short*)(ws + 162791424);
    unsigned short* w2m  = (unsigned short*)(ws + 163971072);
    unsigned short* f1h  = qkvh;   // qkv dead after attn
    unsigned short* f1m  = qkvm;
    float* emis = (float*)(ws + 100663296);                // alias ohb (dead post-encoder)
    float* numb = (float*)(ws + 100663296 + 1048576);
    float* logZ = numb + 16;

    embed_kernel<<<MTOK * 192 / 256, 256, 0, stream>>>(input_ids, emb, xh, xm);

    for (int l = 0; l < NL; ++l) {
        wsplit4_kernel<<<3456, 256, 0, stream>>>(
            in_w + (size_t)l * H3 * HD, out_w + (size_t)l * HD * HD,
            w1 + (size_t)l * HD * HD, w2 + (size_t)l * HD * HD,
            wih, wim, woh, wom, w1h, w1m, w2h, w2m);

        gemm_pair_kernel<false, true><<<dim3(18, 64), 256, 0, stream>>>(
            xh, xm, wih, wim, in_b + (size_t)l * H3, nullptr, qkvh, qkvm, H3);
        vtrans_kernel<<<dim3(8, 192), 256, 0, stream>>>(qkvh, qkvm, vth, vtm);
        attn_kernel<<<dim3(2, 192), 256, 0, stream>>>(qkvh, qkvm, vth, vtm, ohb, omb);
        gemm_pair_kernel<false, false><<<dim3(6, 64), 256, 0, stream>>>(
            ohb, omb, woh, wom, out_b + (size_t)l * HD, tmp, nullptr, nullptr, HD);
        ln_residual_kernel<<<2048, 256, 0, stream>>>(xh, xm, tmp, ln1g + l * HD, ln1b + l * HD);
        gemm_pair_kernel<true, true><<<dim3(6, 64), 256, 0, stream>>>(
            xh, xm, w1h, w1m, b1 + (size_t)l * HD, nullptr, f1h, f1m, HD);
        gemm_pair_kernel<false, false><<<dim3(6, 64), 256, 0, stream>>>(
            f1h, f1m, w2h, w2m, b2 + (size_t)l * HD, tmp, nullptr, nullptr, HD);
        ln_residual_kernel<<<2048, 256, 0, stream>>>(xh, xm, tmp, ln2g + l * HD, ln2b + l * HD);
    }

    out_logits_kernel<<<MTOK * 192 / 256, 256, 0, stream>>>(xh, xm, out);

    emis_kernel<<<2048, 256, 0, stream>>>(xh, xm, hw, hb, emis);
    crf_num_kernel<<<16, 64, 0, stream>>>(emis, labels, cs, ce, ct, numb);
    crf_path_kernel<<<32, 64, 0, stream>>>(emis, cs, ce, ct, logZ, out + 6291457);
    crf_loss_kernel<<<1, 64, 0, stream>>>(numb, logZ, out + 6291456);
}